// Round 5
// baseline (618.881 us; speedup 1.0000x reference)
//
#include <hip/hip_runtime.h>
#include <hip/hip_bf16.h>
#include <math.h>

#define SEQ 8192
#define DIMS 1024
#define NH 16
#define HD 64

typedef _Float16 h16;
typedef __attribute__((ext_vector_type(8))) _Float16 f16x8;
typedef __attribute__((ext_vector_type(4))) _Float16 h16x4;
typedef __attribute__((ext_vector_type(4))) float f32x4;

// ---------------- LN stats over x: xhat (fp16) + mag ----------------
__global__ void k_ln_stats(const float* __restrict__ x, h16* __restrict__ xhat,
                           float* __restrict__ mag){
  const int row = blockIdx.x, t = threadIdx.x;
  float4 v = ((const float4*)(x + (size_t)row*DIMS))[t];
  float s = v.x+v.y+v.z+v.w;
  float s2 = v.x*v.x+v.y*v.y+v.z*v.z+v.w*v.w;
  #pragma unroll
  for(int m=1;m<64;m<<=1){ s += __shfl_xor(s,m,64); s2 += __shfl_xor(s2,m,64); }
  __shared__ float ls[4], ls2[4];
  const int wid = t>>6;
  if((t&63)==0){ ls[wid]=s; ls2[wid]=s2; }
  __syncthreads();
  s  = ls[0]+ls[1]+ls[2]+ls[3];
  s2 = ls2[0]+ls2[1]+ls2[2]+ls2[3];
  const float mean = s*(1.f/DIMS);
  const float var  = s2*(1.f/DIMS) - mean*mean;
  const float rstd = rsqrtf(var + 1e-5f);
  if(t==0) mag[row] = mean;
  h16x4 o;
  o[0] = (h16)((v.x-mean)*rstd); o[1] = (h16)((v.y-mean)*rstd);
  o[2] = (h16)((v.z-mean)*rstd); o[3] = (h16)((v.w-mean)*rstd);
  ((h16x4*)(xhat + (size_t)row*DIMS))[t] = o;
}

// ---------------- RoPE cos/sin table (f64 accurate) ----------------
__global__ void k_sincos(float2* __restrict__ tab){
  const int id = blockIdx.x*256 + threadIdx.x;   // 8192*32
  const int t = id >> 5, d = id & 31;
  const double fr = 0.2 * (pow(21.0, (double)d / 31.0) - 1.0);
  const double ang = (double)t * fr;
  tab[id] = make_float2((float)cos(ang), (float)sin(ang));
}

// ------- deterministic bias fold: bias_out[j] = b0[j] + sum_i bln[i]*W[i][j] -------
__global__ void k_fold_bias(const float* __restrict__ W, const float* __restrict__ bln,
                            const float* __restrict__ b0, float* __restrict__ bias_out,
                            const int C){
  const int j = blockIdx.x*256 + threadIdx.x;
  if(j >= C) return;
  float acc = b0[j];
  for(int i=0;i<1024;i++) acc += bln[i]*W[(size_t)i*C + j];
  bias_out[j] = acc;
}

// ------- weight prep: Wt[j][i] = g[i]*W[i][j] (fp16) -------
__global__ void k_prep_w(const float* __restrict__ W, const float* __restrict__ g,
                         h16* __restrict__ Wt, const int R, const int C){
  __shared__ float tile[64][65];
  const int c0 = blockIdx.x*64, r0 = blockIdx.y*64;
  const int t = threadIdx.x;
  const int cl = t & 63, rl0 = t >> 6;
  #pragma unroll
  for(int i=0;i<16;i++){
    const int r = rl0 + i*4;
    const float w = W[(size_t)(r0+r)*C + c0 + cl];
    const float gg = g ? g[r0+r] : 1.f;
    tile[r][cl] = w*gg;
  }
  __syncthreads();
  const int jl = t >> 2, ic = (t & 3)*16;
  h16* dst = Wt + (size_t)(c0+jl)*R + r0 + ic;
  #pragma unroll
  for(int i=0;i<16;i+=4){
    h16x4 o;
    o[0] = (h16)tile[ic+i+0][jl];
    o[1] = (h16)tile[ic+i+1][jl];
    o[2] = (h16)tile[ic+i+2][jl];
    o[3] = (h16)tile[ic+i+3][jl];
    *(h16x4*)(dst + i) = o;
  }
}

// MODE 0: plain f32 C=A@Bt+bias   (final out GEMM)
// MODE 1: Q GEMM, epilogue RoPE + head-LN -> OutB=qn (x0.125)
// MODE 2: KV GEMM (compacted strided rows); cols<1024: K path (RoPE+LN -> OutB=kn),
//         cols>=1024: V path (bias only, LDS transpose -> vT[h][d][key])
template<int MODE>
__global__ __launch_bounds__(256) void k_gemm(
    const h16* __restrict__ A, const h16* __restrict__ Bt,
    const float* __restrict__ bias, float* __restrict__ Cf,
    h16* __restrict__ OutB, h16* __restrict__ vT,
    const float* __restrict__ mag, const float2* __restrict__ tab,
    const float* __restrict__ lg, const float* __restrict__ lb,
    const int N, const int* __restrict__ skip_p){
  int M = SEQ, pitchA = DIMS, st = 1;
  if(MODE==2){
    st = max(1, 4 - skip_p[0]);
    M = (SEQ + st - 1)/st;
    pitchA = st*DIMS;
  }
  const int m0 = blockIdx.y*128, n0 = blockIdx.x*128;
  if(m0 >= M) return;
  __shared__ h16 smem[(MODE==2) ? 128*136 : 8192];
  h16* As = smem;
  h16* Bs = smem + 4096;
  const int t = threadIdx.x;
  const int w = t>>6, l = t&63, l4 = l>>4, l16 = l&15;
  const int wm = w>>1, wn = w&1;
  f32x4 acc[4][4];
  #pragma unroll
  for(int i=0;i<4;i++)
    #pragma unroll
    for(int j=0;j<4;j++)
      #pragma unroll
      for(int r=0;r<4;r++) acc[i][j][r] = 0.f;
  for(int k0=0;k0<1024;k0+=32){
    __syncthreads();
    #pragma unroll
    for(int c=t;c<512;c+=256){
      const int row = c>>2, kp = (c&3)*8;
      int ar = m0+row; if(ar > M-1) ar = M-1;
      *(f16x8*)(&As[row*32+kp]) = *(const f16x8*)(A + (size_t)ar*pitchA + k0 + kp);
      *(f16x8*)(&Bs[row*32+kp]) = *(const f16x8*)(Bt + (size_t)(n0+row)*1024 + k0 + kp);
    }
    __syncthreads();
    f16x8 af[4], bfr[4];
    #pragma unroll
    for(int i=0;i<4;i++){
      af[i]  = *(const f16x8*)(&As[(wm*64 + i*16 + l16)*32 + l4*8]);
      bfr[i] = *(const f16x8*)(&Bs[(wn*64 + i*16 + l16)*32 + l4*8]);
    }
    #pragma unroll
    for(int i=0;i<4;i++)
      #pragma unroll
      for(int j=0;j<4;j++)
        acc[i][j] = __builtin_amdgcn_mfma_f32_16x16x32_f16(af[i], bfr[j], acc[i][j], 0,0,0);
  }

  if(MODE==0){
    #pragma unroll
    for(int i=0;i<4;i++){
      const int rb = m0 + wm*64 + i*16 + l4*4;
      #pragma unroll
      for(int j=0;j<4;j++){
        const int col = n0 + wn*64 + j*16 + l16;
        const float bb = bias[col];
        #pragma unroll
        for(int r=0;r<4;r++)
          Cf[(size_t)(rb+r)*N + col] = acc[i][j][r] + bb;
      }
    }
    return;
  }

  float biasv[4];
  #pragma unroll
  for(int j=0;j<4;j++) biasv[j] = bias[n0 + wn*64 + j*16 + l16];

  const bool vpath = (MODE==2) && (n0 >= 1024);
  if(!vpath){
    // ---- RoPE + per-head LN epilogue (Q or K) ----
    float gv[4], bv[4];
    #pragma unroll
    for(int j=0;j<4;j++){ gv[j] = lg[j*16+l16]; bv[j] = lb[j*16+l16]; }
    const int h = (n0>>6) + wn;
    const float scl = (MODE==1) ? 0.125f : 1.0f;
    const float sgn = (l16&1) ? 1.f : -1.f;
    #pragma unroll
    for(int i=0;i<4;i++){
      #pragma unroll
      for(int r=0;r<4;r++){
        int row = m0 + wm*64 + i*16 + l4*4 + r;
        const int rowc = (row < M) ? row : (M-1);
        const int tpos = (MODE==2) ? rowc*st : rowc;
        const float mg = mag[tpos];
        float v[4], pr[4], o4[4];
        #pragma unroll
        for(int j=0;j<4;j++) v[j] = acc[i][j][r] + biasv[j];
        #pragma unroll
        for(int j=0;j<4;j++) pr[j] = __shfl_xor(v[j], 1);
        float s1 = 0.f, s2 = 0.f;
        #pragma unroll
        for(int j=0;j<4;j++){
          const float2 cs = tab[(size_t)tpos*32 + j*8 + (l16>>1)];
          const float e = mg * (v[j]*cs.x + sgn*pr[j]*cs.y);
          o4[j] = e; s1 += e; s2 += e*e;
        }
        #pragma unroll
        for(int mm=1;mm<16;mm<<=1){ s1 += __shfl_xor(s1,mm,64); s2 += __shfl_xor(s2,mm,64); }
        const float mean = s1*(1.f/HD);
        const float var  = s2*(1.f/HD) - mean*mean;
        const float rstd = rsqrtf(var + 1e-5f);
        if(row < M){
          h16* dst = OutB + ((size_t)h*SEQ + row)*HD;
          #pragma unroll
          for(int j=0;j<4;j++)
            dst[j*16 + l16] = (h16)(((o4[j]-mean)*rstd*gv[j] + bv[j])*scl);
        }
      }
    }
  } else {
    // ---- V path: bias, LDS transpose, coalesced vT[h][d][key] writes ----
    __syncthreads();
    #pragma unroll
    for(int i=0;i<4;i++)
      #pragma unroll
      for(int j=0;j<4;j++)
        #pragma unroll
        for(int r=0;r<4;r++){
          const int key = wm*64 + i*16 + l4*4 + r;
          smem[(wn*64 + j*16 + l16)*136 + key] = (h16)(acc[i][j][r] + biasv[j]);
        }
    __syncthreads();
    const int rowT = t>>1, dh = rowT & 63, hloc = rowT>>6;
    const int hglob = ((n0-1024)>>6) + hloc;
    const h16* src = &smem[rowT*136 + (t&1)*64];
    h16* dstv = vT + ((size_t)hglob*HD + dh)*SEQ + m0 + (t&1)*64;
    #pragma unroll
    for(int c=0;c<64;c+=4)
      *(h16x4*)(dstv+c) = *(const h16x4*)(src+c);
  }
}

// ---------------- zero-pad vT tail keys up to 64-boundary ----------------
__global__ void k_pad_vt(h16* __restrict__ vT, const int* __restrict__ skip_p){
  const int st = max(1, 4 - skip_p[0]);
  const int n_kv = (SEQ + st - 1)/st;
  const int kb = ((n_kv + 63)/64)*64;
  const int pad = min(kb, SEQ) - n_kv;
  if(pad <= 0) return;
  const int total = NH*HD*pad;
  for(int i = threadIdx.x; i < total; i += 256){
    const int key = n_kv + (i % pad);
    const int hd = i / pad;
    vT[(size_t)hd*SEQ + key] = (h16)0.f;
  }
}

// ---------------- flash attention ----------------
__launch_bounds__(256)
__global__ void k_attn(const h16* __restrict__ qn, const h16* __restrict__ kn,
                       const h16* __restrict__ vT, h16* __restrict__ aout,
                       const int* __restrict__ skip_p){
  const int st = max(1, 4 - skip_p[0]);
  const int n_kv = (SEQ + st - 1)/st;
  const int h = blockIdx.y, q0 = blockIdx.x*128;
  const int w = threadIdx.x >> 6, l = threadIdx.x & 63;
  const int l4 = l >> 4, l16 = l & 15;
  __shared__ h16 P[4][32][64];
  const h16* Qh = qn + (size_t)h*SEQ*HD;
  const h16* Kh = kn + (size_t)h*SEQ*HD;
  const h16* Vh = vT + (size_t)h*HD*SEQ;
  f16x8 qf[2][2];
  #pragma unroll
  for(int mi=0;mi<2;mi++)
    #pragma unroll
    for(int ks=0;ks<2;ks++)
      qf[mi][ks] = *(const f16x8*)(Qh + (size_t)(q0 + w*32 + mi*16 + l16)*HD + ks*32 + l4*8);
  f32x4 o[2][4];
  float mrow[2][4], lrow[2][4];
  #pragma unroll
  for(int mi=0;mi<2;mi++)
    #pragma unroll
    for(int r=0;r<4;r++){ mrow[mi][r] = -1e30f; lrow[mi][r] = 0.f; }
  #pragma unroll
  for(int mi=0;mi<2;mi++)
    #pragma unroll
    for(int j=0;j<4;j++)
      #pragma unroll
      for(int r=0;r<4;r++) o[mi][j][r] = 0.f;
  const int nkb = (n_kv + 63) >> 6;
  for(int kb=0; kb<nkb; kb++){
    const int kbase = kb*64;
    f32x4 S[2][4];
    #pragma unroll
    for(int mi=0;mi<2;mi++)
      #pragma unroll
      for(int j=0;j<4;j++)
        #pragma unroll
        for(int r=0;r<4;r++) S[mi][j][r] = 0.f;
    #pragma unroll
    for(int ks=0;ks<2;ks++){
      f16x8 kf[4];
      #pragma unroll
      for(int nj=0;nj<4;nj++)
        kf[nj] = *(const f16x8*)(Kh + (size_t)(kbase + nj*16 + l16)*HD + ks*32 + l4*8);
      #pragma unroll
      for(int mi=0;mi<2;mi++)
        #pragma unroll
        for(int nj=0;nj<4;nj++)
          S[mi][nj] = __builtin_amdgcn_mfma_f32_16x16x32_f16(qf[mi][ks], kf[nj], S[mi][nj], 0,0,0);
    }
    #pragma unroll
    for(int nj=0;nj<4;nj++){
      const int key = kbase + nj*16 + l16;
      if(key >= n_kv){
        #pragma unroll
        for(int r=0;r<4;r++){ S[0][nj][r] = -1e30f; S[1][nj][r] = -1e30f; }
      }
    }
    #pragma unroll
    for(int mi=0;mi<2;mi++){
      #pragma unroll
      for(int r=0;r<4;r++){
        float mx = fmaxf(fmaxf(S[mi][0][r],S[mi][1][r]), fmaxf(S[mi][2][r],S[mi][3][r]));
        #pragma unroll
        for(int mm=1;mm<16;mm<<=1) mx = fmaxf(mx, __shfl_xor(mx,mm,64));
        const float mnew = fmaxf(mrow[mi][r], mx);
        const float fac = __expf(mrow[mi][r] - mnew);
        mrow[mi][r] = mnew;
        float rs = 0.f;
        #pragma unroll
        for(int nj=0;nj<4;nj++){
          const float p = __expf(S[mi][nj][r] - mnew);
          S[mi][nj][r] = p; rs += p;
        }
        #pragma unroll
        for(int mm=1;mm<16;mm<<=1) rs += __shfl_xor(rs,mm,64);
        lrow[mi][r] = lrow[mi][r]*fac + rs;
        #pragma unroll
        for(int j2=0;j2<4;j2++) o[mi][j2][r] *= fac;
      }
    }
    #pragma unroll
    for(int mi=0;mi<2;mi++)
      #pragma unroll
      for(int nj=0;nj<4;nj++)
        #pragma unroll
        for(int r=0;r<4;r++)
          P[w][mi*16 + l4*4 + r][nj*16 + l16] = (h16)S[mi][nj][r];
    asm volatile("s_waitcnt lgkmcnt(0)" ::: "memory");
    #pragma unroll
    for(int ks=0;ks<2;ks++){
      f16x8 pf[2];
      #pragma unroll
      for(int mi=0;mi<2;mi++)
        pf[mi] = *(const f16x8*)(&P[w][mi*16 + l16][ks*32 + l4*8]);
      #pragma unroll
      for(int j2=0;j2<4;j2++){
        const f16x8 vf = *(const f16x8*)(Vh + (size_t)(j2*16 + l16)*SEQ + kbase + ks*32 + l4*8);
        #pragma unroll
        for(int mi=0;mi<2;mi++)
          o[mi][j2] = __builtin_amdgcn_mfma_f32_16x16x32_f16(pf[mi], vf, o[mi][j2], 0,0,0);
      }
    }
  }
  #pragma unroll
  for(int mi=0;mi<2;mi++){
    #pragma unroll
    for(int r=0;r<4;r++){
      const float inv = 1.f/lrow[mi][r];
      const int row = q0 + w*32 + mi*16 + l4*4 + r;
      #pragma unroll
      for(int j2=0;j2<4;j2++)
        aout[(size_t)row*DIMS + h*HD + j2*16 + l16] = (h16)(o[mi][j2][r]*inv);
    }
  }
}

// ---------------- launch ----------------
extern "C" void kernel_launch(void* const* d_in, const int* in_sizes, int n_in,
                              void* d_out, int out_size, void* d_ws, size_t ws_size,
                              hipStream_t stream){
  const float* x    = (const float*)d_in[0];
  const float* qn_g = (const float*)d_in[1];
  const float* qn_b = (const float*)d_in[2];
  const float* Wq   = (const float*)d_in[3];
  const float* bq   = (const float*)d_in[4];
  const float* kvn_g= (const float*)d_in[5];
  const float* kvn_b= (const float*)d_in[6];
  const float* Wkv  = (const float*)d_in[7];
  const float* bkv  = (const float*)d_in[8];
  const float* Wout = (const float*)d_in[9];
  const float* bout = (const float*)d_in[10];
  const float* ln_g = (const float*)d_in[11];
  const float* ln_b = (const float*)d_in[12];
  const int*  skip  = (const int*)d_in[13];

  // Workspace budget ~74 MB; refuse (clean fail, no OOB scribble) if undersized.
  if(ws_size < (size_t)78*1000*1000) return;

  char* p = (char*)d_ws;
  size_t off = 0;
  auto take = [&](size_t n)->char*{
    char* r = p + off; off = (off + n + 255) & ~(size_t)255; return r;
  };
  h16*    xhat = (h16*)   take((size_t)SEQ*DIMS*2);   // also reused as abuf after kv GEMM
  float*  mag  = (float*) take((size_t)SEQ*4);
  float2* tab  = (float2*)take((size_t)SEQ*32*8);
  h16*    WqT  = (h16*)   take((size_t)1024*1024*2);
  h16*    WkvT = (h16*)   take((size_t)2048*1024*2);
  h16*    WoutT= (h16*)   take((size_t)1024*1024*2);
  float*  bqp  = (float*) take(1024*4);
  float*  bkvp = (float*) take(2048*4);
  h16*    qn   = (h16*)   take((size_t)NH*SEQ*HD*2);
  h16*    kn   = (h16*)   take((size_t)NH*SEQ*HD*2);
  h16*    vT   = (h16*)   take((size_t)NH*HD*SEQ*2);
  h16*    abuf = xhat;   // alias: xhat dead after kv GEMM, attn writes after

  k_ln_stats<<<dim3(SEQ), dim3(256), 0, stream>>>(x, xhat, mag);
  k_sincos<<<dim3(SEQ*32/256), dim3(256), 0, stream>>>(tab);
  k_fold_bias<<<dim3(4), dim3(256), 0, stream>>>(Wq,  qn_b,  bq,  bqp,  1024);
  k_fold_bias<<<dim3(8), dim3(256), 0, stream>>>(Wkv, kvn_b, bkv, bkvp, 2048);
  k_prep_w<<<dim3(16,16), dim3(256), 0, stream>>>(Wq,  qn_g,  WqT,  1024, 1024);
  k_prep_w<<<dim3(32,16), dim3(256), 0, stream>>>(Wkv, kvn_g, WkvT, 1024, 2048);
  k_prep_w<<<dim3(16,16), dim3(256), 0, stream>>>(Wout, nullptr, WoutT, 1024, 1024);
  k_gemm<1><<<dim3(8,64),  dim3(256), 0, stream>>>(xhat, WqT,  bqp, nullptr, qn, nullptr,
                                                   mag, tab, ln_g, ln_b, 1024, skip);
  k_gemm<2><<<dim3(16,64), dim3(256), 0, stream>>>(xhat, WkvT, bkvp, nullptr, kn, vT,
                                                   mag, tab, ln_g, ln_b, 2048, skip);
  k_pad_vt<<<dim3(1), dim3(256), 0, stream>>>(vT, skip);
  k_attn<<<dim3(64,16), dim3(256), 0, stream>>>(qn, kn, vT, abuf, skip);
  k_gemm<0><<<dim3(8,64), dim3(256), 0, stream>>>(abuf, WoutT, bout, (float*)d_out,
                                                  nullptr, nullptr, nullptr, nullptr,
                                                  nullptr, nullptr, 1024, skip);
}

// Round 6
// 606.813 us; speedup vs baseline: 1.0199x; 1.0199x over previous
//
#include <hip/hip_runtime.h>
#include <hip/hip_bf16.h>
#include <math.h>

#define SEQ 8192
#define DIMS 1024
#define NH 16
#define HD 64

typedef _Float16 h16;
typedef __attribute__((ext_vector_type(8))) _Float16 f16x8;
typedef __attribute__((ext_vector_type(4))) _Float16 h16x4;
typedef __attribute__((ext_vector_type(4))) float f32x4;

#if defined(__has_builtin)
#if __has_builtin(__builtin_amdgcn_global_load_lds)
#define USE_GLOAD 1
#endif
#endif
#ifndef USE_GLOAD
#define USE_GLOAD 0
#endif

#if USE_GLOAD
__device__ __forceinline__ void gload16(h16* lds, const h16* g){
  __builtin_amdgcn_global_load_lds((const __attribute__((address_space(1))) void*)g,
                                   (__attribute__((address_space(3))) void*)lds, 16, 0, 0);
}
#endif

// ---------------- LN stats over x: xhat (fp16) + mag ----------------
__global__ void k_ln_stats(const float* __restrict__ x, h16* __restrict__ xhat,
                           float* __restrict__ mag){
  const int row = blockIdx.x, t = threadIdx.x;
  float4 v = ((const float4*)(x + (size_t)row*DIMS))[t];
  float s = v.x+v.y+v.z+v.w;
  float s2 = v.x*v.x+v.y*v.y+v.z*v.z+v.w*v.w;
  #pragma unroll
  for(int m=1;m<64;m<<=1){ s += __shfl_xor(s,m,64); s2 += __shfl_xor(s2,m,64); }
  __shared__ float ls[4], ls2[4];
  const int wid = t>>6;
  if((t&63)==0){ ls[wid]=s; ls2[wid]=s2; }
  __syncthreads();
  s  = ls[0]+ls[1]+ls[2]+ls[3];
  s2 = ls2[0]+ls2[1]+ls2[2]+ls2[3];
  const float mean = s*(1.f/DIMS);
  const float var  = s2*(1.f/DIMS) - mean*mean;
  const float rstd = rsqrtf(var + 1e-5f);
  if(t==0) mag[row] = mean;
  h16x4 o;
  o[0] = (h16)((v.x-mean)*rstd); o[1] = (h16)((v.y-mean)*rstd);
  o[2] = (h16)((v.z-mean)*rstd); o[3] = (h16)((v.w-mean)*rstd);
  ((h16x4*)(xhat + (size_t)row*DIMS))[t] = o;
}

// ---------------- RoPE freqs (f64 pow, 32 threads once) ----------------
__global__ void k_freq(double* __restrict__ fr){
  const int d = threadIdx.x;
  if(d < 32) fr[d] = 0.2 * (pow(21.0, (double)d / 31.0) - 1.0);
}

// ---------------- cos/sin table: f64 range-reduce, f32 trig ----------------
__global__ void k_sincos(const double* __restrict__ fr, float2* __restrict__ tab){
  const int id = blockIdx.x*256 + threadIdx.x;   // 8192*32
  const int t = id >> 5, d = id & 31;
  const double ang = (double)t * fr[d];
  const double k = rint(ang * 0.15915494309189535);
  const float red = (float)(ang - k * 6.283185307179586);
  float s, c;
  __sincosf(red, &s, &c);
  tab[id] = make_float2(c, s);
}

// ------- deterministic two-stage bias fold: bias_out[j] = b0[j] + sum_i bln[i]*W[i][j] -------
__global__ void k_fold_part(const float* __restrict__ W, const float* __restrict__ bln,
                            float* __restrict__ part, const int C){
  const int j = blockIdx.x*256 + threadIdx.x;
  const int ib = blockIdx.y;                 // 16 chunks x 64 rows
  if(j >= C) return;
  float acc = 0.f;
  const int i0 = ib*64;
  #pragma unroll 4
  for(int i=i0;i<i0+64;i++) acc += bln[i]*W[(size_t)i*C + j];
  part[(size_t)ib*C + j] = acc;
}
__global__ void k_fold_sum(const float* __restrict__ part, const float* __restrict__ b0,
                           float* __restrict__ bias_out, const int C){
  const int j = blockIdx.x*256 + threadIdx.x;
  if(j >= C) return;
  float acc = b0[j];
  #pragma unroll
  for(int ib=0; ib<16; ib++) acc += part[(size_t)ib*C + j];
  bias_out[j] = acc;
}

// ------- weight prep: Wt[j][i] = g[i]*W[i][j] (fp16) -------
__global__ void k_prep_w(const float* __restrict__ W, const float* __restrict__ g,
                         h16* __restrict__ Wt, const int R, const int C){
  __shared__ float tile[64][65];
  const int c0 = blockIdx.x*64, r0 = blockIdx.y*64;
  const int t = threadIdx.x;
  const int cl = t & 63, rl0 = t >> 6;
  #pragma unroll
  for(int i=0;i<16;i++){
    const int r = rl0 + i*4;
    const float w = W[(size_t)(r0+r)*C + c0 + cl];
    const float gg = g ? g[r0+r] : 1.f;
    tile[r][cl] = w*gg;
  }
  __syncthreads();
  const int jl = t >> 2, ic = (t & 3)*16;
  h16* dst = Wt + (size_t)(c0+jl)*R + r0 + ic;
  #pragma unroll
  for(int i=0;i<16;i+=4){
    h16x4 o;
    o[0] = (h16)tile[ic+i+0][jl];
    o[1] = (h16)tile[ic+i+1][jl];
    o[2] = (h16)tile[ic+i+2][jl];
    o[3] = (h16)tile[ic+i+3][jl];
    *(h16x4*)(dst + i) = o;
  }
}

// MODE 0: plain f32 C=A@Bt+bias   (final out GEMM)
// MODE 1: Q GEMM, epilogue RoPE + head-LN -> OutB=qn (x0.125)
// MODE 2: KV GEMM (compacted strided rows); cols<1024: K path (RoPE+LN -> OutB=kn),
//         cols>=1024: V path (bias only, LDS transpose -> vT[h][d][key])
template<int MODE>
__global__ __launch_bounds__(256) void k_gemm(
    const h16* __restrict__ A, const h16* __restrict__ Bt,
    const float* __restrict__ bias, float* __restrict__ Cf,
    h16* __restrict__ OutB, h16* __restrict__ vT,
    const float* __restrict__ mag, const float2* __restrict__ tab,
    const float* __restrict__ lg, const float* __restrict__ lb,
    const int N, const int* __restrict__ skip_p){
  int M = SEQ, pitchA = DIMS, st = 1;
  if(MODE==2){
    st = max(1, 4 - skip_p[0]);
    M = (SEQ + st - 1)/st;
    pitchA = st*DIMS;
  }
  const int m0 = blockIdx.y*128, n0 = blockIdx.x*128;
  if(m0 >= M) return;
  __shared__ h16 smem[(MODE==2) ? 128*136 : 8192];
  h16* As = smem;
  h16* Bs = smem + 4096;
  const int t = threadIdx.x;
  const int w = t>>6, l = t&63, l4 = l>>4, l16 = l&15;
  const int wm = w>>1, wn = w&1;
  f32x4 acc[4][4];
  #pragma unroll
  for(int i=0;i<4;i++)
    #pragma unroll
    for(int j=0;j<4;j++)
      #pragma unroll
      for(int r=0;r<4;r++) acc[i][j][r] = 0.f;
  for(int k0=0;k0<1024;k0+=32){
    __syncthreads();
    #pragma unroll
    for(int c=t;c<512;c+=256){
      const int row = c>>2, kp = (c&3)*8;
      int ar = m0+row; if(ar > M-1) ar = M-1;
#if USE_GLOAD
      gload16(&As[row*32+kp], A + (size_t)ar*pitchA + k0 + kp);
      gload16(&Bs[row*32+kp], Bt + (size_t)(n0+row)*1024 + k0 + kp);
#else
      *(f16x8*)(&As[row*32+kp]) = *(const f16x8*)(A + (size_t)ar*pitchA + k0 + kp);
      *(f16x8*)(&Bs[row*32+kp]) = *(const f16x8*)(Bt + (size_t)(n0+row)*1024 + k0 + kp);
#endif
    }
    __syncthreads();
    f16x8 af[4], bfr[4];
    #pragma unroll
    for(int i=0;i<4;i++){
      af[i]  = *(const f16x8*)(&As[(wm*64 + i*16 + l16)*32 + l4*8]);
      bfr[i] = *(const f16x8*)(&Bs[(wn*64 + i*16 + l16)*32 + l4*8]);
    }
    #pragma unroll
    for(int i=0;i<4;i++)
      #pragma unroll
      for(int j=0;j<4;j++)
        acc[i][j] = __builtin_amdgcn_mfma_f32_16x16x32_f16(af[i], bfr[j], acc[i][j], 0,0,0);
  }

  if(MODE==0){
    #pragma unroll
    for(int i=0;i<4;i++){
      const int rb = m0 + wm*64 + i*16 + l4*4;
      #pragma unroll
      for(int j=0;j<4;j++){
        const int col = n0 + wn*64 + j*16 + l16;
        const float bb = bias[col];
        #pragma unroll
        for(int r=0;r<4;r++)
          Cf[(size_t)(rb+r)*N + col] = acc[i][j][r] + bb;
      }
    }
    return;
  }

  float biasv[4];
  #pragma unroll
  for(int j=0;j<4;j++) biasv[j] = bias[n0 + wn*64 + j*16 + l16];

  const bool vpath = (MODE==2) && (n0 >= 1024);
  if(!vpath){
    // ---- RoPE + per-head LN epilogue (Q or K) ----
    float gv[4], bv[4];
    #pragma unroll
    for(int j=0;j<4;j++){ gv[j] = lg[j*16+l16]; bv[j] = lb[j*16+l16]; }
    const int h = (n0>>6) + wn;
    const float scl = (MODE==1) ? 0.125f : 1.0f;
    const float sgn = (l16&1) ? 1.f : -1.f;
    #pragma unroll
    for(int i=0;i<4;i++){
      #pragma unroll
      for(int r=0;r<4;r++){
        int row = m0 + wm*64 + i*16 + l4*4 + r;
        const int rowc = (row < M) ? row : (M-1);
        const int tpos = (MODE==2) ? rowc*st : rowc;
        const float mg = mag[tpos];
        float v[4], pr[4], o4[4];
        #pragma unroll
        for(int j=0;j<4;j++) v[j] = acc[i][j][r] + biasv[j];
        #pragma unroll
        for(int j=0;j<4;j++) pr[j] = __shfl_xor(v[j], 1);
        float s1 = 0.f, s2 = 0.f;
        #pragma unroll
        for(int j=0;j<4;j++){
          const float2 cs = tab[(size_t)tpos*32 + j*8 + (l16>>1)];
          const float e = mg * (v[j]*cs.x + sgn*pr[j]*cs.y);
          o4[j] = e; s1 += e; s2 += e*e;
        }
        #pragma unroll
        for(int mm=1;mm<16;mm<<=1){ s1 += __shfl_xor(s1,mm,64); s2 += __shfl_xor(s2,mm,64); }
        const float mean = s1*(1.f/HD);
        const float var  = s2*(1.f/HD) - mean*mean;
        const float rstd = rsqrtf(var + 1e-5f);
        if(row < M){
          h16* dst = OutB + ((size_t)h*SEQ + row)*HD;
          #pragma unroll
          for(int j=0;j<4;j++)
            dst[j*16 + l16] = (h16)(((o4[j]-mean)*rstd*gv[j] + bv[j])*scl);
        }
      }
    }
  } else {
    // ---- V path: bias, LDS transpose, coalesced vT[h][d][key] writes ----
    __syncthreads();
    #pragma unroll
    for(int i=0;i<4;i++)
      #pragma unroll
      for(int j=0;j<4;j++)
        #pragma unroll
        for(int r=0;r<4;r++){
          const int key = wm*64 + i*16 + l4*4 + r;
          smem[(wn*64 + j*16 + l16)*136 + key] = (h16)(acc[i][j][r] + biasv[j]);
        }
    __syncthreads();
    const int rowT = t>>1, dh = rowT & 63, hloc = rowT>>6;
    const int hglob = ((n0-1024)>>6) + hloc;
    const h16* src = &smem[rowT*136 + (t&1)*64];
    h16* dstv = vT + ((size_t)hglob*HD + dh)*SEQ + m0 + (t&1)*64;
    #pragma unroll
    for(int c=0;c<64;c+=4)
      *(h16x4*)(dstv+c) = *(const h16x4*)(src+c);
  }
}

// ---------------- zero-pad vT tail keys up to 64-boundary ----------------
__global__ void k_pad_vt(h16* __restrict__ vT, const int* __restrict__ skip_p){
  const int st = max(1, 4 - skip_p[0]);
  const int n_kv = (SEQ + st - 1)/st;
  const int kb = ((n_kv + 63)/64)*64;
  const int pad = min(kb, SEQ) - n_kv;
  if(pad <= 0) return;
  const int total = NH*HD*pad;
  for(int i = threadIdx.x; i < total; i += 256){
    const int key = n_kv + (i % pad);
    const int hd = i / pad;
    vT[(size_t)hd*SEQ + key] = (h16)0.f;
  }
}

// ---------------- flash attention: 64-q blocks, 16 q rows/wave ----------------
// grid (head=16, qblk=128): linear id = h + 16*qb -> XCD = h%8 -> 2 heads/XCD L2
__launch_bounds__(256)
__global__ void k_attn(const h16* __restrict__ qn, const h16* __restrict__ kn,
                       const h16* __restrict__ vT, h16* __restrict__ aout,
                       const int* __restrict__ skip_p){
  const int st = max(1, 4 - skip_p[0]);
  const int n_kv = (SEQ + st - 1)/st;
  const int h = blockIdx.x, q0 = blockIdx.y*64;
  const int w = threadIdx.x >> 6, l = threadIdx.x & 63;
  const int l4 = l >> 4, l16 = l & 15;
  __shared__ __align__(16) h16 P[4][16][68];   // stride 68: conflict-free b16 writes, 8B rows
  const h16* Qh = qn + (size_t)h*SEQ*HD;
  const h16* Kh = kn + (size_t)h*SEQ*HD;
  const h16* Vh = vT + (size_t)h*HD*SEQ;
  const int qrow = q0 + w*16 + l16;
  f16x8 qf[2];
  #pragma unroll
  for(int ks=0;ks<2;ks++)
    qf[ks] = *(const f16x8*)(Qh + (size_t)qrow*HD + ks*32 + l4*8);
  f32x4 o[4];
  float mrow[4], lrow[4];
  #pragma unroll
  for(int r=0;r<4;r++){ mrow[r] = -1e30f; lrow[r] = 0.f; }
  #pragma unroll
  for(int j=0;j<4;j++)
    #pragma unroll
    for(int r=0;r<4;r++) o[j][r] = 0.f;
  const int nkb = (n_kv + 63) >> 6;
  for(int kb=0; kb<nkb; kb++){
    const int kbase = kb*64;
    f32x4 S[4];
    #pragma unroll
    for(int j=0;j<4;j++)
      #pragma unroll
      for(int r=0;r<4;r++) S[j][r] = 0.f;
    __builtin_amdgcn_s_setprio(1);
    #pragma unroll
    for(int ks=0;ks<2;ks++){
      f16x8 kf[4];
      #pragma unroll
      for(int nj=0;nj<4;nj++)
        kf[nj] = *(const f16x8*)(Kh + (size_t)(kbase + nj*16 + l16)*HD + ks*32 + l4*8);
      #pragma unroll
      for(int nj=0;nj<4;nj++)
        S[nj] = __builtin_amdgcn_mfma_f32_16x16x32_f16(qf[ks], kf[nj], S[nj], 0,0,0);
    }
    __builtin_amdgcn_s_setprio(0);
    #pragma unroll
    for(int nj=0;nj<4;nj++){
      const int key = kbase + nj*16 + l16;
      if(key >= n_kv){
        #pragma unroll
        for(int r=0;r<4;r++) S[nj][r] = -1e30f;
      }
    }
    // online softmax, rows = l4*4+r; defer-max (THR=8) skips o-rescale
    #pragma unroll
    for(int r=0;r<4;r++){
      float mx = fmaxf(fmaxf(S[0][r],S[1][r]), fmaxf(S[2][r],S[3][r]));
      #pragma unroll
      for(int mm=1;mm<16;mm<<=1) mx = fmaxf(mx, __shfl_xor(mx,mm,64));
      if(!__all(mx <= mrow[r] + 8.f)){
        const float mnew = fmaxf(mrow[r], mx);
        const float fac = __expf(mrow[r] - mnew);
        mrow[r] = mnew;
        lrow[r] *= fac;
        #pragma unroll
        for(int j2=0;j2<4;j2++) o[j2][r] *= fac;
      }
      float rs = 0.f;
      #pragma unroll
      for(int nj=0;nj<4;nj++){
        const float p = __expf(S[nj][r] - mrow[r]);
        S[nj][r] = p; rs += p;
      }
      #pragma unroll
      for(int mm=1;mm<16;mm<<=1) rs += __shfl_xor(rs,mm,64);
      lrow[r] += rs;
    }
    #pragma unroll
    for(int nj=0;nj<4;nj++)
      #pragma unroll
      for(int r=0;r<4;r++)
        P[w][l4*4 + r][nj*16 + l16] = (h16)S[nj][r];
    asm volatile("s_waitcnt lgkmcnt(0)" ::: "memory");
    __builtin_amdgcn_sched_barrier(0);
    __builtin_amdgcn_s_setprio(1);
    #pragma unroll
    for(int ks=0;ks<2;ks++){
      const h16* pb = &P[w][l16][ks*32 + l4*8];
      const h16x4 plo = *(const h16x4*)pb;
      const h16x4 phi = *(const h16x4*)(pb + 4);
      f16x8 pf;
      pf[0]=plo[0]; pf[1]=plo[1]; pf[2]=plo[2]; pf[3]=plo[3];
      pf[4]=phi[0]; pf[5]=phi[1]; pf[6]=phi[2]; pf[7]=phi[3];
      #pragma unroll
      for(int j2=0;j2<4;j2++){
        const f16x8 vf = *(const f16x8*)(Vh + (size_t)(j2*16 + l16)*SEQ + kbase + ks*32 + l4*8);
        o[j2] = __builtin_amdgcn_mfma_f32_16x16x32_f16(pf, vf, o[j2], 0,0,0);
      }
    }
    __builtin_amdgcn_s_setprio(0);
  }
  #pragma unroll
  for(int r=0;r<4;r++){
    const float inv = 1.f/lrow[r];
    const int row = q0 + w*16 + l4*4 + r;
    #pragma unroll
    for(int j2=0;j2<4;j2++)
      aout[(size_t)row*DIMS + h*HD + j2*16 + l16] = (h16)(o[j2][r]*inv);
  }
}

// ---------------- launch ----------------
extern "C" void kernel_launch(void* const* d_in, const int* in_sizes, int n_in,
                              void* d_out, int out_size, void* d_ws, size_t ws_size,
                              hipStream_t stream){
  const float* x    = (const float*)d_in[0];
  const float* qn_g = (const float*)d_in[1];
  const float* qn_b = (const float*)d_in[2];
  const float* Wq   = (const float*)d_in[3];
  const float* bq   = (const float*)d_in[4];
  const float* kvn_g= (const float*)d_in[5];
  const float* kvn_b= (const float*)d_in[6];
  const float* Wkv  = (const float*)d_in[7];
  const float* bkv  = (const float*)d_in[8];
  const float* Wout = (const float*)d_in[9];
  const float* bout = (const float*)d_in[10];
  const float* ln_g = (const float*)d_in[11];
  const float* ln_b = (const float*)d_in[12];
  const int*  skip  = (const int*)d_in[13];

  // Workspace budget ~75 MB; refuse (clean fail, no OOB scribble) if undersized.
  if(ws_size < (size_t)79*1000*1000) return;

  char* p = (char*)d_ws;
  size_t off = 0;
  auto take = [&](size_t n)->char*{
    char* r = p + off; off = (off + n + 255) & ~(size_t)255; return r;
  };
  h16*    xhat = (h16*)   take((size_t)SEQ*DIMS*2);   // reused as abuf after kv GEMM
  float*  mag  = (float*) take((size_t)SEQ*4);
  float2* tab  = (float2*)take((size_t)SEQ*32*8);
  h16*    WqT  = (h16*)   take((size_t)1024*1024*2);
  h16*    WkvT = (h16*)   take((size_t)2048*1024*2);
  h16*    WoutT= (h16*)   take((size_t)1024*1024*2);
  float*  bqp  = (float*) take(1024*4);
  float*  bkvp = (float*) take(2048*4);
  h16*    qn   = (h16*)   take((size_t)NH*SEQ*HD*2);
  h16*    kn   = (h16*)   take((size_t)NH*SEQ*HD*2);
  h16*    vT   = (h16*)   take((size_t)NH*HD*SEQ*2);
  float*  part = (float*) take((size_t)16*2048*4);
  double* freq = (double*)take(32*8);
  h16*    abuf = xhat;   // alias: xhat dead after kv GEMM, attn writes after

  k_ln_stats<<<dim3(SEQ), dim3(256), 0, stream>>>(x, xhat, mag);
  k_freq<<<dim3(1), dim3(32), 0, stream>>>(freq);
  k_sincos<<<dim3(SEQ*32/256), dim3(256), 0, stream>>>(freq, tab);
  k_fold_part<<<dim3(4,16), dim3(256), 0, stream>>>(Wq, qn_b, part, 1024);
  k_fold_sum<<<dim3(4), dim3(256), 0, stream>>>(part, bq, bqp, 1024);
  k_fold_part<<<dim3(8,16), dim3(256), 0, stream>>>(Wkv, kvn_b, part, 2048);
  k_fold_sum<<<dim3(8), dim3(256), 0, stream>>>(part, bkv, bkvp, 2048);
  k_prep_w<<<dim3(16,16), dim3(256), 0, stream>>>(Wq,  qn_g,  WqT,  1024, 1024);
  k_prep_w<<<dim3(32,16), dim3(256), 0, stream>>>(Wkv, kvn_g, WkvT, 1024, 2048);
  k_prep_w<<<dim3(16,16), dim3(256), 0, stream>>>(Wout, nullptr, WoutT, 1024, 1024);
  k_gemm<1><<<dim3(8,64),  dim3(256), 0, stream>>>(xhat, WqT,  bqp, nullptr, qn, nullptr,
                                                   mag, tab, ln_g, ln_b, 1024, skip);
  k_gemm<2><<<dim3(16,64), dim3(256), 0, stream>>>(xhat, WkvT, bkvp, nullptr, kn, vT,
                                                   mag, tab, ln_g, ln_b, 2048, skip);
  k_pad_vt<<<dim3(1), dim3(256), 0, stream>>>(vT, skip);
  k_attn<<<dim3(16,128), dim3(256), 0, stream>>>(qn, kn, vT, abuf, skip);
  k_gemm<0><<<dim3(8,64), dim3(256), 0, stream>>>(abuf, WoutT, bout, (float*)d_out,
                                                  nullptr, nullptr, nullptr, nullptr,
                                                  nullptr, nullptr, 1024, skip);
}

// Round 7
// 392.841 us; speedup vs baseline: 1.5754x; 1.5447x over previous
//
#include <hip/hip_runtime.h>
#include <hip/hip_bf16.h>
#include <math.h>

#define SEQ 8192
#define DIMS 1024
#define NH 16
#define HD 64

typedef _Float16 h16;
typedef __attribute__((ext_vector_type(8))) _Float16 f16x8;
typedef __attribute__((ext_vector_type(4))) _Float16 h16x4;
typedef __attribute__((ext_vector_type(4))) float f32x4;

#if defined(__has_builtin)
#if __has_builtin(__builtin_amdgcn_global_load_lds)
#define USE_GLOAD 1
#endif
#endif
#ifndef USE_GLOAD
#define USE_GLOAD 0
#endif

#if USE_GLOAD
__device__ __forceinline__ void gload16(h16* lds, const h16* g){
  __builtin_amdgcn_global_load_lds((const __attribute__((address_space(1))) void*)g,
                                   (__attribute__((address_space(3))) void*)lds, 16, 0, 0);
}
#endif

// ---------------- LN stats over x: xhat (fp16) + mag ----------------
__global__ void k_ln_stats(const float* __restrict__ x, h16* __restrict__ xhat,
                           float* __restrict__ mag){
  const int row = blockIdx.x, t = threadIdx.x;
  float4 v = ((const float4*)(x + (size_t)row*DIMS))[t];
  float s = v.x+v.y+v.z+v.w;
  float s2 = v.x*v.x+v.y*v.y+v.z*v.z+v.w*v.w;
  #pragma unroll
  for(int m=1;m<64;m<<=1){ s += __shfl_xor(s,m,64); s2 += __shfl_xor(s2,m,64); }
  __shared__ float ls[4], ls2[4];
  const int wid = t>>6;
  if((t&63)==0){ ls[wid]=s; ls2[wid]=s2; }
  __syncthreads();
  s  = ls[0]+ls[1]+ls[2]+ls[3];
  s2 = ls2[0]+ls2[1]+ls2[2]+ls2[3];
  const float mean = s*(1.f/DIMS);
  const float var  = s2*(1.f/DIMS) - mean*mean;
  const float rstd = rsqrtf(var + 1e-5f);
  if(t==0) mag[row] = mean;
  h16x4 o;
  o[0] = (h16)((v.x-mean)*rstd); o[1] = (h16)((v.y-mean)*rstd);
  o[2] = (h16)((v.z-mean)*rstd); o[3] = (h16)((v.w-mean)*rstd);
  ((h16x4*)(xhat + (size_t)row*DIMS))[t] = o;
}

// ---------------- RoPE freqs (f64 pow, 32 threads once) ----------------
__global__ void k_freq(double* __restrict__ fr){
  const int d = threadIdx.x;
  if(d < 32) fr[d] = 0.2 * (pow(21.0, (double)d / 31.0) - 1.0);
}

// ---------------- cos/sin table: f64 range-reduce, f32 trig ----------------
__global__ void k_sincos(const double* __restrict__ fr, float2* __restrict__ tab){
  const int id = blockIdx.x*256 + threadIdx.x;   // 8192*32
  const int t = id >> 5, d = id & 31;
  const double ang = (double)t * fr[d];
  const double k = rint(ang * 0.15915494309189535);
  const float red = (float)(ang - k * 6.283185307179586);
  float s, c;
  __sincosf(red, &s, &c);
  tab[id] = make_float2(c, s);
}

// ------- deterministic two-stage bias fold: bias_out[j] = b0[j] + sum_i bln[i]*W[i][j] -------
__global__ void k_fold_part(const float* __restrict__ W, const float* __restrict__ bln,
                            float* __restrict__ part, const int C){
  const int j = blockIdx.x*256 + threadIdx.x;
  const int ib = blockIdx.y;                 // 16 chunks x 64 rows
  if(j >= C) return;
  float acc = 0.f;
  const int i0 = ib*64;
  #pragma unroll 4
  for(int i=i0;i<i0+64;i++) acc += bln[i]*W[(size_t)i*C + j];
  part[(size_t)ib*C + j] = acc;
}
__global__ void k_fold_sum(const float* __restrict__ part, const float* __restrict__ b0,
                           float* __restrict__ bias_out, const int C){
  const int j = blockIdx.x*256 + threadIdx.x;
  if(j >= C) return;
  float acc = b0[j];
  #pragma unroll
  for(int ib=0; ib<16; ib++) acc += part[(size_t)ib*C + j];
  bias_out[j] = acc;
}

// ------- weight prep: Wt[j][i] = g[i]*W[i][j] (fp16) -------
__global__ void k_prep_w(const float* __restrict__ W, const float* __restrict__ g,
                         h16* __restrict__ Wt, const int R, const int C){
  __shared__ float tile[64][65];
  const int c0 = blockIdx.x*64, r0 = blockIdx.y*64;
  const int t = threadIdx.x;
  const int cl = t & 63, rl0 = t >> 6;
  #pragma unroll
  for(int i=0;i<16;i++){
    const int r = rl0 + i*4;
    const float w = W[(size_t)(r0+r)*C + c0 + cl];
    const float gg = g ? g[r0+r] : 1.f;
    tile[r][cl] = w*gg;
  }
  __syncthreads();
  const int jl = t >> 2, ic = (t & 3)*16;
  h16* dst = Wt + (size_t)(c0+jl)*R + r0 + ic;
  #pragma unroll
  for(int i=0;i<16;i+=4){
    h16x4 o;
    o[0] = (h16)tile[ic+i+0][jl];
    o[1] = (h16)tile[ic+i+1][jl];
    o[2] = (h16)tile[ic+i+2][jl];
    o[3] = (h16)tile[ic+i+3][jl];
    *(h16x4*)(dst + i) = o;
  }
}

// MODE 0: plain f32 C=A@Bt+bias   (final out GEMM)
// MODE 1: Q GEMM, epilogue RoPE + head-LN -> OutB=qn (x0.125)
// MODE 2: KV GEMM (compacted strided rows); cols<1024: K path (RoPE+LN -> OutB=kn),
//         cols>=1024: V path (bias only, LDS transpose -> vT[h][d][key])
template<int MODE>
__global__ __launch_bounds__(256) void k_gemm(
    const h16* __restrict__ A, const h16* __restrict__ Bt,
    const float* __restrict__ bias, float* __restrict__ Cf,
    h16* __restrict__ OutB, h16* __restrict__ vT,
    const float* __restrict__ mag, const float2* __restrict__ tab,
    const float* __restrict__ lg, const float* __restrict__ lb,
    const int N, const int* __restrict__ skip_p){
  int M = SEQ, pitchA = DIMS, st = 1;
  if(MODE==2){
    st = max(1, 4 - skip_p[0]);
    M = (SEQ + st - 1)/st;
    pitchA = st*DIMS;
  }
  const int m0 = blockIdx.y*128, n0 = blockIdx.x*128;
  if(m0 >= M) return;
  __shared__ h16 smem[(MODE==2) ? 128*136 : 8192];
  h16* As = smem;
  h16* Bs = smem + 4096;
  const int t = threadIdx.x;
  const int w = t>>6, l = t&63, l4 = l>>4, l16 = l&15;
  const int wm = w>>1, wn = w&1;
  f32x4 acc[4][4];
  #pragma unroll
  for(int i=0;i<4;i++)
    #pragma unroll
    for(int j=0;j<4;j++)
      #pragma unroll
      for(int r=0;r<4;r++) acc[i][j][r] = 0.f;
  for(int k0=0;k0<1024;k0+=32){
    __syncthreads();
    #pragma unroll
    for(int c=t;c<512;c+=256){
      const int row = c>>2, kp = (c&3)*8;
      int ar = m0+row; if(ar > M-1) ar = M-1;
#if USE_GLOAD
      gload16(&As[row*32+kp], A + (size_t)ar*pitchA + k0 + kp);
      gload16(&Bs[row*32+kp], Bt + (size_t)(n0+row)*1024 + k0 + kp);
#else
      *(f16x8*)(&As[row*32+kp]) = *(const f16x8*)(A + (size_t)ar*pitchA + k0 + kp);
      *(f16x8*)(&Bs[row*32+kp]) = *(const f16x8*)(Bt + (size_t)(n0+row)*1024 + k0 + kp);
#endif
    }
    __syncthreads();
    f16x8 af[4], bfr[4];
    #pragma unroll
    for(int i=0;i<4;i++){
      af[i]  = *(const f16x8*)(&As[(wm*64 + i*16 + l16)*32 + l4*8]);
      bfr[i] = *(const f16x8*)(&Bs[(wn*64 + i*16 + l16)*32 + l4*8]);
    }
    #pragma unroll
    for(int i=0;i<4;i++)
      #pragma unroll
      for(int j=0;j<4;j++)
        acc[i][j] = __builtin_amdgcn_mfma_f32_16x16x32_f16(af[i], bfr[j], acc[i][j], 0,0,0);
  }

  if(MODE==0){
    #pragma unroll
    for(int i=0;i<4;i++){
      const int rb = m0 + wm*64 + i*16 + l4*4;
      #pragma unroll
      for(int j=0;j<4;j++){
        const int col = n0 + wn*64 + j*16 + l16;
        const float bb = bias[col];
        #pragma unroll
        for(int r=0;r<4;r++)
          Cf[(size_t)(rb+r)*N + col] = acc[i][j][r] + bb;
      }
    }
    return;
  }

  float biasv[4];
  #pragma unroll
  for(int j=0;j<4;j++) biasv[j] = bias[n0 + wn*64 + j*16 + l16];

  const bool vpath = (MODE==2) && (n0 >= 1024);
  if(!vpath){
    // ---- RoPE + per-head LN epilogue (Q or K) ----
    float gv[4], bv[4];
    #pragma unroll
    for(int j=0;j<4;j++){ gv[j] = lg[j*16+l16]; bv[j] = lb[j*16+l16]; }
    const int h = (n0>>6) + wn;
    const float scl = (MODE==1) ? 0.125f : 1.0f;
    const float sgn = (l16&1) ? 1.f : -1.f;
    #pragma unroll
    for(int i=0;i<4;i++){
      #pragma unroll
      for(int r=0;r<4;r++){
        int row = m0 + wm*64 + i*16 + l4*4 + r;
        const int rowc = (row < M) ? row : (M-1);
        const int tpos = (MODE==2) ? rowc*st : rowc;
        const float mg = mag[tpos];
        float v[4], pr[4], o4[4];
        #pragma unroll
        for(int j=0;j<4;j++) v[j] = acc[i][j][r] + biasv[j];
        #pragma unroll
        for(int j=0;j<4;j++) pr[j] = __shfl_xor(v[j], 1);
        float s1 = 0.f, s2 = 0.f;
        #pragma unroll
        for(int j=0;j<4;j++){
          const float2 cs = tab[(size_t)tpos*32 + j*8 + (l16>>1)];
          const float e = mg * (v[j]*cs.x + sgn*pr[j]*cs.y);
          o4[j] = e; s1 += e; s2 += e*e;
        }
        #pragma unroll
        for(int mm=1;mm<16;mm<<=1){ s1 += __shfl_xor(s1,mm,64); s2 += __shfl_xor(s2,mm,64); }
        const float mean = s1*(1.f/HD);
        const float var  = s2*(1.f/HD) - mean*mean;
        const float rstd = rsqrtf(var + 1e-5f);
        if(row < M){
          h16* dst = OutB + ((size_t)h*SEQ + row)*HD;
          #pragma unroll
          for(int j=0;j<4;j++)
            dst[j*16 + l16] = (h16)(((o4[j]-mean)*rstd*gv[j] + bv[j])*scl);
        }
      }
    }
  } else {
    // ---- V path: bias, LDS transpose, coalesced vT[h][d][key] writes ----
    __syncthreads();
    #pragma unroll
    for(int i=0;i<4;i++)
      #pragma unroll
      for(int j=0;j<4;j++)
        #pragma unroll
        for(int r=0;r<4;r++){
          const int key = wm*64 + i*16 + l4*4 + r;
          smem[(wn*64 + j*16 + l16)*136 + key] = (h16)(acc[i][j][r] + biasv[j]);
        }
    __syncthreads();
    const int rowT = t>>1, dh = rowT & 63, hloc = rowT>>6;
    const int hglob = ((n0-1024)>>6) + hloc;
    const h16* src = &smem[rowT*136 + (t&1)*64];
    h16* dstv = vT + ((size_t)hglob*HD + dh)*SEQ + m0 + (t&1)*64;
    #pragma unroll
    for(int c=0;c<64;c+=4)
      *(h16x4*)(dstv+c) = *(const h16x4*)(src+c);
  }
}

// ---------------- zero-pad vT tail keys up to 64-boundary ----------------
__global__ void k_pad_vt(h16* __restrict__ vT, const int* __restrict__ skip_p){
  const int st = max(1, 4 - skip_p[0]);
  const int n_kv = (SEQ + st - 1)/st;
  const int kb = ((n_kv + 63)/64)*64;
  const int pad = min(kb, SEQ) - n_kv;
  if(pad <= 0) return;
  const int total = NH*HD*pad;
  for(int i = threadIdx.x; i < total; i += 256){
    const int key = n_kv + (i % pad);
    const int hd = i / pad;
    vT[(size_t)hd*SEQ + key] = (h16)0.f;
  }
}

// ---------------- flash attention: swapped QK^T, 2 waves x 32 q-rows ----------------
// grid (head=16, qblk=128): linear id = h + 16*qb -> XCD = h%8 -> 2 heads/XCD L2
__launch_bounds__(128)
__global__ void k_attn(const h16* __restrict__ qn, const h16* __restrict__ kn,
                       const h16* __restrict__ vT, h16* __restrict__ aout,
                       const int* __restrict__ skip_p){
  const int st = max(1, 4 - skip_p[0]);
  const int n_kv = (SEQ + st - 1)/st;
  const int h = blockIdx.x, q0 = blockIdx.y*64;
  const int w = threadIdx.x >> 6, l = threadIdx.x & 63;
  const int l4 = l >> 4, l16 = l & 15;
  __shared__ __align__(16) h16 P[2][32][72];   // stride 72 h16 = 144 B: 16B-aligned, conflict-free
  const h16* Qh = qn + (size_t)h*SEQ*HD;
  const h16* Kh = kn + (size_t)h*SEQ*HD;
  const h16* Vh = vT + (size_t)h*HD*SEQ;
  f16x8 qf[2][2];
  #pragma unroll
  for(int mi=0;mi<2;mi++)
    #pragma unroll
    for(int ks=0;ks<2;ks++)
      qf[mi][ks] = *(const f16x8*)(Qh + (size_t)(q0 + w*32 + mi*16 + l16)*HD + ks*32 + l4*8);
  f32x4 o[2][4];
  float mrow[2], lrow[2];
  #pragma unroll
  for(int mi=0;mi<2;mi++){ mrow[mi] = -1e30f; lrow[mi] = 0.f; }
  #pragma unroll
  for(int mi=0;mi<2;mi++)
    #pragma unroll
    for(int j=0;j<4;j++)
      #pragma unroll
      for(int r=0;r<4;r++) o[mi][j][r] = 0.f;
  const int nkb = (n_kv + 63) >> 6;
  for(int kb=0; kb<nkb; kb++){
    const int kbase = kb*64;
    f32x4 S[2][4];
    #pragma unroll
    for(int mi=0;mi<2;mi++)
      #pragma unroll
      for(int j=0;j<4;j++)
        #pragma unroll
        for(int r=0;r<4;r++) S[mi][j][r] = 0.f;
    __builtin_amdgcn_s_setprio(1);
    #pragma unroll
    for(int ks=0;ks<2;ks++){
      f16x8 kf[4];
      #pragma unroll
      for(int nj=0;nj<4;nj++)
        kf[nj] = *(const f16x8*)(Kh + (size_t)(kbase + nj*16 + l16)*HD + ks*32 + l4*8);
      // swapped: A=K (rows=keys), B=Q (cols=q). Lane: q=l16 (lane-local softmax rows)
      #pragma unroll
      for(int mi=0;mi<2;mi++)
        #pragma unroll
        for(int nj=0;nj<4;nj++)
          S[mi][nj] = __builtin_amdgcn_mfma_f32_16x16x32_f16(kf[nj], qf[mi][ks], S[mi][nj], 0,0,0);
    }
    __builtin_amdgcn_s_setprio(0);
    // mask: lane's S rows are keys kbase + nj*16 + l4*4 + r
    #pragma unroll
    for(int nj=0;nj<4;nj++){
      const int keyb = kbase + nj*16 + l4*4;
      #pragma unroll
      for(int r=0;r<4;r++)
        if(keyb + r >= n_kv){ S[0][nj][r] = -1e30f; S[1][nj][r] = -1e30f; }
    }
    // softmax: per mi, lane owns q=mi*16+l16; 16 S-values local + 2 shuffles over l4 groups
    #pragma unroll
    for(int mi=0;mi<2;mi++){
      f32x4 t4;
      #pragma unroll
      for(int r=0;r<4;r++)
        t4[r] = fmaxf(fmaxf(S[mi][0][r],S[mi][1][r]), fmaxf(S[mi][2][r],S[mi][3][r]));
      float mx = fmaxf(fmaxf(t4[0],t4[1]), fmaxf(t4[2],t4[3]));
      mx = fmaxf(mx, __shfl_xor(mx,16,64));
      mx = fmaxf(mx, __shfl_xor(mx,32,64));
      if(!__all(mx <= mrow[mi] + 8.f)){     // defer-max THR=8
        const float mnew = fmaxf(mrow[mi], mx);
        const float fac = __expf(mrow[mi] - mnew);
        mrow[mi] = mnew;
        lrow[mi] *= fac;
        #pragma unroll
        for(int r=0;r<4;r++){
          const float f2 = __shfl(fac, (l & 48) | (l4*4 + r), 64);
          #pragma unroll
          for(int j2=0;j2<4;j2++) o[mi][j2][r] *= f2;
        }
      }
      float pr[4];
      #pragma unroll
      for(int nj=0;nj<4;nj++){
        #pragma unroll
        for(int r=0;r<4;r++)
          S[mi][nj][r] = __expf(S[mi][nj][r] - mrow[mi]);
        pr[nj] = (S[mi][nj][0]+S[mi][nj][1]) + (S[mi][nj][2]+S[mi][nj][3]);
      }
      float rs = (pr[0]+pr[1]) + (pr[2]+pr[3]);
      rs += __shfl_xor(rs,16,64);
      rs += __shfl_xor(rs,32,64);
      lrow[mi] += rs;
      // write P[q][key] (b64 per nj: 4 consecutive keys)
      #pragma unroll
      for(int nj=0;nj<4;nj++){
        h16x4 pw;
        pw[0]=(h16)S[mi][nj][0]; pw[1]=(h16)S[mi][nj][1];
        pw[2]=(h16)S[mi][nj][2]; pw[3]=(h16)S[mi][nj][3];
        *(h16x4*)(&P[w][mi*16+l16][nj*16+l4*4]) = pw;
      }
    }
    asm volatile("s_waitcnt lgkmcnt(0)" ::: "memory");
    __builtin_amdgcn_sched_barrier(0);
    __builtin_amdgcn_s_setprio(1);
    #pragma unroll
    for(int ks=0;ks<2;ks++){
      f16x8 pf[2];
      #pragma unroll
      for(int mi=0;mi<2;mi++)
        pf[mi] = *(const f16x8*)(&P[w][mi*16+l16][ks*32 + l4*8]);
      #pragma unroll
      for(int j2=0;j2<4;j2++){
        const f16x8 vf = *(const f16x8*)(Vh + (size_t)(j2*16 + l16)*SEQ + kbase + ks*32 + l4*8);
        #pragma unroll
        for(int mi=0;mi<2;mi++)
          o[mi][j2] = __builtin_amdgcn_mfma_f32_16x16x32_f16(pf[mi], vf, o[mi][j2], 0,0,0);
      }
    }
    __builtin_amdgcn_s_setprio(0);
  }
  // epilogue: o rows are q = mi*16 + l4*4 + r; fetch 1/l from lane holding that q (l16 = l4*4+r)
  #pragma unroll
  for(int mi=0;mi<2;mi++){
    const float inv = 1.f/lrow[mi];
    #pragma unroll
    for(int r=0;r<4;r++){
      const float iv = __shfl(inv, (l & 48) | (l4*4 + r), 64);
      const int row = q0 + w*32 + mi*16 + l4*4 + r;
      #pragma unroll
      for(int j2=0;j2<4;j2++)
        aout[(size_t)row*DIMS + h*HD + j2*16 + l16] = (h16)(o[mi][j2][r]*iv);
    }
  }
}

// ---------------- launch ----------------
extern "C" void kernel_launch(void* const* d_in, const int* in_sizes, int n_in,
                              void* d_out, int out_size, void* d_ws, size_t ws_size,
                              hipStream_t stream){
  const float* x    = (const float*)d_in[0];
  const float* qn_g = (const float*)d_in[1];
  const float* qn_b = (const float*)d_in[2];
  const float* Wq   = (const float*)d_in[3];
  const float* bq   = (const float*)d_in[4];
  const float* kvn_g= (const float*)d_in[5];
  const float* kvn_b= (const float*)d_in[6];
  const float* Wkv  = (const float*)d_in[7];
  const float* bkv  = (const float*)d_in[8];
  const float* Wout = (const float*)d_in[9];
  const float* bout = (const float*)d_in[10];
  const float* ln_g = (const float*)d_in[11];
  const float* ln_b = (const float*)d_in[12];
  const int*  skip  = (const int*)d_in[13];

  // Workspace budget ~75 MB; refuse (clean fail, no OOB scribble) if undersized.
  if(ws_size < (size_t)79*1000*1000) return;

  char* p = (char*)d_ws;
  size_t off = 0;
  auto take = [&](size_t n)->char*{
    char* r = p + off; off = (off + n + 255) & ~(size_t)255; return r;
  };
  h16*    xhat = (h16*)   take((size_t)SEQ*DIMS*2);   // reused as abuf after kv GEMM
  float*  mag  = (float*) take((size_t)SEQ*4);
  float2* tab  = (float2*)take((size_t)SEQ*32*8);
  h16*    WqT  = (h16*)   take((size_t)1024*1024*2);
  h16*    WkvT = (h16*)   take((size_t)2048*1024*2);
  h16*    WoutT= (h16*)   take((size_t)1024*1024*2);
  float*  bqp  = (float*) take(1024*4);
  float*  bkvp = (float*) take(2048*4);
  h16*    qn   = (h16*)   take((size_t)NH*SEQ*HD*2);
  h16*    kn   = (h16*)   take((size_t)NH*SEQ*HD*2);
  h16*    vT   = (h16*)   take((size_t)NH*HD*SEQ*2);
  float*  part = (float*) take((size_t)16*2048*4);
  double* freq = (double*)take(32*8);
  h16*    abuf = xhat;   // alias: xhat dead after kv GEMM, attn writes after

  k_ln_stats<<<dim3(SEQ), dim3(256), 0, stream>>>(x, xhat, mag);
  k_freq<<<dim3(1), dim3(32), 0, stream>>>(freq);
  k_sincos<<<dim3(SEQ*32/256), dim3(256), 0, stream>>>(freq, tab);
  k_fold_part<<<dim3(4,16), dim3(256), 0, stream>>>(Wq, qn_b, part, 1024);
  k_fold_sum<<<dim3(4), dim3(256), 0, stream>>>(part, bq, bqp, 1024);
  k_fold_part<<<dim3(8,16), dim3(256), 0, stream>>>(Wkv, kvn_b, part, 2048);
  k_fold_sum<<<dim3(8), dim3(256), 0, stream>>>(part, bkv, bkvp, 2048);
  k_prep_w<<<dim3(16,16), dim3(256), 0, stream>>>(Wq,  qn_g,  WqT,  1024, 1024);
  k_prep_w<<<dim3(32,16), dim3(256), 0, stream>>>(Wkv, kvn_g, WkvT, 1024, 2048);
  k_prep_w<<<dim3(16,16), dim3(256), 0, stream>>>(Wout, nullptr, WoutT, 1024, 1024);
  k_gemm<1><<<dim3(8,64),  dim3(256), 0, stream>>>(xhat, WqT,  bqp, nullptr, qn, nullptr,
                                                   mag, tab, ln_g, ln_b, 1024, skip);
  k_gemm<2><<<dim3(16,64), dim3(256), 0, stream>>>(xhat, WkvT, bkvp, nullptr, kn, vT,
                                                   mag, tab, ln_g, ln_b, 2048, skip);
  k_pad_vt<<<dim3(1), dim3(256), 0, stream>>>(vT, skip);
  k_attn<<<dim3(16,128), dim3(128), 0, stream>>>(qn, kn, vT, abuf, skip);
  k_gemm<0><<<dim3(8,64), dim3(256), 0, stream>>>(abuf, WoutT, bout, (float*)d_out,
                                                  nullptr, nullptr, nullptr, nullptr,
                                                  nullptr, nullptr, 1024, skip);
}

// Round 9
// 325.702 us; speedup vs baseline: 1.9001x; 1.2061x over previous
//
#include <hip/hip_runtime.h>
#include <hip/hip_bf16.h>
#include <math.h>

#define SEQ 8192
#define DIMS 1024
#define NH 16
#define HD 64

typedef _Float16 h16;
typedef __attribute__((ext_vector_type(8))) _Float16 f16x8;
typedef __attribute__((ext_vector_type(4))) _Float16 h16x4;
typedef __attribute__((ext_vector_type(4))) float f32x4;

#if defined(__has_builtin)
#if __has_builtin(__builtin_amdgcn_global_load_lds)
#define USE_GLOAD 1
#endif
#endif
#ifndef USE_GLOAD
#define USE_GLOAD 0
#endif

__device__ __forceinline__ void gload16(h16* lds, const h16* g){
#if USE_GLOAD
  __builtin_amdgcn_global_load_lds((const __attribute__((address_space(1))) void*)g,
                                   (__attribute__((address_space(3))) void*)lds, 16, 0, 0);
#endif
}

// ---------------- LN stats over x: xhat (fp16) + mag ----------------
__global__ void k_ln_stats(const float* __restrict__ x, h16* __restrict__ xhat,
                           float* __restrict__ mag){
  const int row = blockIdx.x, t = threadIdx.x;
  float4 v = ((const float4*)(x + (size_t)row*DIMS))[t];
  float s = v.x+v.y+v.z+v.w;
  float s2 = v.x*v.x+v.y*v.y+v.z*v.z+v.w*v.w;
  #pragma unroll
  for(int m=1;m<64;m<<=1){ s += __shfl_xor(s,m,64); s2 += __shfl_xor(s2,m,64); }
  __shared__ float ls[4], ls2[4];
  const int wid = t>>6;
  if((t&63)==0){ ls[wid]=s; ls2[wid]=s2; }
  __syncthreads();
  s  = ls[0]+ls[1]+ls[2]+ls[3];
  s2 = ls2[0]+ls2[1]+ls2[2]+ls2[3];
  const float mean = s*(1.f/DIMS);
  const float var  = s2*(1.f/DIMS) - mean*mean;
  const float rstd = rsqrtf(var + 1e-5f);
  if(t==0) mag[row] = mean;
  h16x4 o;
  o[0] = (h16)((v.x-mean)*rstd); o[1] = (h16)((v.y-mean)*rstd);
  o[2] = (h16)((v.z-mean)*rstd); o[3] = (h16)((v.w-mean)*rstd);
  ((h16x4*)(xhat + (size_t)row*DIMS))[t] = o;
}

// ---------------- RoPE freqs (f64 pow, 32 threads once) ----------------
__global__ void k_freq(double* __restrict__ fr){
  const int d = threadIdx.x;
  if(d < 32) fr[d] = 0.2 * (pow(21.0, (double)d / 31.0) - 1.0);
}

// ---------------- cos/sin table: f64 range-reduce, f32 trig ----------------
__global__ void k_sincos(const double* __restrict__ fr, float2* __restrict__ tab){
  const int id = blockIdx.x*256 + threadIdx.x;   // 8192*32
  const int t = id >> 5, d = id & 31;
  const double ang = (double)t * fr[d];
  const double k = rint(ang * 0.15915494309189535);
  const float red = (float)(ang - k * 6.283185307179586);
  float s, c;
  __sincosf(red, &s, &c);
  tab[id] = make_float2(c, s);
}

// ------- deterministic two-stage bias fold: bias_out[j] = b0[j] + sum_i bln[i]*W[i][j] -------
__global__ void k_fold_part(const float* __restrict__ W, const float* __restrict__ bln,
                            float* __restrict__ part, const int C){
  const int j = blockIdx.x*256 + threadIdx.x;
  const int ib = blockIdx.y;                 // 16 chunks x 64 rows
  if(j >= C) return;
  float acc = 0.f;
  const int i0 = ib*64;
  #pragma unroll 4
  for(int i=i0;i<i0+64;i++) acc += bln[i]*W[(size_t)i*C + j];
  part[(size_t)ib*C + j] = acc;
}
__global__ void k_fold_sum(const float* __restrict__ part, const float* __restrict__ b0,
                           float* __restrict__ bias_out, const int C){
  const int j = blockIdx.x*256 + threadIdx.x;
  if(j >= C) return;
  float acc = b0[j];
  #pragma unroll
  for(int ib=0; ib<16; ib++) acc += part[(size_t)ib*C + j];
  bias_out[j] = acc;
}

// ------- weight prep: Wt[j][i] = g[i]*W[i][j] (fp16) -------
__global__ void k_prep_w(const float* __restrict__ W, const float* __restrict__ g,
                         h16* __restrict__ Wt, const int R, const int C){
  __shared__ float tile[64][65];
  const int c0 = blockIdx.x*64, r0 = blockIdx.y*64;
  const int t = threadIdx.x;
  const int cl = t & 63, rl0 = t >> 6;
  #pragma unroll
  for(int i=0;i<16;i++){
    const int r = rl0 + i*4;
    const float w = W[(size_t)(r0+r)*C + c0 + cl];
    const float gg = g ? g[r0+r] : 1.f;
    tile[r][cl] = w*gg;
  }
  __syncthreads();
  const int jl = t >> 2, ic = (t & 3)*16;
  h16* dst = Wt + (size_t)(c0+jl)*R + r0 + ic;
  #pragma unroll
  for(int i=0;i<16;i+=4){
    h16x4 o;
    o[0] = (h16)tile[ic+i+0][jl];
    o[1] = (h16)tile[ic+i+1][jl];
    o[2] = (h16)tile[ic+i+2][jl];
    o[3] = (h16)tile[ic+i+3][jl];
    *(h16x4*)(dst + i) = o;
  }
}

// MODE 0: plain f32 C=A@Bt+bias   (final out GEMM)
// MODE 1: Q GEMM, epilogue RoPE + head-LN -> OutB=qn (x 0.125*log2e)
// MODE 2: KV GEMM (compacted strided rows); cols<1024: K path (RoPE+LN -> OutB=kn),
//         cols>=1024: V path (bias only, LDS transpose -> vT[h][d][key])
template<int MODE>
__global__ __launch_bounds__(256) void k_gemm(
    const h16* __restrict__ A, const h16* __restrict__ Bt,
    const float* __restrict__ bias, float* __restrict__ Cf,
    h16* __restrict__ OutB, h16* __restrict__ vT,
    const float* __restrict__ mag, const float2* __restrict__ tab,
    const float* __restrict__ lg, const float* __restrict__ lb,
    const int N, const int* __restrict__ skip_p){
  int M = SEQ, pitchA = DIMS, st = 1;
  if(MODE==2){
    st = max(1, 4 - skip_p[0]);
    M = (SEQ + st - 1)/st;
    pitchA = st*DIMS;
  }
  const int m0 = blockIdx.y*128, n0 = blockIdx.x*128;
  if(m0 >= M) return;
  __shared__ h16 smem[(MODE==2) ? 128*136 : 8192];
  h16* As = smem;
  h16* Bs = smem + 4096;
  const int t = threadIdx.x;
  const int w = t>>6, l = t&63, l4 = l>>4, l16 = l&15;
  const int wm = w>>1, wn = w&1;
  f32x4 acc[4][4];
  #pragma unroll
  for(int i=0;i<4;i++)
    #pragma unroll
    for(int j=0;j<4;j++)
      #pragma unroll
      for(int r=0;r<4;r++) acc[i][j][r] = 0.f;
  for(int k0=0;k0<1024;k0+=32){
    __syncthreads();
    #pragma unroll
    for(int c=t;c<512;c+=256){
      const int row = c>>2, kp = (c&3)*8;
      int ar = m0+row; if(ar > M-1) ar = M-1;
#if USE_GLOAD
      gload16(&As[row*32+kp], A + (size_t)ar*pitchA + k0 + kp);
      gload16(&Bs[row*32+kp], Bt + (size_t)(n0+row)*1024 + k0 + kp);
#else
      *(f16x8*)(&As[row*32+kp]) = *(const f16x8*)(A + (size_t)ar*pitchA + k0 + kp);
      *(f16x8*)(&Bs[row*32+kp]) = *(const f16x8*)(Bt + (size_t)(n0+row)*1024 + k0 + kp);
#endif
    }
    __syncthreads();
    f16x8 af[4], bfr[4];
    #pragma unroll
    for(int i=0;i<4;i++){
      af[i]  = *(const f16x8*)(&As[(wm*64 + i*16 + l16)*32 + l4*8]);
      bfr[i] = *(const f16x8*)(&Bs[(wn*64 + i*16 + l16)*32 + l4*8]);
    }
    #pragma unroll
    for(int i=0;i<4;i++)
      #pragma unroll
      for(int j=0;j<4;j++)
        acc[i][j] = __builtin_amdgcn_mfma_f32_16x16x32_f16(af[i], bfr[j], acc[i][j], 0,0,0);
  }

  if(MODE==0){
    #pragma unroll
    for(int i=0;i<4;i++){
      const int rb = m0 + wm*64 + i*16 + l4*4;
      #pragma unroll
      for(int j=0;j<4;j++){
        const int col = n0 + wn*64 + j*16 + l16;
        const float bb = bias[col];
        #pragma unroll
        for(int r=0;r<4;r++)
          Cf[(size_t)(rb+r)*N + col] = acc[i][j][r] + bb;
      }
    }
    return;
  }

  float biasv[4];
  #pragma unroll
  for(int j=0;j<4;j++) biasv[j] = bias[n0 + wn*64 + j*16 + l16];

  const bool vpath = (MODE==2) && (n0 >= 1024);
  if(!vpath){
    // ---- RoPE + per-head LN epilogue (Q or K) ----
    float gv[4], bv[4];
    #pragma unroll
    for(int j=0;j<4;j++){ gv[j] = lg[j*16+l16]; bv[j] = lb[j*16+l16]; }
    const int h = (n0>>6) + wn;
    const float scl = (MODE==1) ? 0.125f*1.44269504f : 1.0f;   // fold 1/sqrt(64) * log2(e)
    const float sgn = (l16&1) ? 1.f : -1.f;
    #pragma unroll
    for(int i=0;i<4;i++){
      #pragma unroll
      for(int r=0;r<4;r++){
        int row = m0 + wm*64 + i*16 + l4*4 + r;
        const int rowc = (row < M) ? row : (M-1);
        const int tpos = (MODE==2) ? rowc*st : rowc;
        const float mg = mag[tpos];
        float v[4], pr[4], o4[4];
        #pragma unroll
        for(int j=0;j<4;j++) v[j] = acc[i][j][r] + biasv[j];
        #pragma unroll
        for(int j=0;j<4;j++) pr[j] = __shfl_xor(v[j], 1);
        float s1 = 0.f, s2 = 0.f;
        #pragma unroll
        for(int j=0;j<4;j++){
          const float2 cs = tab[(size_t)tpos*32 + j*8 + (l16>>1)];
          const float e = mg * (v[j]*cs.x + sgn*pr[j]*cs.y);
          o4[j] = e; s1 += e; s2 += e*e;
        }
        #pragma unroll
        for(int mm=1;mm<16;mm<<=1){ s1 += __shfl_xor(s1,mm,64); s2 += __shfl_xor(s2,mm,64); }
        const float mean = s1*(1.f/HD);
        const float var  = s2*(1.f/HD) - mean*mean;
        const float rstd = rsqrtf(var + 1e-5f);
        if(row < M){
          h16* dst = OutB + ((size_t)h*SEQ + row)*HD;
          #pragma unroll
          for(int j=0;j<4;j++)
            dst[j*16 + l16] = (h16)(((o4[j]-mean)*rstd*gv[j] + bv[j])*scl);
        }
      }
    }
  } else {
    // ---- V path: bias, LDS transpose, coalesced vT[h][d][key] writes ----
    __syncthreads();
    #pragma unroll
    for(int i=0;i<4;i++)
      #pragma unroll
      for(int j=0;j<4;j++)
        #pragma unroll
        for(int r=0;r<4;r++){
          const int key = wm*64 + i*16 + l4*4 + r;
          smem[(wn*64 + j*16 + l16)*136 + key] = (h16)(acc[i][j][r] + biasv[j]);
        }
    __syncthreads();
    const int rowT = t>>1, dh = rowT & 63, hloc = rowT>>6;
    const int hglob = ((n0-1024)>>6) + hloc;
    const h16* src = &smem[rowT*136 + (t&1)*64];
    h16* dstv = vT + ((size_t)hglob*HD + dh)*SEQ + m0 + (t&1)*64;
    #pragma unroll
    for(int c=0;c<64;c+=4)
      *(h16x4*)(dstv+c) = *(const h16x4*)(src+c);
  }
}

// ---------------- zero-pad vT tail keys up to 64-boundary ----------------
__global__ void k_pad_vt(h16* __restrict__ vT, const int* __restrict__ skip_p){
  const int st = max(1, 4 - skip_p[0]);
  const int n_kv = (SEQ + st - 1)/st;
  const int kb = ((n_kv + 63)/64)*64;
  const int pad = min(kb, SEQ) - n_kv;
  if(pad <= 0) return;
  const int total = NH*HD*pad;
  for(int i = threadIdx.x; i < total; i += 256){
    const int key = n_kv + (i % pad);
    const int hd = i / pad;
    vT[(size_t)hd*SEQ + key] = (h16)0.f;
  }
}

// ---------------- flash attention: swapped QK^T, LDS-staged K/V, 4 waves x 32 q ----------------
// grid (head=16, qblk=64): linear id = h + 16*qb -> XCD = h&7 -> 2 heads/XCD L2
__launch_bounds__(256)
__global__ void k_attn(const h16* __restrict__ qn, const h16* __restrict__ kn,
                       const h16* __restrict__ vT, h16* __restrict__ aout,
                       const int* __restrict__ skip_p){
  const int st = max(1, 4 - skip_p[0]);
  const int n_kv = (SEQ + st - 1)/st;
  const int h = blockIdx.x, q0 = blockIdx.y*128;
  const int w = threadIdx.x >> 6, l = threadIdx.x & 63;
  const int l4 = l >> 4, l16 = l & 15;
  // LDS: K/V 64x64 tiles double-buffered, XOR-swizzled (col_byte ^= (row&7)<<4); P per wave (mi-split)
  __shared__ __align__(16) h16 Kl[2][64*64];
  __shared__ __align__(16) h16 Vl[2][64*64];
  __shared__ __align__(16) h16 Pl[4][16*64];
  const h16* Qh = qn + (size_t)h*SEQ*HD;
  const h16* Kh = kn + (size_t)h*SEQ*HD;
  const h16* Vh = vT + (size_t)h*HD*SEQ;
  // staging geometry: 8 rows x 128B per gload; swizzled GLOBAL source, linear LDS dest (rule 21)
  const int srow = l >> 3;
  const int scol = ((l & 7) << 4) ^ (srow << 4);   // byte offset within 128B row
  const int swz  = (l16 & 7) << 4;                 // read-side swizzle (byte)

  f16x8 qf[2][2];
  #pragma unroll
  for(int mi=0;mi<2;mi++)
    #pragma unroll
    for(int ks=0;ks<2;ks++)
      qf[mi][ks] = *(const f16x8*)(Qh + (size_t)(q0 + w*32 + mi*16 + l16)*HD + ks*32 + l4*8);
  f32x4 o[2][4];
  float mrow[2], lrow[2];
  #pragma unroll
  for(int mi=0;mi<2;mi++){ mrow[mi] = -1e30f; lrow[mi] = 0.f; }
  #pragma unroll
  for(int mi=0;mi<2;mi++)
    #pragma unroll
    for(int j=0;j<4;j++)
      #pragma unroll
      for(int r=0;r<4;r++) o[mi][j][r] = 0.f;

  const int nkb = (n_kv + 63) >> 6;
  int cur = 0;
  // prologue stage kb=0: wave w stages K rows w*16..+15 and V d-rows w*16..+15
  {
    const int r0 = w*16;
    gload16(&Kl[0][(r0+0)*64], (const h16*)((const char*)(Kh + (size_t)(r0+srow)*HD) + scol));
    gload16(&Kl[0][(r0+8)*64], (const h16*)((const char*)(Kh + (size_t)(r0+8+srow)*HD) + scol));
    gload16(&Vl[0][(r0+0)*64], (const h16*)((const char*)(Vh + (size_t)(r0+srow)*SEQ) + scol));
    gload16(&Vl[0][(r0+8)*64], (const h16*)((const char*)(Vh + (size_t)(r0+8+srow)*SEQ) + scol));
  }
  for(int kb=0; kb<nkb; kb++){
    asm volatile("s_waitcnt vmcnt(0)" ::: "memory");
    __syncthreads();
    if(kb+1 < nkb){
      const int kb2 = (kb+1)*64, r0 = w*16, nxt = cur^1;
      gload16(&Kl[nxt][(r0+0)*64], (const h16*)((const char*)(Kh + (size_t)(kb2+r0+srow)*HD) + scol));
      gload16(&Kl[nxt][(r0+8)*64], (const h16*)((const char*)(Kh + (size_t)(kb2+r0+8+srow)*HD) + scol));
      gload16(&Vl[nxt][(r0+0)*64], (const h16*)((const char*)(Vh + (size_t)(r0+srow)*SEQ + kb2) + scol));
      gload16(&Vl[nxt][(r0+8)*64], (const h16*)((const char*)(Vh + (size_t)(r0+8+srow)*SEQ + kb2) + scol));
    }
    const int kbase = kb*64;
    f32x4 S[2][4];
    #pragma unroll
    for(int mi=0;mi<2;mi++)
      #pragma unroll
      for(int j=0;j<4;j++)
        #pragma unroll
        for(int r=0;r<4;r++) S[mi][j][r] = 0.f;
    __builtin_amdgcn_s_setprio(1);
    #pragma unroll
    for(int ks=0;ks<2;ks++){
      f16x8 kf[4];
      #pragma unroll
      for(int nj=0;nj<4;nj++)
        kf[nj] = *(const f16x8*)((const char*)&Kl[cur][(nj*16+l16)*64] + ((ks*64 + l4*16) ^ swz));
      #pragma unroll
      for(int mi=0;mi<2;mi++)
        #pragma unroll
        for(int nj=0;nj<4;nj++)
          S[mi][nj] = __builtin_amdgcn_mfma_f32_16x16x32_f16(kf[nj], qf[mi][ks], S[mi][nj], 0,0,0);
    }
    __builtin_amdgcn_s_setprio(0);
    // mask tail keys (rows of swapped-C are keys: kbase + nj*16 + l4*4 + r)
    #pragma unroll
    for(int nj=0;nj<4;nj++){
      const int keyb = kbase + nj*16 + l4*4;
      #pragma unroll
      for(int r=0;r<4;r++)
        if(keyb + r >= n_kv){ S[0][nj][r] = -1e30f; S[1][nj][r] = -1e30f; }
    }
    // softmax (log2 domain, exp2f native); per mi, lane owns q=mi*16+l16
    #pragma unroll
    for(int mi=0;mi<2;mi++){
      f32x4 t4;
      #pragma unroll
      for(int r=0;r<4;r++)
        t4[r] = fmaxf(fmaxf(S[mi][0][r],S[mi][1][r]), fmaxf(S[mi][2][r],S[mi][3][r]));
      float mx = fmaxf(fmaxf(t4[0],t4[1]), fmaxf(t4[2],t4[3]));
      mx = fmaxf(mx, __shfl_xor(mx,16,64));
      mx = fmaxf(mx, __shfl_xor(mx,32,64));
      if(!__all(mx <= mrow[mi] + 11.5f)){     // defer-max, THR ~ 8 nats in log2 units
        const float mnew = fmaxf(mrow[mi], mx);
        const float fac = exp2f(mrow[mi] - mnew);
        mrow[mi] = mnew;
        lrow[mi] *= fac;
        #pragma unroll
        for(int r=0;r<4;r++){
          const float f2 = __shfl(fac, (l & 48) | (l4*4 + r), 64);
          #pragma unroll
          for(int j2=0;j2<4;j2++) o[mi][j2][r] *= f2;
        }
      }
      float pr[4];
      #pragma unroll
      for(int nj=0;nj<4;nj++){
        #pragma unroll
        for(int r=0;r<4;r++)
          S[mi][nj][r] = exp2f(S[mi][nj][r] - mrow[mi]);
        pr[nj] = (S[mi][nj][0]+S[mi][nj][1]) + (S[mi][nj][2]+S[mi][nj][3]);
      }
      float rs = (pr[0]+pr[1]) + (pr[2]+pr[3]);
      rs += __shfl_xor(rs,16,64);
      rs += __shfl_xor(rs,32,64);
      lrow[mi] += rs;
    }
    // per-mi: P write (swizzled) -> lgkm -> PV from Vl[cur]
    #pragma unroll
    for(int mi=0;mi<2;mi++){
      #pragma unroll
      for(int nj=0;nj<4;nj++){
        h16x4 pw;
        pw[0]=(h16)S[mi][nj][0]; pw[1]=(h16)S[mi][nj][1];
        pw[2]=(h16)S[mi][nj][2]; pw[3]=(h16)S[mi][nj][3];
        *(h16x4*)((char*)&Pl[w][l16*64] + ((nj*32 + l4*8) ^ swz)) = pw;
      }
      asm volatile("s_waitcnt lgkmcnt(0)" ::: "memory");
      __builtin_amdgcn_sched_barrier(0);
      __builtin_amdgcn_s_setprio(1);
      #pragma unroll
      for(int ks=0;ks<2;ks++){
        const f16x8 pf = *(const f16x8*)((const char*)&Pl[w][l16*64] + ((ks*64 + l4*16) ^ swz));
        #pragma unroll
        for(int j2=0;j2<4;j2++){
          const f16x8 vf = *(const f16x8*)((const char*)&Vl[cur][(j2*16+l16)*64] + ((ks*64 + l4*16) ^ swz));
          o[mi][j2] = __builtin_amdgcn_mfma_f32_16x16x32_f16(pf, vf, o[mi][j2], 0,0,0);
        }
      }
      __builtin_amdgcn_s_setprio(0);
    }
    cur ^= 1;
  }
  // epilogue: o rows are q = mi*16 + l4*4 + r; fetch 1/l from lane l16 = l4*4+r
  #pragma unroll
  for(int mi=0;mi<2;mi++){
    const float inv = 1.f/lrow[mi];
    #pragma unroll
    for(int r=0;r<4;r++){
      const float iv = __shfl(inv, (l & 48) | (l4*4 + r), 64);
      const int row = q0 + w*32 + mi*16 + l4*4 + r;
      #pragma unroll
      for(int j2=0;j2<4;j2++)
        aout[(size_t)row*DIMS + h*HD + j2*16 + l16] = (h16)(o[mi][j2][r]*iv);
    }
  }
}

// ---------------- launch ----------------
extern "C" void kernel_launch(void* const* d_in, const int* in_sizes, int n_in,
                              void* d_out, int out_size, void* d_ws, size_t ws_size,
                              hipStream_t stream){
  const float* x    = (const float*)d_in[0];
  const float* qn_g = (const float*)d_in[1];
  const float* qn_b = (const float*)d_in[2];
  const float* Wq   = (const float*)d_in[3];
  const float* bq   = (const float*)d_in[4];
  const float* kvn_g= (const float*)d_in[5];
  const float* kvn_b= (const float*)d_in[6];
  const float* Wkv  = (const float*)d_in[7];
  const float* bkv  = (const float*)d_in[8];
  const float* Wout = (const float*)d_in[9];
  const float* bout = (const float*)d_in[10];
  const float* ln_g = (const float*)d_in[11];
  const float* ln_b = (const float*)d_in[12];
  const int*  skip  = (const int*)d_in[13];

  // Workspace budget ~75 MB; refuse (clean fail, no OOB scribble) if undersized.
  if(ws_size < (size_t)79*1000*1000) return;

  char* p = (char*)d_ws;
  size_t off = 0;
  auto take = [&](size_t n)->char*{
    char* r = p + off; off = (off + n + 255) & ~(size_t)255; return r;
  };
  h16*    xhat = (h16*)   take((size_t)SEQ*DIMS*2);   // reused as abuf after kv GEMM
  float*  mag  = (float*) take((size_t)SEQ*4);
  float2* tab  = (float2*)take((size_t)SEQ*32*8);
  h16*    WqT  = (h16*)   take((size_t)1024*1024*2);
  h16*    WkvT = (h16*)   take((size_t)2048*1024*2);
  h16*    WoutT= (h16*)   take((size_t)1024*1024*2);
  float*  bqp  = (float*) take(1024*4);
  float*  bkvp = (float*) take(2048*4);
  h16*    qn   = (h16*)   take((size_t)NH*SEQ*HD*2);
  h16*    kn   = (h16*)   take((size_t)NH*SEQ*HD*2);
  h16*    vT   = (h16*)   take((size_t)NH*HD*SEQ*2);
  float*  part = (float*) take((size_t)16*2048*4);
  double* freq = (double*)take(32*8);
  h16*    abuf = xhat;   // alias: xhat dead after kv GEMM, attn writes after

  k_ln_stats<<<dim3(SEQ), dim3(256), 0, stream>>>(x, xhat, mag);
  k_freq<<<dim3(1), dim3(32), 0, stream>>>(freq);
  k_sincos<<<dim3(SEQ*32/256), dim3(256), 0, stream>>>(freq, tab);
  k_fold_part<<<dim3(4,16), dim3(256), 0, stream>>>(Wq, qn_b, part, 1024);
  k_fold_sum<<<dim3(4), dim3(256), 0, stream>>>(part, bq, bqp, 1024);
  k_fold_part<<<dim3(8,16), dim3(256), 0, stream>>>(Wkv, kvn_b, part, 2048);
  k_fold_sum<<<dim3(8), dim3(256), 0, stream>>>(part, bkv, bkvp, 2048);
  k_prep_w<<<dim3(16,16), dim3(256), 0, stream>>>(Wq,  qn_g,  WqT,  1024, 1024);
  k_prep_w<<<dim3(32,16), dim3(256), 0, stream>>>(Wkv, kvn_g, WkvT, 1024, 2048);
  k_prep_w<<<dim3(16,16), dim3(256), 0, stream>>>(Wout, nullptr, WoutT, 1024, 1024);
  k_gemm<1><<<dim3(8,64),  dim3(256), 0, stream>>>(xhat, WqT,  bqp, nullptr, qn, nullptr,
                                                   mag, tab, ln_g, ln_b, 1024, skip);
  k_gemm<2><<<dim3(16,64), dim3(256), 0, stream>>>(xhat, WkvT, bkvp, nullptr, kn, vT,
                                                   mag, tab, ln_g, ln_b, 2048, skip);
  k_pad_vt<<<dim3(1), dim3(256), 0, stream>>>(vT, skip);
  k_attn<<<dim3(16,64), dim3(256), 0, stream>>>(qn, kn, vT, abuf, skip);
  k_gemm<0><<<dim3(8,64), dim3(256), 0, stream>>>(abuf, WoutT, bout, (float*)d_out,
                                                  nullptr, nullptr, nullptr, nullptr,
                                                  nullptr, nullptr, 1024, skip);
}

// Round 12
// 297.870 us; speedup vs baseline: 2.0777x; 1.0934x over previous
//
#include <hip/hip_runtime.h>
#include <hip/hip_bf16.h>
#include <math.h>

#define SEQ 8192
#define DIMS 1024
#define NH 16
#define HD 64

typedef _Float16 h16;
typedef __attribute__((ext_vector_type(8))) _Float16 f16x8;
typedef __attribute__((ext_vector_type(4))) _Float16 h16x4;
typedef __attribute__((ext_vector_type(4))) float f32x4;

#if defined(__has_builtin)
#if __has_builtin(__builtin_amdgcn_global_load_lds)
#define USE_GLOAD 1
#endif
#endif
#ifndef USE_GLOAD
#define USE_GLOAD 0
#endif

__device__ __forceinline__ void gload16(h16* lds, const h16* g){
#if USE_GLOAD
  __builtin_amdgcn_global_load_lds((const __attribute__((address_space(1))) void*)g,
                                   (__attribute__((address_space(3))) void*)lds, 16, 0, 0);
#endif
}

// ---------------- LN stats over x: xhat (fp16) + mag ----------------
__global__ void k_ln_stats(const float* __restrict__ x, h16* __restrict__ xhat,
                           float* __restrict__ mag){
  const int row = blockIdx.x, t = threadIdx.x;
  float4 v = ((const float4*)(x + (size_t)row*DIMS))[t];
  float s = v.x+v.y+v.z+v.w;
  float s2 = v.x*v.x+v.y*v.y+v.z*v.z+v.w*v.w;
  #pragma unroll
  for(int m=1;m<64;m<<=1){ s += __shfl_xor(s,m,64); s2 += __shfl_xor(s2,m,64); }
  __shared__ float ls[4], ls2[4];
  const int wid = t>>6;
  if((t&63)==0){ ls[wid]=s; ls2[wid]=s2; }
  __syncthreads();
  s  = ls[0]+ls[1]+ls[2]+ls[3];
  s2 = ls2[0]+ls2[1]+ls2[2]+ls2[3];
  const float mean = s*(1.f/DIMS);
  const float var  = s2*(1.f/DIMS) - mean*mean;
  const float rstd = rsqrtf(var + 1e-5f);
  if(t==0) mag[row] = mean;
  h16x4 o;
  o[0] = (h16)((v.x-mean)*rstd); o[1] = (h16)((v.y-mean)*rstd);
  o[2] = (h16)((v.z-mean)*rstd); o[3] = (h16)((v.w-mean)*rstd);
  ((h16x4*)(xhat + (size_t)row*DIMS))[t] = o;
}

// ---------------- RoPE freqs (f64 pow, 32 threads once) ----------------
__global__ void k_freq(double* __restrict__ fr){
  const int d = threadIdx.x;
  if(d < 32) fr[d] = 0.2 * (pow(21.0, (double)d / 31.0) - 1.0);
}

// ---------------- cos/sin table: f64 range-reduce, f32 trig ----------------
__global__ void k_sincos(const double* __restrict__ fr, float2* __restrict__ tab){
  const int id = blockIdx.x*256 + threadIdx.x;   // 8192*32
  const int t = id >> 5, d = id & 31;
  const double ang = (double)t * fr[d];
  const double k = rint(ang * 0.15915494309189535);
  const float red = (float)(ang - k * 6.283185307179586);
  float s, c;
  __sincosf(red, &s, &c);
  tab[id] = make_float2(c, s);
}

// ------- deterministic two-stage bias fold: bias_out[j] = b0[j] + sum_i bln[i]*W[i][j] -------
__global__ void k_fold_part(const float* __restrict__ W, const float* __restrict__ bln,
                            float* __restrict__ part, const int C){
  const int j = blockIdx.x*256 + threadIdx.x;
  const int ib = blockIdx.y;                 // 16 chunks x 64 rows
  if(j >= C) return;
  float acc = 0.f;
  const int i0 = ib*64;
  #pragma unroll 4
  for(int i=i0;i<i0+64;i++) acc += bln[i]*W[(size_t)i*C + j];
  part[(size_t)ib*C + j] = acc;
}
__global__ void k_fold_sum(const float* __restrict__ part, const float* __restrict__ b0,
                           float* __restrict__ bias_out, const int C){
  const int j = blockIdx.x*256 + threadIdx.x;
  if(j >= C) return;
  float acc = b0[j];
  #pragma unroll
  for(int ib=0; ib<16; ib++) acc += part[(size_t)ib*C + j];
  bias_out[j] = acc;
}

// ------- weight prep: Wt[j][i] = g[i]*W[i][j] (fp16) -------
__global__ void k_prep_w(const float* __restrict__ W, const float* __restrict__ g,
                         h16* __restrict__ Wt, const int R, const int C){
  __shared__ float tile[64][65];
  const int c0 = blockIdx.x*64, r0 = blockIdx.y*64;
  const int t = threadIdx.x;
  const int cl = t & 63, rl0 = t >> 6;
  #pragma unroll
  for(int i=0;i<16;i++){
    const int r = rl0 + i*4;
    const float w = W[(size_t)(r0+r)*C + c0 + cl];
    const float gg = g ? g[r0+r] : 1.f;
    tile[r][cl] = w*gg;
  }
  __syncthreads();
  const int jl = t >> 2, ic = (t & 3)*16;
  h16* dst = Wt + (size_t)(c0+jl)*R + r0 + ic;
  #pragma unroll
  for(int i=0;i<16;i+=4){
    h16x4 o;
    o[0] = (h16)tile[ic+i+0][jl];
    o[1] = (h16)tile[ic+i+1][jl];
    o[2] = (h16)tile[ic+i+2][jl];
    o[3] = (h16)tile[ic+i+3][jl];
    *(h16x4*)(dst + i) = o;
  }
}

// MODE 0: plain f32 C=A@Bt+bias   (final out GEMM)
// MODE 1: Q GEMM, epilogue RoPE + head-LN -> OutB=qn (x 0.125*log2e)
// MODE 2: KV GEMM (compacted strided rows); cols<1024: K path (RoPE+LN -> OutB=kn),
//         cols>=1024: V path (bias only, LDS transpose -> vT[h][d][key])
template<int MODE>
__global__ __launch_bounds__(256) void k_gemm(
    const h16* __restrict__ A, const h16* __restrict__ Bt,
    const float* __restrict__ bias, float* __restrict__ Cf,
    h16* __restrict__ OutB, h16* __restrict__ vT,
    const float* __restrict__ mag, const float2* __restrict__ tab,
    const float* __restrict__ lg, const float* __restrict__ lb,
    const int N, const int* __restrict__ skip_p){
  int M = SEQ, pitchA = DIMS, st = 1;
  if(MODE==2){
    st = max(1, 4 - skip_p[0]);
    M = (SEQ + st - 1)/st;
    pitchA = st*DIMS;
  }
  const int m0 = blockIdx.y*128, n0 = blockIdx.x*128;
  if(m0 >= M) return;
  __shared__ h16 smem[(MODE==2) ? 128*136 : 8192];
  h16* As = smem;
  h16* Bs = smem + 4096;
  const int t = threadIdx.x;
  const int w = t>>6, l = t&63, l4 = l>>4, l16 = l&15;
  const int wm = w>>1, wn = w&1;
  f32x4 acc[4][4];
  #pragma unroll
  for(int i=0;i<4;i++)
    #pragma unroll
    for(int j=0;j<4;j++)
      #pragma unroll
      for(int r=0;r<4;r++) acc[i][j][r] = 0.f;
  for(int k0=0;k0<1024;k0+=32){
    __syncthreads();
    #pragma unroll
    for(int c=t;c<512;c+=256){
      const int row = c>>2, kp = (c&3)*8;
      int ar = m0+row; if(ar > M-1) ar = M-1;
#if USE_GLOAD
      gload16(&As[row*32+kp], A + (size_t)ar*pitchA + k0 + kp);
      gload16(&Bs[row*32+kp], Bt + (size_t)(n0+row)*1024 + k0 + kp);
#else
      *(f16x8*)(&As[row*32+kp]) = *(const f16x8*)(A + (size_t)ar*pitchA + k0 + kp);
      *(f16x8*)(&Bs[row*32+kp]) = *(const f16x8*)(Bt + (size_t)(n0+row)*1024 + k0 + kp);
#endif
    }
    __syncthreads();
    f16x8 af[4], bfr[4];
    #pragma unroll
    for(int i=0;i<4;i++){
      af[i]  = *(const f16x8*)(&As[(wm*64 + i*16 + l16)*32 + l4*8]);
      bfr[i] = *(const f16x8*)(&Bs[(wn*64 + i*16 + l16)*32 + l4*8]);
    }
    #pragma unroll
    for(int i=0;i<4;i++)
      #pragma unroll
      for(int j=0;j<4;j++)
        acc[i][j] = __builtin_amdgcn_mfma_f32_16x16x32_f16(af[i], bfr[j], acc[i][j], 0,0,0);
  }

  if(MODE==0){
    #pragma unroll
    for(int i=0;i<4;i++){
      const int rb = m0 + wm*64 + i*16 + l4*4;
      #pragma unroll
      for(int j=0;j<4;j++){
        const int col = n0 + wn*64 + j*16 + l16;
        const float bb = bias[col];
        #pragma unroll
        for(int r=0;r<4;r++)
          Cf[(size_t)(rb+r)*N + col] = acc[i][j][r] + bb;
      }
    }
    return;
  }

  float biasv[4];
  #pragma unroll
  for(int j=0;j<4;j++) biasv[j] = bias[n0 + wn*64 + j*16 + l16];

  const bool vpath = (MODE==2) && (n0 >= 1024);
  if(!vpath){
    // ---- RoPE + per-head LN epilogue (Q or K) ----
    float gv[4], bv[4];
    #pragma unroll
    for(int j=0;j<4;j++){ gv[j] = lg[j*16+l16]; bv[j] = lb[j*16+l16]; }
    const int h = (n0>>6) + wn;
    const float scl = (MODE==1) ? 0.125f*1.44269504f : 1.0f;   // fold 1/sqrt(64) * log2(e)
    const float sgn = (l16&1) ? 1.f : -1.f;
    #pragma unroll
    for(int i=0;i<4;i++){
      #pragma unroll
      for(int r=0;r<4;r++){
        int row = m0 + wm*64 + i*16 + l4*4 + r;
        const int rowc = (row < M) ? row : (M-1);
        const int tpos = (MODE==2) ? rowc*st : rowc;
        const float mg = mag[tpos];
        float v[4], pr[4], o4[4];
        #pragma unroll
        for(int j=0;j<4;j++) v[j] = acc[i][j][r] + biasv[j];
        #pragma unroll
        for(int j=0;j<4;j++) pr[j] = __shfl_xor(v[j], 1);
        float s1 = 0.f, s2 = 0.f;
        #pragma unroll
        for(int j=0;j<4;j++){
          const float2 cs = tab[(size_t)tpos*32 + j*8 + (l16>>1)];
          const float e = mg * (v[j]*cs.x + sgn*pr[j]*cs.y);
          o4[j] = e; s1 += e; s2 += e*e;
        }
        #pragma unroll
        for(int mm=1;mm<16;mm<<=1){ s1 += __shfl_xor(s1,mm,64); s2 += __shfl_xor(s2,mm,64); }
        const float mean = s1*(1.f/HD);
        const float var  = s2*(1.f/HD) - mean*mean;
        const float rstd = rsqrtf(var + 1e-5f);
        if(row < M){
          h16* dst = OutB + ((size_t)h*SEQ + row)*HD;
          #pragma unroll
          for(int j=0;j<4;j++)
            dst[j*16 + l16] = (h16)(((o4[j]-mean)*rstd*gv[j] + bv[j])*scl);
        }
      }
    }
  } else {
    // ---- V path: bias, LDS transpose, coalesced vT[h][d][key] writes ----
    __syncthreads();
    #pragma unroll
    for(int i=0;i<4;i++)
      #pragma unroll
      for(int j=0;j<4;j++)
        #pragma unroll
        for(int r=0;r<4;r++){
          const int key = wm*64 + i*16 + l4*4 + r;
          smem[(wn*64 + j*16 + l16)*136 + key] = (h16)(acc[i][j][r] + biasv[j]);
        }
    __syncthreads();
    const int rowT = t>>1, dh = rowT & 63, hloc = rowT>>6;
    const int hglob = ((n0-1024)>>6) + hloc;
    const h16* src = &smem[rowT*136 + (t&1)*64];
    h16* dstv = vT + ((size_t)hglob*HD + dh)*SEQ + m0 + (t&1)*64;
    #pragma unroll
    for(int c=0;c<64;c+=4)
      *(h16x4*)(dstv+c) = *(const h16x4*)(src+c);
  }
}

// ---------------- zero-pad vT tail keys up to 64-boundary ----------------
__global__ void k_pad_vt(h16* __restrict__ vT, const int* __restrict__ skip_p){
  const int st = max(1, 4 - skip_p[0]);
  const int n_kv = (SEQ + st - 1)/st;
  const int kb = ((n_kv + 63)/64)*64;
  const int pad = min(kb, SEQ) - n_kv;
  if(pad <= 0) return;
  const int total = NH*HD*pad;
  for(int i = threadIdx.x; i < total; i += 256){
    const int key = n_kv + (i % pad);
    const int hd = i / pad;
    vT[(size_t)hd*SEQ + key] = (h16)0.f;
  }
}

// ---------------- flash attention: round-9 sync skeleton + pure-arith deltas ----------------
// grid (head=16, qblk=64): linear id = h + 16*qb -> XCD = h&7 -> 2 heads/XCD L2
__launch_bounds__(256)
__global__ void k_attn(const h16* __restrict__ qn, const h16* __restrict__ kn,
                       const h16* __restrict__ vT, h16* __restrict__ aout,
                       const int* __restrict__ skip_p){
  const int st = max(1, 4 - skip_p[0]);
  const int n_kv = (SEQ + st - 1)/st;
  const int h = blockIdx.x, q0 = blockIdx.y*128;
  const int w = threadIdx.x >> 6, l = threadIdx.x & 63;
  const int l4 = l >> 4, l16 = l & 15;
  __shared__ __align__(16) h16 Kl[2][64*64];
  __shared__ __align__(16) h16 Vl[2][64*64];
  __shared__ __align__(16) h16 Pl[4][16*64];   // per-wave, per-mi overwrite (round-9 verified)
  const h16* Qh = qn + (size_t)h*SEQ*HD;
  const h16* Kh = kn + (size_t)h*SEQ*HD;
  const h16* Vh = vT + (size_t)h*HD*SEQ;
  // staging geometry: 8 rows x 128B per gload; swizzled GLOBAL source, linear LDS dest (rule 21)
  const int srow = l >> 3;
  const int scol = ((l & 7) << 4) ^ (srow << 4);   // byte offset within 128B row
  const int swz  = (l16 & 7) << 4;                 // read-side swizzle (byte)

  f16x8 onesv;
  #pragma unroll
  for(int i=0;i<8;i++) onesv[i] = (h16)1.f;

  f16x8 qf[2][2];
  #pragma unroll
  for(int mi=0;mi<2;mi++)
    #pragma unroll
    for(int ks=0;ks<2;ks++)
      qf[mi][ks] = *(const f16x8*)(Qh + (size_t)(q0 + w*32 + mi*16 + l16)*HD + ks*32 + l4*8);
  f32x4 o[2][4], osum[2];
  float mrow[2];
  #pragma unroll
  for(int mi=0;mi<2;mi++){
    mrow[mi] = -1e30f;
    #pragma unroll
    for(int r=0;r<4;r++) osum[mi][r] = 0.f;
    #pragma unroll
    for(int j=0;j<4;j++)
      #pragma unroll
      for(int r=0;r<4;r++) o[mi][j][r] = 0.f;
  }

  const int nkb = (n_kv + 63) >> 6;
  int cur = 0;
  {
    const int r0 = w*16;
    gload16(&Kl[0][(r0+0)*64], (const h16*)((const char*)(Kh + (size_t)(r0+srow)*HD) + scol));
    gload16(&Kl[0][(r0+8)*64], (const h16*)((const char*)(Kh + (size_t)(r0+8+srow)*HD) + scol));
    gload16(&Vl[0][(r0+0)*64], (const h16*)((const char*)(Vh + (size_t)(r0+srow)*SEQ) + scol));
    gload16(&Vl[0][(r0+8)*64], (const h16*)((const char*)(Vh + (size_t)(r0+8+srow)*SEQ) + scol));
  }
  for(int kb=0; kb<nkb; kb++){
    asm volatile("s_waitcnt vmcnt(0)" ::: "memory");
    __syncthreads();
    if(kb+1 < nkb){
      const int kb2 = (kb+1)*64, r0 = w*16, nxt = cur^1;
      gload16(&Kl[nxt][(r0+0)*64], (const h16*)((const char*)(Kh + (size_t)(kb2+r0+srow)*HD) + scol));
      gload16(&Kl[nxt][(r0+8)*64], (const h16*)((const char*)(Kh + (size_t)(kb2+r0+8+srow)*HD) + scol));
      gload16(&Vl[nxt][(r0+0)*64], (const h16*)((const char*)(Vh + (size_t)(r0+srow)*SEQ + kb2) + scol));
      gload16(&Vl[nxt][(r0+8)*64], (const h16*)((const char*)(Vh + (size_t)(r0+8+srow)*SEQ + kb2) + scol));
    }
    f32x4 S[2][4];
    #pragma unroll
    for(int mi=0;mi<2;mi++)
      #pragma unroll
      for(int j=0;j<4;j++)
        #pragma unroll
        for(int r=0;r<4;r++) S[mi][j][r] = 0.f;
    __builtin_amdgcn_s_setprio(1);
    #pragma unroll
    for(int ks=0;ks<2;ks++){
      f16x8 kf[4];
      #pragma unroll
      for(int nj=0;nj<4;nj++)
        kf[nj] = *(const f16x8*)((const char*)&Kl[cur][(nj*16+l16)*64] + ((ks*64 + l4*16) ^ swz));
      #pragma unroll
      for(int mi=0;mi<2;mi++)
        #pragma unroll
        for(int nj=0;nj<4;nj++)
          S[mi][nj] = __builtin_amdgcn_mfma_f32_16x16x32_f16(kf[nj], qf[mi][ks], S[mi][nj], 0,0,0);
    }
    __builtin_amdgcn_s_setprio(0);
    // tail masking: only on the last k-tile (uniform branch; no-op when n_kv%64==0)
    if(kb == nkb-1 && (n_kv & 63)){
      const int kbase = kb*64;
      #pragma unroll
      for(int nj=0;nj<4;nj++){
        const int keyb = kbase + nj*16 + l4*4;
        #pragma unroll
        for(int r=0;r<4;r++)
          if(keyb + r >= n_kv){ S[0][nj][r] = -1e30f; S[1][nj][r] = -1e30f; }
      }
    }
    // per-mi (round-9 skeleton): softmax -> P write -> lgkm drain -> PV (+osum MFMA)
    #pragma unroll
    for(int mi=0;mi<2;mi++){
      f32x4 t4;
      #pragma unroll
      for(int r=0;r<4;r++)
        t4[r] = fmaxf(fmaxf(S[mi][0][r],S[mi][1][r]), fmaxf(S[mi][2][r],S[mi][3][r]));
      float mx = fmaxf(fmaxf(t4[0],t4[1]), fmaxf(t4[2],t4[3]));
      mx = fmaxf(mx, __shfl_xor(mx,16,64));
      mx = fmaxf(mx, __shfl_xor(mx,32,64));
      if(!__all(mx <= mrow[mi] + 11.5f)){     // defer-max, THR ~ 8 nats in log2 units
        const float mnew = fmaxf(mrow[mi], mx);
        const float fac = exp2f(mrow[mi] - mnew);
        mrow[mi] = mnew;
        #pragma unroll
        for(int r=0;r<4;r++){
          const float f2 = __shfl(fac, (l & 48) | (l4*4 + r), 64);
          #pragma unroll
          for(int j2=0;j2<4;j2++) o[mi][j2][r] *= f2;
          osum[mi][r] *= f2;
        }
      }
      #pragma unroll
      for(int nj=0;nj<4;nj++){
        #pragma unroll
        for(int r=0;r<4;r++)
          S[mi][nj][r] = exp2f(S[mi][nj][r] - mrow[mi]);
        const unsigned plo = __builtin_bit_cast(unsigned,
            __builtin_amdgcn_cvt_pkrtz(S[mi][nj][0], S[mi][nj][1]));
        const unsigned phi = __builtin_bit_cast(unsigned,
            __builtin_amdgcn_cvt_pkrtz(S[mi][nj][2], S[mi][nj][3]));
        uint2 pw; pw.x = plo; pw.y = phi;
        *(uint2*)((char*)&Pl[w][l16*64] + ((nj*32 + l4*8) ^ swz)) = pw;
      }
      asm volatile("s_waitcnt lgkmcnt(0)" ::: "memory");
      __builtin_amdgcn_sched_barrier(0);
      __builtin_amdgcn_s_setprio(1);
      #pragma unroll
      for(int ks=0;ks<2;ks++){
        const f16x8 pf = *(const f16x8*)((const char*)&Pl[w][l16*64] + ((ks*64 + l4*16) ^ swz));
        #pragma unroll
        for(int j2=0;j2<4;j2++){
          const f16x8 vf = *(const f16x8*)((const char*)&Vl[cur][(j2*16+l16)*64] + ((ks*64 + l4*16) ^ swz));
          o[mi][j2] = __builtin_amdgcn_mfma_f32_16x16x32_f16(pf, vf, o[mi][j2], 0,0,0);
        }
        osum[mi] = __builtin_amdgcn_mfma_f32_16x16x32_f16(pf, onesv, osum[mi], 0,0,0);
      }
      __builtin_amdgcn_s_setprio(0);
    }
    cur ^= 1;
  }
  // epilogue: o rows are q = mi*16 + l4*4 + r; osum has the row-sum in the SAME layout
  #pragma unroll
  for(int mi=0;mi<2;mi++){
    #pragma unroll
    for(int r=0;r<4;r++){
      const float iv = 1.f/osum[mi][r];
      const int row = q0 + w*32 + mi*16 + l4*4 + r;
      #pragma unroll
      for(int j2=0;j2<4;j2++)
        aout[(size_t)row*DIMS + h*HD + j2*16 + l16] = (h16)(o[mi][j2][r]*iv);
    }
  }
}

// ---------------- launch ----------------
extern "C" void kernel_launch(void* const* d_in, const int* in_sizes, int n_in,
                              void* d_out, int out_size, void* d_ws, size_t ws_size,
                              hipStream_t stream){
  const float* x    = (const float*)d_in[0];
  const float* qn_g = (const float*)d_in[1];
  const float* qn_b = (const float*)d_in[2];
  const float* Wq   = (const float*)d_in[3];
  const float* bq   = (const float*)d_in[4];
  const float* kvn_g= (const float*)d_in[5];
  const float* kvn_b= (const float*)d_in[6];
  const float* Wkv  = (const float*)d_in[7];
  const float* bkv  = (const float*)d_in[8];
  const float* Wout = (const float*)d_in[9];
  const float* bout = (const float*)d_in[10];
  const float* ln_g = (const float*)d_in[11];
  const float* ln_b = (const float*)d_in[12];
  const int*  skip  = (const int*)d_in[13];

  // Workspace budget ~75 MB; refuse (clean fail, no OOB scribble) if undersized.
  if(ws_size < (size_t)79*1000*1000) return;

  char* p = (char*)d_ws;
  size_t off = 0;
  auto take = [&](size_t n)->char*{
    char* r = p + off; off = (off + n + 255) & ~(size_t)255; return r;
  };
  h16*    xhat = (h16*)   take((size_t)SEQ*DIMS*2);   // reused as abuf after kv GEMM
  float*  mag  = (float*) take((size_t)SEQ*4);
  float2* tab  = (float2*)take((size_t)SEQ*32*8);
  h16*    WqT  = (h16*)   take((size_t)1024*1024*2);
  h16*    WkvT = (h16*)   take((size_t)2048*1024*2);
  h16*    WoutT= (h16*)   take((size_t)1024*1024*2);
  float*  bqp  = (float*) take(1024*4);
  float*  bkvp = (float*) take(2048*4);
  h16*    qn   = (h16*)   take((size_t)NH*SEQ*HD*2);
  h16*    kn   = (h16*)   take((size_t)NH*SEQ*HD*2);
  h16*    vT   = (h16*)   take((size_t)NH*HD*SEQ*2);
  float*  part = (float*) take((size_t)16*2048*4);
  double* freq = (double*)take(32*8);
  h16*    abuf = xhat;   // alias: xhat dead after kv GEMM, attn writes after

  k_ln_stats<<<dim3(SEQ), dim3(256), 0, stream>>>(x, xhat, mag);
  k_freq<<<dim3(1), dim3(32), 0, stream>>>(freq);
  k_sincos<<<dim3(SEQ*32/256), dim3(256), 0, stream>>>(freq, tab);
  k_fold_part<<<dim3(4,16), dim3(256), 0, stream>>>(Wq, qn_b, part, 1024);
  k_fold_sum<<<dim3(4), dim3(256), 0, stream>>>(part, bq, bqp, 1024);
  k_fold_part<<<dim3(8,16), dim3(256), 0, stream>>>(Wkv, kvn_b, part, 2048);
  k_fold_sum<<<dim3(8), dim3(256), 0, stream>>>(part, bkv, bkvp, 2048);
  k_prep_w<<<dim3(16,16), dim3(256), 0, stream>>>(Wq,  qn_g,  WqT,  1024, 1024);
  k_prep_w<<<dim3(32,16), dim3(256), 0, stream>>>(Wkv, kvn_g, WkvT, 1024, 2048);
  k_prep_w<<<dim3(16,16), dim3(256), 0, stream>>>(Wout, nullptr, WoutT, 1024, 1024);
  k_gemm<1><<<dim3(8,64),  dim3(256), 0, stream>>>(xhat, WqT,  bqp, nullptr, qn, nullptr,
                                                   mag, tab, ln_g, ln_b, 1024, skip);
  k_gemm<2><<<dim3(16,64), dim3(256), 0, stream>>>(xhat, WkvT, bkvp, nullptr, kn, vT,
                                                   mag, tab, ln_g, ln_b, 2048, skip);
  k_pad_vt<<<dim3(1), dim3(256), 0, stream>>>(vT, skip);
  k_attn<<<dim3(16,64), dim3(256), 0, stream>>>(qn, kn, vT, abuf, skip);
  k_gemm<0><<<dim3(8,64), dim3(256), 0, stream>>>(abuf, WoutT, bout, (float*)d_out,
                                                  nullptr, nullptr, nullptr, nullptr,
                                                  nullptr, nullptr, 1024, skip);
}

// Round 14
// 267.326 us; speedup vs baseline: 2.3151x; 1.1143x over previous
//
#include <hip/hip_runtime.h>
#include <hip/hip_bf16.h>
#include <math.h>

#define SEQ 8192
#define DIMS 1024
#define NH 16
#define HD 64

typedef _Float16 h16;
typedef __attribute__((ext_vector_type(8))) _Float16 f16x8;
typedef __attribute__((ext_vector_type(4))) _Float16 h16x4;
typedef __attribute__((ext_vector_type(4))) float f32x4;

#if defined(__has_builtin)
#if __has_builtin(__builtin_amdgcn_global_load_lds)
#define USE_GLOAD 1
#endif
#if __has_builtin(__builtin_amdgcn_exp2f)
#define FEXP2(x) __builtin_amdgcn_exp2f(x)
#endif
#endif
#ifndef USE_GLOAD
#define USE_GLOAD 0
#endif
#ifndef FEXP2
#define FEXP2(x) exp2f(x)
#endif

__device__ __forceinline__ void gload16(h16* lds, const h16* g){
#if USE_GLOAD
  __builtin_amdgcn_global_load_lds((const __attribute__((address_space(1))) void*)g,
                                   (__attribute__((address_space(3))) void*)lds, 16, 0, 0);
#endif
}

// ---------------- LN stats over x: xhat (fp16) + mag ----------------
__global__ void k_ln_stats(const float* __restrict__ x, h16* __restrict__ xhat,
                           float* __restrict__ mag){
  const int row = blockIdx.x, t = threadIdx.x;
  float4 v = ((const float4*)(x + (size_t)row*DIMS))[t];
  float s = v.x+v.y+v.z+v.w;
  float s2 = v.x*v.x+v.y*v.y+v.z*v.z+v.w*v.w;
  #pragma unroll
  for(int m=1;m<64;m<<=1){ s += __shfl_xor(s,m,64); s2 += __shfl_xor(s2,m,64); }
  __shared__ float ls[4], ls2[4];
  const int wid = t>>6;
  if((t&63)==0){ ls[wid]=s; ls2[wid]=s2; }
  __syncthreads();
  s  = ls[0]+ls[1]+ls[2]+ls[3];
  s2 = ls2[0]+ls2[1]+ls2[2]+ls2[3];
  const float mean = s*(1.f/DIMS);
  const float var  = s2*(1.f/DIMS) - mean*mean;
  const float rstd = rsqrtf(var + 1e-5f);
  if(t==0) mag[row] = mean;
  h16x4 o;
  o[0] = (h16)((v.x-mean)*rstd); o[1] = (h16)((v.y-mean)*rstd);
  o[2] = (h16)((v.z-mean)*rstd); o[3] = (h16)((v.w-mean)*rstd);
  ((h16x4*)(xhat + (size_t)row*DIMS))[t] = o;
}

// ---------------- RoPE freqs (f64 pow, 32 threads once) ----------------
__global__ void k_freq(double* __restrict__ fr){
  const int d = threadIdx.x;
  if(d < 32) fr[d] = 0.2 * (pow(21.0, (double)d / 31.0) - 1.0);
}

// ---------------- cos/sin table: f64 range-reduce, f32 trig ----------------
__global__ void k_sincos(const double* __restrict__ fr, float2* __restrict__ tab){
  const int id = blockIdx.x*256 + threadIdx.x;   // 8192*32
  const int t = id >> 5, d = id & 31;
  const double ang = (double)t * fr[d];
  const double k = rint(ang * 0.15915494309189535);
  const float red = (float)(ang - k * 6.283185307179586);
  float s, c;
  __sincosf(red, &s, &c);
  tab[id] = make_float2(c, s);
}

// ------- deterministic two-stage bias fold: bias_out[j] = b0[j] + sum_i bln[i]*W[i][j] -------
__global__ void k_fold_part(const float* __restrict__ W, const float* __restrict__ bln,
                            float* __restrict__ part, const int C){
  const int j = blockIdx.x*256 + threadIdx.x;
  const int ib = blockIdx.y;                 // 16 chunks x 64 rows
  if(j >= C) return;
  float acc = 0.f;
  const int i0 = ib*64;
  #pragma unroll 4
  for(int i=i0;i<i0+64;i++) acc += bln[i]*W[(size_t)i*C + j];
  part[(size_t)ib*C + j] = acc;
}
__global__ void k_fold_sum(const float* __restrict__ part, const float* __restrict__ b0,
                           float* __restrict__ bias_out, const int C){
  const int j = blockIdx.x*256 + threadIdx.x;
  if(j >= C) return;
  float acc = b0[j];
  #pragma unroll
  for(int ib=0; ib<16; ib++) acc += part[(size_t)ib*C + j];
  bias_out[j] = acc;
}

// ------- weight prep: Wt[j][i] = g[i]*W[i][j] (fp16) -------
__global__ void k_prep_w(const float* __restrict__ W, const float* __restrict__ g,
                         h16* __restrict__ Wt, const int R, const int C){
  __shared__ float tile[64][65];
  const int c0 = blockIdx.x*64, r0 = blockIdx.y*64;
  const int t = threadIdx.x;
  const int cl = t & 63, rl0 = t >> 6;
  #pragma unroll
  for(int i=0;i<16;i++){
    const int r = rl0 + i*4;
    const float w = W[(size_t)(r0+r)*C + c0 + cl];
    const float gg = g ? g[r0+r] : 1.f;
    tile[r][cl] = w*gg;
  }
  __syncthreads();
  const int jl = t >> 2, ic = (t & 3)*16;
  h16* dst = Wt + (size_t)(c0+jl)*R + r0 + ic;
  #pragma unroll
  for(int i=0;i<16;i+=4){
    h16x4 o;
    o[0] = (h16)tile[ic+i+0][jl];
    o[1] = (h16)tile[ic+i+1][jl];
    o[2] = (h16)tile[ic+i+2][jl];
    o[3] = (h16)tile[ic+i+3][jl];
    *(h16x4*)(dst + i) = o;
  }
}

// MODE 0: plain f32 C=A@Bt+bias   (final out GEMM)
// MODE 1: Q GEMM, epilogue RoPE + head-LN -> OutB=qn (x 0.125*log2e)
// MODE 2: KV GEMM (compacted strided rows); cols<1024: K path (RoPE+LN -> OutB=kn),
//         cols>=1024: V path (bias only, LDS transpose -> vT[h][d][key])
template<int MODE>
__global__ __launch_bounds__(256) void k_gemm(
    const h16* __restrict__ A, const h16* __restrict__ Bt,
    const float* __restrict__ bias, float* __restrict__ Cf,
    h16* __restrict__ OutB, h16* __restrict__ vT,
    const float* __restrict__ mag, const float2* __restrict__ tab,
    const float* __restrict__ lg, const float* __restrict__ lb,
    const int N, const int* __restrict__ skip_p){
  int M = SEQ, pitchA = DIMS, st = 1;
  if(MODE==2){
    st = max(1, 4 - skip_p[0]);
    M = (SEQ + st - 1)/st;
    pitchA = st*DIMS;
  }
  const int m0 = blockIdx.y*128, n0 = blockIdx.x*128;
  if(m0 >= M) return;
  __shared__ h16 smem[(MODE==2) ? 128*136 : 8192];
  h16* As = smem;
  h16* Bs = smem + 4096;
  const int t = threadIdx.x;
  const int w = t>>6, l = t&63, l4 = l>>4, l16 = l&15;
  const int wm = w>>1, wn = w&1;
  f32x4 acc[4][4];
  #pragma unroll
  for(int i=0;i<4;i++)
    #pragma unroll
    for(int j=0;j<4;j++)
      #pragma unroll
      for(int r=0;r<4;r++) acc[i][j][r] = 0.f;
  for(int k0=0;k0<1024;k0+=32){
    __syncthreads();
    #pragma unroll
    for(int c=t;c<512;c+=256){
      const int row = c>>2, kp = (c&3)*8;
      int ar = m0+row; if(ar > M-1) ar = M-1;
#if USE_GLOAD
      gload16(&As[row*32+kp], A + (size_t)ar*pitchA + k0 + kp);
      gload16(&Bs[row*32+kp], Bt + (size_t)(n0+row)*1024 + k0 + kp);
#else
      *(f16x8*)(&As[row*32+kp]) = *(const f16x8*)(A + (size_t)ar*pitchA + k0 + kp);
      *(f16x8*)(&Bs[row*32+kp]) = *(const f16x8*)(Bt + (size_t)(n0+row)*1024 + k0 + kp);
#endif
    }
    __syncthreads();
    f16x8 af[4], bfr[4];
    #pragma unroll
    for(int i=0;i<4;i++){
      af[i]  = *(const f16x8*)(&As[(wm*64 + i*16 + l16)*32 + l4*8]);
      bfr[i] = *(const f16x8*)(&Bs[(wn*64 + i*16 + l16)*32 + l4*8]);
    }
    #pragma unroll
    for(int i=0;i<4;i++)
      #pragma unroll
      for(int j=0;j<4;j++)
        acc[i][j] = __builtin_amdgcn_mfma_f32_16x16x32_f16(af[i], bfr[j], acc[i][j], 0,0,0);
  }

  if(MODE==0){
    #pragma unroll
    for(int i=0;i<4;i++){
      const int rb = m0 + wm*64 + i*16 + l4*4;
      #pragma unroll
      for(int j=0;j<4;j++){
        const int col = n0 + wn*64 + j*16 + l16;
        const float bb = bias[col];
        #pragma unroll
        for(int r=0;r<4;r++)
          Cf[(size_t)(rb+r)*N + col] = acc[i][j][r] + bb;
      }
    }
    return;
  }

  float biasv[4];
  #pragma unroll
  for(int j=0;j<4;j++) biasv[j] = bias[n0 + wn*64 + j*16 + l16];

  const bool vpath = (MODE==2) && (n0 >= 1024);
  if(!vpath){
    // ---- RoPE + per-head LN epilogue (Q or K) ----
    float gv[4], bv[4];
    #pragma unroll
    for(int j=0;j<4;j++){ gv[j] = lg[j*16+l16]; bv[j] = lb[j*16+l16]; }
    const int h = (n0>>6) + wn;
    const float scl = (MODE==1) ? 0.125f*1.44269504f : 1.0f;   // fold 1/sqrt(64) * log2(e)
    const float sgn = (l16&1) ? 1.f : -1.f;
    #pragma unroll
    for(int i=0;i<4;i++){
      #pragma unroll
      for(int r=0;r<4;r++){
        int row = m0 + wm*64 + i*16 + l4*4 + r;
        const int rowc = (row < M) ? row : (M-1);
        const int tpos = (MODE==2) ? rowc*st : rowc;
        const float mg = mag[tpos];
        float v[4], pr[4], o4[4];
        #pragma unroll
        for(int j=0;j<4;j++) v[j] = acc[i][j][r] + biasv[j];
        #pragma unroll
        for(int j=0;j<4;j++) pr[j] = __shfl_xor(v[j], 1);
        float s1 = 0.f, s2 = 0.f;
        #pragma unroll
        for(int j=0;j<4;j++){
          const float2 cs = tab[(size_t)tpos*32 + j*8 + (l16>>1)];
          const float e = mg * (v[j]*cs.x + sgn*pr[j]*cs.y);
          o4[j] = e; s1 += e; s2 += e*e;
        }
        #pragma unroll
        for(int mm=1;mm<16;mm<<=1){ s1 += __shfl_xor(s1,mm,64); s2 += __shfl_xor(s2,mm,64); }
        const float mean = s1*(1.f/HD);
        const float var  = s2*(1.f/HD) - mean*mean;
        const float rstd = rsqrtf(var + 1e-5f);
        if(row < M){
          h16* dst = OutB + ((size_t)h*SEQ + row)*HD;
          #pragma unroll
          for(int j=0;j<4;j++)
            dst[j*16 + l16] = (h16)(((o4[j]-mean)*rstd*gv[j] + bv[j])*scl);
        }
      }
    }
  } else {
    // ---- V path: bias, LDS transpose, coalesced vT[h][d][key] writes ----
    __syncthreads();
    #pragma unroll
    for(int i=0;i<4;i++)
      #pragma unroll
      for(int j=0;j<4;j++)
        #pragma unroll
        for(int r=0;r<4;r++){
          const int key = wm*64 + i*16 + l4*4 + r;
          smem[(wn*64 + j*16 + l16)*136 + key] = (h16)(acc[i][j][r] + biasv[j]);
        }
    __syncthreads();
    const int rowT = t>>1, dh = rowT & 63, hloc = rowT>>6;
    const int hglob = ((n0-1024)>>6) + hloc;
    const h16* src = &smem[rowT*136 + (t&1)*64];
    h16* dstv = vT + ((size_t)hglob*HD + dh)*SEQ + m0 + (t&1)*64;
    #pragma unroll
    for(int c=0;c<64;c+=4)
      *(h16x4*)(dstv+c) = *(const h16x4*)(src+c);
  }
}

// ---------------- zero-pad vT tail keys up to 64-boundary ----------------
__global__ void k_pad_vt(h16* __restrict__ vT, const int* __restrict__ skip_p){
  const int st = max(1, 4 - skip_p[0]);
  const int n_kv = (SEQ + st - 1)/st;
  const int kb = ((n_kv + 63)/64)*64;
  const int pad = min(kb, SEQ) - n_kv;
  if(pad <= 0) return;
  const int total = NH*HD*pad;
  for(int i = threadIdx.x; i < total; i += 256){
    const int key = n_kv + (i % pad);
    const int hd = i / pad;
    vT[(size_t)hd*SEQ + key] = (h16)0.f;
  }
}

// ---------------- flash attention: synchronous single-buffer staging (GEMM contract) ----------------
// grid (head=16, qblk=64): linear id = h + 16*qb -> XCD = h&7 -> 2 heads/XCD L2
__launch_bounds__(256)
__global__ void k_attn(const h16* __restrict__ qn, const h16* __restrict__ kn,
                       const h16* __restrict__ vT, h16* __restrict__ aout,
                       const int* __restrict__ skip_p){
  const int st = max(1, 4 - skip_p[0]);
  const int n_kv = (SEQ + st - 1)/st;
  const int h = blockIdx.x, q0 = blockIdx.y*128;
  const int w = threadIdx.x >> 6, l = threadIdx.x & 63;
  const int l4 = l >> 4, l16 = l & 15;
  __shared__ __align__(16) h16 Kl[64*64];
  __shared__ __align__(16) h16 Vl[64*64];
  __shared__ __align__(16) h16 Pl[4][16*64];   // per-wave, per-mi overwrite
  const h16* Qh = qn + (size_t)h*SEQ*HD;
  const h16* Kh = kn + (size_t)h*SEQ*HD;
  const h16* Vh = vT + (size_t)h*HD*SEQ;
  // staging geometry: 8 rows x 128B per gload; swizzled GLOBAL source, linear LDS dest (rule 21)
  const int srow = l >> 3;
  const int scol = ((l & 7) << 4) ^ (srow << 4);   // byte offset within 128B row
  const int swz  = (l16 & 7) << 4;                 // read-side swizzle (byte)

  f16x8 onesv;
  #pragma unroll
  for(int i=0;i<8;i++) onesv[i] = (h16)1.f;
  const f32x4 zf = {0.f, 0.f, 0.f, 0.f};           // hoisted zero C-operand

  f16x8 qf[2][2];
  #pragma unroll
  for(int mi=0;mi<2;mi++)
    #pragma unroll
    for(int ks=0;ks<2;ks++)
      qf[mi][ks] = *(const f16x8*)(Qh + (size_t)(q0 + w*32 + mi*16 + l16)*HD + ks*32 + l4*8);
  f32x4 o[2][4], osum[2];
  float mrow[2];
  #pragma unroll
  for(int mi=0;mi<2;mi++){
    mrow[mi] = -1e30f;
    #pragma unroll
    for(int r=0;r<4;r++) osum[mi][r] = 0.f;
    #pragma unroll
    for(int j=0;j<4;j++)
      #pragma unroll
      for(int r=0;r<4;r++) o[mi][j][r] = 0.f;
  }

  const int nkb = (n_kv + 63) >> 6;
  for(int kb=0; kb<nkb; kb++){
    const int kb0 = kb*64, r0 = w*16;
    // ---- synchronous stage (exact GEMM contract: barrier / gload / barrier) ----
    __syncthreads();   // all waves done reading previous tile
    gload16(&Kl[(r0+0)*64], (const h16*)((const char*)(Kh + (size_t)(kb0+r0+srow)*HD) + scol));
    gload16(&Kl[(r0+8)*64], (const h16*)((const char*)(Kh + (size_t)(kb0+r0+8+srow)*HD) + scol));
    gload16(&Vl[(r0+0)*64], (const h16*)((const char*)(Vh + (size_t)(r0+srow)*SEQ + kb0) + scol));
    gload16(&Vl[(r0+8)*64], (const h16*)((const char*)(Vh + (size_t)(r0+8+srow)*SEQ + kb0) + scol));
    __syncthreads();   // compiler-managed vmcnt drain; tile visible to all waves
    f32x4 S[2][4];
    __builtin_amdgcn_s_setprio(1);
    {   // ks = 0: C = zf (no per-iter zero-init of S)
      f16x8 kf[4];
      #pragma unroll
      for(int nj=0;nj<4;nj++)
        kf[nj] = *(const f16x8*)((const char*)&Kl[(nj*16+l16)*64] + ((0*64 + l4*16) ^ swz));
      #pragma unroll
      for(int mi=0;mi<2;mi++)
        #pragma unroll
        for(int nj=0;nj<4;nj++)
          S[mi][nj] = __builtin_amdgcn_mfma_f32_16x16x32_f16(kf[nj], qf[mi][0], zf, 0,0,0);
    }
    {   // ks = 1: accumulate
      f16x8 kf[4];
      #pragma unroll
      for(int nj=0;nj<4;nj++)
        kf[nj] = *(const f16x8*)((const char*)&Kl[(nj*16+l16)*64] + ((1*64 + l4*16) ^ swz));
      #pragma unroll
      for(int mi=0;mi<2;mi++)
        #pragma unroll
        for(int nj=0;nj<4;nj++)
          S[mi][nj] = __builtin_amdgcn_mfma_f32_16x16x32_f16(kf[nj], qf[mi][1], S[mi][nj], 0,0,0);
    }
    __builtin_amdgcn_s_setprio(0);
    // tail masking: only on the last k-tile (uniform branch; no-op when n_kv%64==0)
    if(kb == nkb-1 && (n_kv & 63)){
      #pragma unroll
      for(int nj=0;nj<4;nj++){
        const int keyb = kb0 + nj*16 + l4*4;
        #pragma unroll
        for(int r=0;r<4;r++)
          if(keyb + r >= n_kv){ S[0][nj][r] = -1e30f; S[1][nj][r] = -1e30f; }
      }
    }
    // per-mi: softmax -> P write -> lgkm drain -> PV (+osum MFMA)
    #pragma unroll
    for(int mi=0;mi<2;mi++){
      f32x4 t4;
      #pragma unroll
      for(int r=0;r<4;r++)
        t4[r] = fmaxf(fmaxf(S[mi][0][r],S[mi][1][r]), fmaxf(S[mi][2][r],S[mi][3][r]));
      float mx = fmaxf(fmaxf(t4[0],t4[1]), fmaxf(t4[2],t4[3]));
      mx = fmaxf(mx, __shfl_xor(mx,16,64));
      mx = fmaxf(mx, __shfl_xor(mx,32,64));
      if(!__all(mx <= mrow[mi] + 11.5f)){     // defer-max, THR ~ 8 nats in log2 units
        const float mnew = fmaxf(mrow[mi], mx);
        const float fac = FEXP2(mrow[mi] - mnew);
        mrow[mi] = mnew;
        #pragma unroll
        for(int r=0;r<4;r++){
          const float f2 = __shfl(fac, (l & 48) | (l4*4 + r), 64);
          #pragma unroll
          for(int j2=0;j2<4;j2++) o[mi][j2][r] *= f2;
          osum[mi][r] *= f2;
        }
      }
      #pragma unroll
      for(int nj=0;nj<4;nj++){
        #pragma unroll
        for(int r=0;r<4;r++)
          S[mi][nj][r] = FEXP2(S[mi][nj][r] - mrow[mi]);
        const unsigned plo = __builtin_bit_cast(unsigned,
            __builtin_amdgcn_cvt_pkrtz(S[mi][nj][0], S[mi][nj][1]));
        const unsigned phi = __builtin_bit_cast(unsigned,
            __builtin_amdgcn_cvt_pkrtz(S[mi][nj][2], S[mi][nj][3]));
        uint2 pw; pw.x = plo; pw.y = phi;
        *(uint2*)((char*)&Pl[w][l16*64] + ((nj*32 + l4*8) ^ swz)) = pw;
      }
      asm volatile("s_waitcnt lgkmcnt(0)" ::: "memory");
      __builtin_amdgcn_sched_barrier(0);
      __builtin_amdgcn_s_setprio(1);
      #pragma unroll
      for(int ks=0;ks<2;ks++){
        const f16x8 pf = *(const f16x8*)((const char*)&Pl[w][l16*64] + ((ks*64 + l4*16) ^ swz));
        #pragma unroll
        for(int j2=0;j2<4;j2++){
          const f16x8 vf = *(const f16x8*)((const char*)&Vl[(j2*16+l16)*64] + ((ks*64 + l4*16) ^ swz));
          o[mi][j2] = __builtin_amdgcn_mfma_f32_16x16x32_f16(pf, vf, o[mi][j2], 0,0,0);
        }
        osum[mi] = __builtin_amdgcn_mfma_f32_16x16x32_f16(pf, onesv, osum[mi], 0,0,0);
      }
      __builtin_amdgcn_s_setprio(0);
    }
  }
  // epilogue: o rows are q = mi*16 + l4*4 + r; osum has the row-sum in the SAME layout
  #pragma unroll
  for(int mi=0;mi<2;mi++){
    #pragma unroll
    for(int r=0;r<4;r++){
      const float iv = 1.f/osum[mi][r];
      const int row = q0 + w*32 + mi*16 + l4*4 + r;
      #pragma unroll
      for(int j2=0;j2<4;j2++)
        aout[(size_t)row*DIMS + h*HD + j2*16 + l16] = (h16)(o[mi][j2][r]*iv);
    }
  }
}

// ---------------- launch ----------------
extern "C" void kernel_launch(void* const* d_in, const int* in_sizes, int n_in,
                              void* d_out, int out_size, void* d_ws, size_t ws_size,
                              hipStream_t stream){
  const float* x    = (const float*)d_in[0];
  const float* qn_g = (const float*)d_in[1];
  const float* qn_b = (const float*)d_in[2];
  const float* Wq   = (const float*)d_in[3];
  const float* bq   = (const float*)d_in[4];
  const float* kvn_g= (const float*)d_in[5];
  const float* kvn_b= (const float*)d_in[6];
  const float* Wkv  = (const float*)d_in[7];
  const float* bkv  = (const float*)d_in[8];
  const float* Wout = (const float*)d_in[9];
  const float* bout = (const float*)d_in[10];
  const float* ln_g = (const float*)d_in[11];
  const float* ln_b = (const float*)d_in[12];
  const int*  skip  = (const int*)d_in[13];

  // Workspace budget ~75 MB; refuse (clean fail, no OOB scribble) if undersized.
  if(ws_size < (size_t)79*1000*1000) return;

  char* p = (char*)d_ws;
  size_t off = 0;
  auto take = [&](size_t n)->char*{
    char* r = p + off; off = (off + n + 255) & ~(size_t)255; return r;
  };
  h16*    xhat = (h16*)   take((size_t)SEQ*DIMS*2);   // reused as abuf after kv GEMM
  float*  mag  = (float*) take((size_t)SEQ*4);
  float2* tab  = (float2*)take((size_t)SEQ*32*8);
  h16*    WqT  = (h16*)   take((size_t)1024*1024*2);
  h16*    WkvT = (h16*)   take((size_t)2048*1024*2);
  h16*    WoutT= (h16*)   take((size_t)1024*1024*2);
  float*  bqp  = (float*) take(1024*4);
  float*  bkvp = (float*) take(2048*4);
  h16*    qn   = (h16*)   take((size_t)NH*SEQ*HD*2);
  h16*    kn   = (h16*)   take((size_t)NH*SEQ*HD*2);
  h16*    vT   = (h16*)   take((size_t)NH*HD*SEQ*2);
  float*  part = (float*) take((size_t)16*2048*4);
  double* freq = (double*)take(32*8);
  h16*    abuf = xhat;   // alias: xhat dead after kv GEMM, attn writes after

  k_ln_stats<<<dim3(SEQ), dim3(256), 0, stream>>>(x, xhat, mag);
  k_freq<<<dim3(1), dim3(32), 0, stream>>>(freq);
  k_sincos<<<dim3(SEQ*32/256), dim3(256), 0, stream>>>(freq, tab);
  k_fold_part<<<dim3(4,16), dim3(256), 0, stream>>>(Wq, qn_b, part, 1024);
  k_fold_sum<<<dim3(4), dim3(256), 0, stream>>>(part, bq, bqp, 1024);
  k_fold_part<<<dim3(8,16), dim3(256), 0, stream>>>(Wkv, kvn_b, part, 2048);
  k_fold_sum<<<dim3(8), dim3(256), 0, stream>>>(part, bkv, bkvp, 2048);
  k_prep_w<<<dim3(16,16), dim3(256), 0, stream>>>(Wq,  qn_g,  WqT,  1024, 1024);
  k_prep_w<<<dim3(32,16), dim3(256), 0, stream>>>(Wkv, kvn_g, WkvT, 1024, 2048);
  k_prep_w<<<dim3(16,16), dim3(256), 0, stream>>>(Wout, nullptr, WoutT, 1024, 1024);
  k_gemm<1><<<dim3(8,64),  dim3(256), 0, stream>>>(xhat, WqT,  bqp, nullptr, qn, nullptr,
                                                   mag, tab, ln_g, ln_b, 1024, skip);
  k_gemm<2><<<dim3(16,64), dim3(256), 0, stream>>>(xhat, WkvT, bkvp, nullptr, kn, vT,
                                                   mag, tab, ln_g, ln_b, 2048, skip);
  k_pad_vt<<<dim3(1), dim3(256), 0, stream>>>(vT, skip);
  k_attn<<<dim3(16,64), dim3(256), 0, stream>>>(qn, kn, vT, abuf, skip);
  k_gemm<0><<<dim3(8,64), dim3(256), 0, stream>>>(abuf, WoutT, bout, (float*)d_out,
                                                  nullptr, nullptr, nullptr, nullptr,
                                                  nullptr, nullptr, 1024, skip);
}

// Round 18
// 249.157 us; speedup vs baseline: 2.4839x; 1.0729x over previous
//
#include <hip/hip_runtime.h>
#include <hip/hip_bf16.h>
#include <math.h>

#define SEQ 8192
#define DIMS 1024
#define NH 16
#define HD 64

typedef _Float16 h16;
typedef __attribute__((ext_vector_type(8))) _Float16 f16x8;
typedef __attribute__((ext_vector_type(4))) _Float16 h16x4;
typedef __attribute__((ext_vector_type(4))) float f32x4;

#if defined(__has_builtin)
#if __has_builtin(__builtin_amdgcn_global_load_lds)
#define USE_GLOAD 1
#endif
#if __has_builtin(__builtin_amdgcn_exp2f)
#define FEXP2(x) __builtin_amdgcn_exp2f(x)
#endif
#endif
#ifndef USE_GLOAD
#define USE_GLOAD 0
#endif
#ifndef FEXP2
#define FEXP2(x) exp2f(x)
#endif

__device__ __forceinline__ void gload16(h16* lds, const h16* g){
#if USE_GLOAD
  __builtin_amdgcn_global_load_lds((const __attribute__((address_space(1))) void*)g,
                                   (__attribute__((address_space(3))) void*)lds, 16, 0, 0);
#endif
}

// ---------------- LN stats over x: xhat (fp16) + mag ----------------
__global__ void k_ln_stats(const float* __restrict__ x, h16* __restrict__ xhat,
                           float* __restrict__ mag){
  const int row = blockIdx.x, t = threadIdx.x;
  float4 v = ((const float4*)(x + (size_t)row*DIMS))[t];
  float s = v.x+v.y+v.z+v.w;
  float s2 = v.x*v.x+v.y*v.y+v.z*v.z+v.w*v.w;
  #pragma unroll
  for(int m=1;m<64;m<<=1){ s += __shfl_xor(s,m,64); s2 += __shfl_xor(s2,m,64); }
  __shared__ float ls[4], ls2[4];
  const int wid = t>>6;
  if((t&63)==0){ ls[wid]=s; ls2[wid]=s2; }
  __syncthreads();
  s  = ls[0]+ls[1]+ls[2]+ls[3];
  s2 = ls2[0]+ls2[1]+ls2[2]+ls2[3];
  const float mean = s*(1.f/DIMS);
  const float var  = s2*(1.f/DIMS) - mean*mean;
  const float rstd = rsqrtf(var + 1e-5f);
  if(t==0) mag[row] = mean;
  h16x4 o;
  o[0] = (h16)((v.x-mean)*rstd); o[1] = (h16)((v.y-mean)*rstd);
  o[2] = (h16)((v.z-mean)*rstd); o[3] = (h16)((v.w-mean)*rstd);
  ((h16x4*)(xhat + (size_t)row*DIMS))[t] = o;
}

// ---------------- cos/sin table (freq computed per block; f64 range-reduce) ----------------
__global__ void k_sincos(float2* __restrict__ tab){
  __shared__ double fr[32];
  const int t = threadIdx.x;
  if(t < 32) fr[t] = 0.2 * (pow(21.0, (double)t / 31.0) - 1.0);
  __syncthreads();
  const int id = blockIdx.x*256 + t;   // 8192*32 total
  const int tt = id >> 5, d = id & 31;
  const double ang = (double)tt * fr[d];
  const double k = rint(ang * 0.15915494309189535);
  const float red = (float)(ang - k * 6.283185307179586);
  float s, c;
  __sincosf(red, &s, &c);
  tab[id] = make_float2(c, s);
}

// ------- fused deterministic bias folds (disjoint outputs, single writer/elem) -------
__global__ void k_fold_part2(const float* __restrict__ Wq, const float* __restrict__ qb_ln,
                             const float* __restrict__ Wkv, const float* __restrict__ kvb_ln,
                             float* __restrict__ partq, float* __restrict__ partkv){
  const int bx = blockIdx.x, ib = blockIdx.y;
  const float* W; const float* bln; float* part; int C, j;
  if(bx < 4){ W = Wq;  bln = qb_ln;  part = partq;  C = 1024; j = bx*256 + threadIdx.x; }
  else      { W = Wkv; bln = kvb_ln; part = partkv; C = 2048; j = (bx-4)*256 + threadIdx.x; }
  float acc = 0.f;
  const int i0 = ib*64;
  #pragma unroll 4
  for(int i=i0;i<i0+64;i++) acc += bln[i]*W[(size_t)i*C + j];
  part[(size_t)ib*C + j] = acc;
}
__global__ void k_fold_sum2(const float* __restrict__ partq, const float* __restrict__ partkv,
                            const float* __restrict__ bq, const float* __restrict__ bkv,
                            float* __restrict__ bqp, float* __restrict__ bkvp){
  const int bx = blockIdx.x;
  if(bx < 4){
    const int j = bx*256 + threadIdx.x;
    float a = bq[j];
    #pragma unroll
    for(int ib=0; ib<16; ib++) a += partq[(size_t)ib*1024 + j];
    bqp[j] = a;
  } else {
    const int j = (bx-4)*256 + threadIdx.x;
    float a = bkv[j];
    #pragma unroll
    for(int ib=0; ib<16; ib++) a += partkv[(size_t)ib*2048 + j];
    bkvp[j] = a;
  }
}

// ------- fused weight prep: Wt[j][i] = g[i]*W[i][j] (fp16), 3 weights in one grid -------
__global__ void k_prep_w3(const float* __restrict__ Wq, const float* __restrict__ qg,
                          const float* __restrict__ Wkv, const float* __restrict__ kvg,
                          const float* __restrict__ Wout,
                          h16* __restrict__ WqT, h16* __restrict__ WkvT, h16* __restrict__ WoutT){
  __shared__ float tile[64][65];
  const int bx = blockIdx.x;
  const float* W; const float* g; h16* Wt; int C, cb;
  if(bx < 16)      { W = Wq;   g = qg;      Wt = WqT;   C = 1024; cb = bx; }
  else if(bx < 48) { W = Wkv;  g = kvg;     Wt = WkvT;  C = 2048; cb = bx-16; }
  else             { W = Wout; g = nullptr; Wt = WoutT; C = 1024; cb = bx-48; }
  const int R = 1024;
  const int c0 = cb*64, r0 = blockIdx.y*64;
  const int t = threadIdx.x;
  const int cl = t & 63, rl0 = t >> 6;
  #pragma unroll
  for(int i=0;i<16;i++){
    const int r = rl0 + i*4;
    const float w = W[(size_t)(r0+r)*C + c0 + cl];
    const float gg = g ? g[r0+r] : 1.f;
    tile[r][cl] = w*gg;
  }
  __syncthreads();
  const int jl = t >> 2, ic = (t & 3)*16;
  h16* dst = Wt + (size_t)(c0+jl)*R + r0 + ic;
  #pragma unroll
  for(int i=0;i<16;i+=4){
    h16x4 o;
    o[0] = (h16)tile[ic+i+0][jl];
    o[1] = (h16)tile[ic+i+1][jl];
    o[2] = (h16)tile[ic+i+2][jl];
    o[3] = (h16)tile[ic+i+3][jl];
    *(h16x4*)(dst + i) = o;
  }
}

// MODE 0: plain f32 C=A@Bt+bias   (final out GEMM)
// MODE 1: Q GEMM, epilogue RoPE + head-LN -> OutB=qn (x 0.125*log2e)
// MODE 2: KV GEMM (compacted strided rows); cols<1024: K path (RoPE+LN -> OutB=kn),
//         cols>=1024: V path (bias only, LDS transpose -> vT[h][d][key])
template<int MODE>
__global__ __launch_bounds__(256) void k_gemm(
    const h16* __restrict__ A, const h16* __restrict__ Bt,
    const float* __restrict__ bias, float* __restrict__ Cf,
    h16* __restrict__ OutB, h16* __restrict__ vT,
    const float* __restrict__ mag, const float2* __restrict__ tab,
    const float* __restrict__ lg, const float* __restrict__ lb,
    const int N, const int* __restrict__ skip_p){
  int M = SEQ, pitchA = DIMS, st = 1;
  if(MODE==2){
    st = max(1, 4 - skip_p[0]);
    M = (SEQ + st - 1)/st;
    pitchA = st*DIMS;
  }
  const int m0 = blockIdx.y*128, n0 = blockIdx.x*128;
  if(m0 >= M) return;
  __shared__ h16 smem[(MODE==2) ? 128*136 : 8192];
  h16* As = smem;
  h16* Bs = smem + 4096;
  const int t = threadIdx.x;
  const int w = t>>6, l = t&63, l4 = l>>4, l16 = l&15;
  const int wm = w>>1, wn = w&1;
  f32x4 acc[4][4];
  #pragma unroll
  for(int i=0;i<4;i++)
    #pragma unroll
    for(int j=0;j<4;j++)
      #pragma unroll
      for(int r=0;r<4;r++) acc[i][j][r] = 0.f;
  for(int k0=0;k0<1024;k0+=32){
    __syncthreads();
    #pragma unroll
    for(int c=t;c<512;c+=256){
      const int row = c>>2, kp = (c&3)*8;
      int ar = m0+row; if(ar > M-1) ar = M-1;
#if USE_GLOAD
      gload16(&As[row*32+kp], A + (size_t)ar*pitchA + k0 + kp);
      gload16(&Bs[row*32+kp], Bt + (size_t)(n0+row)*1024 + k0 + kp);
#else
      *(f16x8*)(&As[row*32+kp]) = *(const f16x8*)(A + (size_t)ar*pitchA + k0 + kp);
      *(f16x8*)(&Bs[row*32+kp]) = *(const f16x8*)(Bt + (size_t)(n0+row)*1024 + k0 + kp);
#endif
    }
    __syncthreads();
    f16x8 af[4], bfr[4];
    #pragma unroll
    for(int i=0;i<4;i++){
      af[i]  = *(const f16x8*)(&As[(wm*64 + i*16 + l16)*32 + l4*8]);
      bfr[i] = *(const f16x8*)(&Bs[(wn*64 + i*16 + l16)*32 + l4*8]);
    }
    #pragma unroll
    for(int i=0;i<4;i++)
      #pragma unroll
      for(int j=0;j<4;j++)
        acc[i][j] = __builtin_amdgcn_mfma_f32_16x16x32_f16(af[i], bfr[j], acc[i][j], 0,0,0);
  }

  if(MODE==0){
    #pragma unroll
    for(int i=0;i<4;i++){
      const int rb = m0 + wm*64 + i*16 + l4*4;
      #pragma unroll
      for(int j=0;j<4;j++){
        const int col = n0 + wn*64 + j*16 + l16;
        const float bb = bias[col];
        #pragma unroll
        for(int r=0;r<4;r++)
          Cf[(size_t)(rb+r)*N + col] = acc[i][j][r] + bb;
      }
    }
    return;
  }

  float biasv[4];
  #pragma unroll
  for(int j=0;j<4;j++) biasv[j] = bias[n0 + wn*64 + j*16 + l16];

  const bool vpath = (MODE==2) && (n0 >= 1024);
  if(!vpath){
    // ---- RoPE + per-head LN epilogue (Q or K) ----
    float gv[4], bv[4];
    #pragma unroll
    for(int j=0;j<4;j++){ gv[j] = lg[j*16+l16]; bv[j] = lb[j*16+l16]; }
    const int h = (n0>>6) + wn;
    const float scl = (MODE==1) ? 0.125f*1.44269504f : 1.0f;   // fold 1/sqrt(64) * log2(e)
    const float sgn = (l16&1) ? 1.f : -1.f;
    #pragma unroll
    for(int i=0;i<4;i++){
      #pragma unroll
      for(int r=0;r<4;r++){
        int row = m0 + wm*64 + i*16 + l4*4 + r;
        const int rowc = (row < M) ? row : (M-1);
        const int tpos = (MODE==2) ? rowc*st : rowc;
        const float mg = mag[tpos];
        float v[4], pr[4], o4[4];
        #pragma unroll
        for(int j=0;j<4;j++) v[j] = acc[i][j][r] + biasv[j];
        #pragma unroll
        for(int j=0;j<4;j++) pr[j] = __shfl_xor(v[j], 1);
        float s1 = 0.f, s2 = 0.f;
        #pragma unroll
        for(int j=0;j<4;j++){
          const float2 cs = tab[(size_t)tpos*32 + j*8 + (l16>>1)];
          const float e = mg * (v[j]*cs.x + sgn*pr[j]*cs.y);
          o4[j] = e; s1 += e; s2 += e*e;
        }
        #pragma unroll
        for(int mm=1;mm<16;mm<<=1){ s1 += __shfl_xor(s1,mm,64); s2 += __shfl_xor(s2,mm,64); }
        const float mean = s1*(1.f/HD);
        const float var  = s2*(1.f/HD) - mean*mean;
        const float rstd = rsqrtf(var + 1e-5f);
        if(row < M){
          h16* dst = OutB + ((size_t)h*SEQ + row)*HD;
          #pragma unroll
          for(int j=0;j<4;j++)
            dst[j*16 + l16] = (h16)(((o4[j]-mean)*rstd*gv[j] + bv[j])*scl);
        }
      }
    }
  } else {
    // ---- V path: bias, LDS transpose, coalesced vT[h][d][key] writes ----
    __syncthreads();
    #pragma unroll
    for(int i=0;i<4;i++)
      #pragma unroll
      for(int j=0;j<4;j++)
        #pragma unroll
        for(int r=0;r<4;r++){
          const int key = wm*64 + i*16 + l4*4 + r;
          smem[(wn*64 + j*16 + l16)*136 + key] = (h16)(acc[i][j][r] + biasv[j]);
        }
    __syncthreads();
    const int rowT = t>>1, dh = rowT & 63, hloc = rowT>>6;
    const int hglob = ((n0-1024)>>6) + hloc;
    const h16* src = &smem[rowT*136 + (t&1)*64];
    h16* dstv = vT + ((size_t)hglob*HD + dh)*SEQ + m0 + (t&1)*64;
    #pragma unroll
    for(int c=0;c<64;c+=4)
      *(h16x4*)(dstv+c) = *(const h16x4*)(src+c);
  }
}

// ---------------- zero-pad vT tail keys up to 64-boundary ----------------
__global__ void k_pad_vt(h16* __restrict__ vT, const int* __restrict__ skip_p){
  const int st = max(1, 4 - skip_p[0]);
  const int n_kv = (SEQ + st - 1)/st;
  const int kb = ((n_kv + 63)/64)*64;
  const int pad = min(kb, SEQ) - n_kv;
  if(pad <= 0) return;
  const int total = NH*HD*pad;
  for(int i = threadIdx.x; i < total; i += 256){
    const int key = n_kv + (i % pad);
    const int hd = i / pad;
    vT[(size_t)hd*SEQ + key] = (h16)0.f;
  }
}

// ---------------- flash attention: synchronous single-buffer staging (GEMM contract) ----------------
// grid (head=16, qblk=64): linear id = h + 16*qb -> XCD = h&7 -> 2 heads/XCD L2
// BYTE-IDENTICAL to round-14's verified k_attn.
__launch_bounds__(256)
__global__ void k_attn(const h16* __restrict__ qn, const h16* __restrict__ kn,
                       const h16* __restrict__ vT, h16* __restrict__ aout,
                       const int* __restrict__ skip_p){
  const int st = max(1, 4 - skip_p[0]);
  const int n_kv = (SEQ + st - 1)/st;
  const int h = blockIdx.x, q0 = blockIdx.y*128;
  const int w = threadIdx.x >> 6, l = threadIdx.x & 63;
  const int l4 = l >> 4, l16 = l & 15;
  __shared__ __align__(16) h16 Kl[64*64];
  __shared__ __align__(16) h16 Vl[64*64];
  __shared__ __align__(16) h16 Pl[4][16*64];   // per-wave, per-mi overwrite
  const h16* Qh = qn + (size_t)h*SEQ*HD;
  const h16* Kh = kn + (size_t)h*SEQ*HD;
  const h16* Vh = vT + (size_t)h*HD*SEQ;
  // staging geometry: 8 rows x 128B per gload; swizzled GLOBAL source, linear LDS dest (rule 21)
  const int srow = l >> 3;
  const int scol = ((l & 7) << 4) ^ (srow << 4);   // byte offset within 128B row
  const int swz  = (l16 & 7) << 4;                 // read-side swizzle (byte)

  f16x8 onesv;
  #pragma unroll
  for(int i=0;i<8;i++) onesv[i] = (h16)1.f;
  const f32x4 zf = {0.f, 0.f, 0.f, 0.f};           // hoisted zero C-operand

  f16x8 qf[2][2];
  #pragma unroll
  for(int mi=0;mi<2;mi++)
    #pragma unroll
    for(int ks=0;ks<2;ks++)
      qf[mi][ks] = *(const f16x8*)(Qh + (size_t)(q0 + w*32 + mi*16 + l16)*HD + ks*32 + l4*8);
  f32x4 o[2][4], osum[2];
  float mrow[2];
  #pragma unroll
  for(int mi=0;mi<2;mi++){
    mrow[mi] = -1e30f;
    #pragma unroll
    for(int r=0;r<4;r++) osum[mi][r] = 0.f;
    #pragma unroll
    for(int j=0;j<4;j++)
      #pragma unroll
      for(int r=0;r<4;r++) o[mi][j][r] = 0.f;
  }

  const int nkb = (n_kv + 63) >> 6;
  for(int kb=0; kb<nkb; kb++){
    const int kb0 = kb*64, r0 = w*16;
    // ---- synchronous stage (exact GEMM contract: barrier / gload / barrier) ----
    __syncthreads();   // all waves done reading previous tile
    gload16(&Kl[(r0+0)*64], (const h16*)((const char*)(Kh + (size_t)(kb0+r0+srow)*HD) + scol));
    gload16(&Kl[(r0+8)*64], (const h16*)((const char*)(Kh + (size_t)(kb0+r0+8+srow)*HD) + scol));
    gload16(&Vl[(r0+0)*64], (const h16*)((const char*)(Vh + (size_t)(r0+srow)*SEQ + kb0) + scol));
    gload16(&Vl[(r0+8)*64], (const h16*)((const char*)(Vh + (size_t)(r0+8+srow)*SEQ + kb0) + scol));
    __syncthreads();   // compiler-managed vmcnt drain; tile visible to all waves
    f32x4 S[2][4];
    __builtin_amdgcn_s_setprio(1);
    {   // ks = 0: C = zf (no per-iter zero-init of S)
      f16x8 kf[4];
      #pragma unroll
      for(int nj=0;nj<4;nj++)
        kf[nj] = *(const f16x8*)((const char*)&Kl[(nj*16+l16)*64] + ((0*64 + l4*16) ^ swz));
      #pragma unroll
      for(int mi=0;mi<2;mi++)
        #pragma unroll
        for(int nj=0;nj<4;nj++)
          S[mi][nj] = __builtin_amdgcn_mfma_f32_16x16x32_f16(kf[nj], qf[mi][0], zf, 0,0,0);
    }
    {   // ks = 1: accumulate
      f16x8 kf[4];
      #pragma unroll
      for(int nj=0;nj<4;nj++)
        kf[nj] = *(const f16x8*)((const char*)&Kl[(nj*16+l16)*64] + ((1*64 + l4*16) ^ swz));
      #pragma unroll
      for(int mi=0;mi<2;mi++)
        #pragma unroll
        for(int nj=0;nj<4;nj++)
          S[mi][nj] = __builtin_amdgcn_mfma_f32_16x16x32_f16(kf[nj], qf[mi][1], S[mi][nj], 0,0,0);
    }
    __builtin_amdgcn_s_setprio(0);
    // tail masking: only on the last k-tile (uniform branch; no-op when n_kv%64==0)
    if(kb == nkb-1 && (n_kv & 63)){
      #pragma unroll
      for(int nj=0;nj<4;nj++){
        const int keyb = kb0 + nj*16 + l4*4;
        #pragma unroll
        for(int r=0;r<4;r++)
          if(keyb + r >= n_kv){ S[0][nj][r] = -1e30f; S[1][nj][r] = -1e30f; }
      }
    }
    // per-mi: softmax -> P write -> lgkm drain -> PV (+osum MFMA)
    #pragma unroll
    for(int mi=0;mi<2;mi++){
      f32x4 t4;
      #pragma unroll
      for(int r=0;r<4;r++)
        t4[r] = fmaxf(fmaxf(S[mi][0][r],S[mi][1][r]), fmaxf(S[mi][2][r],S[mi][3][r]));
      float mx = fmaxf(fmaxf(t4[0],t4[1]), fmaxf(t4[2],t4[3]));
      mx = fmaxf(mx, __shfl_xor(mx,16,64));
      mx = fmaxf(mx, __shfl_xor(mx,32,64));
      if(!__all(mx <= mrow[mi] + 11.5f)){     // defer-max, THR ~ 8 nats in log2 units
        const float mnew = fmaxf(mrow[mi], mx);
        const float fac = FEXP2(mrow[mi] - mnew);
        mrow[mi] = mnew;
        #pragma unroll
        for(int r=0;r<4;r++){
          const float f2 = __shfl(fac, (l & 48) | (l4*4 + r), 64);
          #pragma unroll
          for(int j2=0;j2<4;j2++) o[mi][j2][r] *= f2;
          osum[mi][r] *= f2;
        }
      }
      #pragma unroll
      for(int nj=0;nj<4;nj++){
        #pragma unroll
        for(int r=0;r<4;r++)
          S[mi][nj][r] = FEXP2(S[mi][nj][r] - mrow[mi]);
        const unsigned plo = __builtin_bit_cast(unsigned,
            __builtin_amdgcn_cvt_pkrtz(S[mi][nj][0], S[mi][nj][1]));
        const unsigned phi = __builtin_bit_cast(unsigned,
            __builtin_amdgcn_cvt_pkrtz(S[mi][nj][2], S[mi][nj][3]));
        uint2 pw; pw.x = plo; pw.y = phi;
        *(uint2*)((char*)&Pl[w][l16*64] + ((nj*32 + l4*8) ^ swz)) = pw;
      }
      asm volatile("s_waitcnt lgkmcnt(0)" ::: "memory");
      __builtin_amdgcn_sched_barrier(0);
      __builtin_amdgcn_s_setprio(1);
      #pragma unroll
      for(int ks=0;ks<2;ks++){
        const f16x8 pf = *(const f16x8*)((const char*)&Pl[w][l16*64] + ((ks*64 + l4*16) ^ swz));
        #pragma unroll
        for(int j2=0;j2<4;j2++){
          const f16x8 vf = *(const f16x8*)((const char*)&Vl[(j2*16+l16)*64] + ((ks*64 + l4*16) ^ swz));
          o[mi][j2] = __builtin_amdgcn_mfma_f32_16x16x32_f16(pf, vf, o[mi][j2], 0,0,0);
        }
        osum[mi] = __builtin_amdgcn_mfma_f32_16x16x32_f16(pf, onesv, osum[mi], 0,0,0);
      }
      __builtin_amdgcn_s_setprio(0);
    }
  }
  // epilogue: o rows are q = mi*16 + l4*4 + r; osum has the row-sum in the SAME layout
  #pragma unroll
  for(int mi=0;mi<2;mi++){
    #pragma unroll
    for(int r=0;r<4;r++){
      const float iv = 1.f/osum[mi][r];
      const int row = q0 + w*32 + mi*16 + l4*4 + r;
      #pragma unroll
      for(int j2=0;j2<4;j2++)
        aout[(size_t)row*DIMS + h*HD + j2*16 + l16] = (h16)(o[mi][j2][r]*iv);
    }
  }
}

// ---------------- launch ----------------
extern "C" void kernel_launch(void* const* d_in, const int* in_sizes, int n_in,
                              void* d_out, int out_size, void* d_ws, size_t ws_size,
                              hipStream_t stream){
  const float* x    = (const float*)d_in[0];
  const float* qn_g = (const float*)d_in[1];
  const float* qn_b = (const float*)d_in[2];
  const float* Wq   = (const float*)d_in[3];
  const float* bq   = (const float*)d_in[4];
  const float* kvn_g= (const float*)d_in[5];
  const float* kvn_b= (const float*)d_in[6];
  const float* Wkv  = (const float*)d_in[7];
  const float* bkv  = (const float*)d_in[8];
  const float* Wout = (const float*)d_in[9];
  const float* bout = (const float*)d_in[10];
  const float* ln_g = (const float*)d_in[11];
  const float* ln_b = (const float*)d_in[12];
  const int*  skip  = (const int*)d_in[13];

  // Workspace budget ~75 MB; refuse (clean fail, no OOB scribble) if undersized.
  if(ws_size < (size_t)79*1000*1000) return;

  char* p = (char*)d_ws;
  size_t off = 0;
  auto take = [&](size_t n)->char*{
    char* r = p + off; off = (off + n + 255) & ~(size_t)255; return r;
  };
  h16*    xhat = (h16*)   take((size_t)SEQ*DIMS*2);   // reused as abuf after kv GEMM
  float*  mag  = (float*) take((size_t)SEQ*4);
  float2* tab  = (float2*)take((size_t)SEQ*32*8);
  h16*    WqT  = (h16*)   take((size_t)1024*1024*2);
  h16*    WkvT = (h16*)   take((size_t)2048*1024*2);
  h16*    WoutT= (h16*)   take((size_t)1024*1024*2);
  float*  bqp  = (float*) take(1024*4);
  float*  bkvp = (float*) take(2048*4);
  h16*    qn   = (h16*)   take((size_t)NH*SEQ*HD*2);
  h16*    kn   = (h16*)   take((size_t)NH*SEQ*HD*2);
  h16*    vT   = (h16*)   take((size_t)NH*HD*SEQ*2);
  float*  partq= (float*) take((size_t)16*1024*4);
  float*  partkv=(float*) take((size_t)16*2048*4);
  h16*    abuf = xhat;   // alias: xhat dead after kv GEMM, attn writes after

  k_ln_stats<<<dim3(SEQ), dim3(256), 0, stream>>>(x, xhat, mag);
  k_sincos<<<dim3(SEQ*32/256), dim3(256), 0, stream>>>(tab);
  k_fold_part2<<<dim3(12,16), dim3(256), 0, stream>>>(Wq, qn_b, Wkv, kvn_b, partq, partkv);
  k_fold_sum2<<<dim3(12), dim3(256), 0, stream>>>(partq, partkv, bq, bkv, bqp, bkvp);
  k_prep_w3<<<dim3(64,16), dim3(256), 0, stream>>>(Wq, qn_g, Wkv, kvn_g, Wout, WqT, WkvT, WoutT);
  k_gemm<1><<<dim3(8,64),  dim3(256), 0, stream>>>(xhat, WqT,  bqp, nullptr, qn, nullptr,
                                                   mag, tab, ln_g, ln_b, 1024, skip);
  k_gemm<2><<<dim3(16,64), dim3(256), 0, stream>>>(xhat, WkvT, bkvp, nullptr, kn, vT,
                                                   mag, tab, ln_g, ln_b, 2048, skip);
  k_pad_vt<<<dim3(1), dim3(256), 0, stream>>>(vT, skip);
  k_attn<<<dim3(16,64), dim3(256), 0, stream>>>(qn, kn, vT, abuf, skip);
  k_gemm<0><<<dim3(8,64), dim3(256), 0, stream>>>(abuf, WoutT, bout, (float*)d_out,
                                                  nullptr, nullptr, nullptr, nullptr,
                                                  nullptr, nullptr, 1024, skip);
}

// Round 20
// 249.070 us; speedup vs baseline: 2.4848x; 1.0003x over previous
//
#include <hip/hip_runtime.h>
#include <hip/hip_bf16.h>
#include <math.h>

#define SEQ 8192
#define DIMS 1024
#define NH 16
#define HD 64

typedef _Float16 h16;
typedef __attribute__((ext_vector_type(8))) _Float16 f16x8;
typedef __attribute__((ext_vector_type(4))) _Float16 h16x4;
typedef __attribute__((ext_vector_type(4))) float f32x4;

#if defined(__has_builtin)
#if __has_builtin(__builtin_amdgcn_global_load_lds)
#define USE_GLOAD 1
#endif
#if __has_builtin(__builtin_amdgcn_exp2f)
#define FEXP2(x) __builtin_amdgcn_exp2f(x)
#endif
#endif
#ifndef USE_GLOAD
#define USE_GLOAD 0
#endif
#ifndef FEXP2
#define FEXP2(x) exp2f(x)
#endif

__device__ __forceinline__ void gload16(h16* lds, const h16* g){
#if USE_GLOAD
  __builtin_amdgcn_global_load_lds((const __attribute__((address_space(1))) void*)g,
                                   (__attribute__((address_space(3))) void*)lds, 16, 0, 0);
#endif
}

// ---------------- LN stats over x: xhat (fp16) + mag ----------------
__global__ void k_ln_stats(const float* __restrict__ x, h16* __restrict__ xhat,
                           float* __restrict__ mag){
  const int row = blockIdx.x, t = threadIdx.x;
  float4 v = ((const float4*)(x + (size_t)row*DIMS))[t];
  float s = v.x+v.y+v.z+v.w;
  float s2 = v.x*v.x+v.y*v.y+v.z*v.z+v.w*v.w;
  #pragma unroll
  for(int m=1;m<64;m<<=1){ s += __shfl_xor(s,m,64); s2 += __shfl_xor(s2,m,64); }
  __shared__ float ls[4], ls2[4];
  const int wid = t>>6;
  if((t&63)==0){ ls[wid]=s; ls2[wid]=s2; }
  __syncthreads();
  s  = ls[0]+ls[1]+ls[2]+ls[3];
  s2 = ls2[0]+ls2[1]+ls2[2]+ls2[3];
  const float mean = s*(1.f/DIMS);
  const float var  = s2*(1.f/DIMS) - mean*mean;
  const float rstd = rsqrtf(var + 1e-5f);
  if(t==0) mag[row] = mean;
  h16x4 o;
  o[0] = (h16)((v.x-mean)*rstd); o[1] = (h16)((v.y-mean)*rstd);
  o[2] = (h16)((v.z-mean)*rstd); o[3] = (h16)((v.w-mean)*rstd);
  ((h16x4*)(xhat + (size_t)row*DIMS))[t] = o;
}

// ---------------- cos/sin table (freq computed per block; f64 range-reduce) ----------------
__global__ void k_sincos(float2* __restrict__ tab){
  __shared__ double fr[32];
  const int t = threadIdx.x;
  if(t < 32) fr[t] = 0.2 * (pow(21.0, (double)t / 31.0) - 1.0);
  __syncthreads();
  const int id = blockIdx.x*256 + t;   // 8192*32 total
  const int tt = id >> 5, d = id & 31;
  const double ang = (double)tt * fr[d];
  const double k = rint(ang * 0.15915494309189535);
  const float red = (float)(ang - k * 6.283185307179586);
  float s, c;
  __sincosf(red, &s, &c);
  tab[id] = make_float2(c, s);
}

// ------- fused deterministic bias folds (disjoint outputs, single writer/elem) -------
__global__ void k_fold_part2(const float* __restrict__ Wq, const float* __restrict__ qb_ln,
                             const float* __restrict__ Wkv, const float* __restrict__ kvb_ln,
                             float* __restrict__ partq, float* __restrict__ partkv){
  const int bx = blockIdx.x, ib = blockIdx.y;
  const float* W; const float* bln; float* part; int C, j;
  if(bx < 4){ W = Wq;  bln = qb_ln;  part = partq;  C = 1024; j = bx*256 + threadIdx.x; }
  else      { W = Wkv; bln = kvb_ln; part = partkv; C = 2048; j = (bx-4)*256 + threadIdx.x; }
  float acc = 0.f;
  const int i0 = ib*64;
  #pragma unroll 4
  for(int i=i0;i<i0+64;i++) acc += bln[i]*W[(size_t)i*C + j];
  part[(size_t)ib*C + j] = acc;
}
__global__ void k_fold_sum2(const float* __restrict__ partq, const float* __restrict__ partkv,
                            const float* __restrict__ bq, const float* __restrict__ bkv,
                            float* __restrict__ bqp, float* __restrict__ bkvp){
  const int bx = blockIdx.x;
  if(bx < 4){
    const int j = bx*256 + threadIdx.x;
    float a = bq[j];
    #pragma unroll
    for(int ib=0; ib<16; ib++) a += partq[(size_t)ib*1024 + j];
    bqp[j] = a;
  } else {
    const int j = (bx-4)*256 + threadIdx.x;
    float a = bkv[j];
    #pragma unroll
    for(int ib=0; ib<16; ib++) a += partkv[(size_t)ib*2048 + j];
    bkvp[j] = a;
  }
}

// ------- fused weight prep: Wt[j][i] = g[i]*W[i][j] (fp16), 3 weights in one grid -------
__global__ void k_prep_w3(const float* __restrict__ Wq, const float* __restrict__ qg,
                          const float* __restrict__ Wkv, const float* __restrict__ kvg,
                          const float* __restrict__ Wout,
                          h16* __restrict__ WqT, h16* __restrict__ WkvT, h16* __restrict__ WoutT){
  __shared__ float tile[64][65];
  const int bx = blockIdx.x;
  const float* W; const float* g; h16* Wt; int C, cb;
  if(bx < 16)      { W = Wq;   g = qg;      Wt = WqT;   C = 1024; cb = bx; }
  else if(bx < 48) { W = Wkv;  g = kvg;     Wt = WkvT;  C = 2048; cb = bx-16; }
  else             { W = Wout; g = nullptr; Wt = WoutT; C = 1024; cb = bx-48; }
  const int R = 1024;
  const int c0 = cb*64, r0 = blockIdx.y*64;
  const int t = threadIdx.x;
  const int cl = t & 63, rl0 = t >> 6;
  #pragma unroll
  for(int i=0;i<16;i++){
    const int r = rl0 + i*4;
    const float w = W[(size_t)(r0+r)*C + c0 + cl];
    const float gg = g ? g[r0+r] : 1.f;
    tile[r][cl] = w*gg;
  }
  __syncthreads();
  const int jl = t >> 2, ic = (t & 3)*16;
  h16* dst = Wt + (size_t)(c0+jl)*R + r0 + ic;
  #pragma unroll
  for(int i=0;i<16;i+=4){
    h16x4 o;
    o[0] = (h16)tile[ic+i+0][jl];
    o[1] = (h16)tile[ic+i+1][jl];
    o[2] = (h16)tile[ic+i+2][jl];
    o[3] = (h16)tile[ic+i+3][jl];
    *(h16x4*)(dst + i) = o;
  }
}

// MODE 0: plain f32 C=A@Bt+bias   (final out GEMM)
// MODE 1: Q GEMM, epilogue RoPE + head-LN -> OutB=qn (x 0.125*log2e)
// MODE 2: KV GEMM (compacted strided rows); cols<1024: K path (RoPE+LN -> OutB=kn),
//         cols>=1024: V path (bias only, LDS transpose -> vT[h][d][key])
template<int MODE>
__global__ __launch_bounds__(256) void k_gemm(
    const h16* __restrict__ A, const h16* __restrict__ Bt,
    const float* __restrict__ bias, float* __restrict__ Cf,
    h16* __restrict__ OutB, h16* __restrict__ vT,
    const float* __restrict__ mag, const float2* __restrict__ tab,
    const float* __restrict__ lg, const float* __restrict__ lb,
    const int N, const int* __restrict__ skip_p){
  int M = SEQ, pitchA = DIMS, st = 1;
  if(MODE==2){
    st = max(1, 4 - skip_p[0]);
    M = (SEQ + st - 1)/st;
    pitchA = st*DIMS;
  }
  const int m0 = blockIdx.y*128, n0 = blockIdx.x*128;
  if(m0 >= M) return;
  __shared__ h16 smem[(MODE==2) ? 128*136 : 8192];
  h16* As = smem;
  h16* Bs = smem + 4096;
  const int t = threadIdx.x;
  const int w = t>>6, l = t&63, l4 = l>>4, l16 = l&15;
  const int wm = w>>1, wn = w&1;
  f32x4 acc[4][4];
  #pragma unroll
  for(int i=0;i<4;i++)
    #pragma unroll
    for(int j=0;j<4;j++)
      #pragma unroll
      for(int r=0;r<4;r++) acc[i][j][r] = 0.f;
  for(int k0=0;k0<1024;k0+=32){
    __syncthreads();
    #pragma unroll
    for(int c=t;c<512;c+=256){
      const int row = c>>2, kp = (c&3)*8;
      int ar = m0+row; if(ar > M-1) ar = M-1;
#if USE_GLOAD
      gload16(&As[row*32+kp], A + (size_t)ar*pitchA + k0 + kp);
      gload16(&Bs[row*32+kp], Bt + (size_t)(n0+row)*1024 + k0 + kp);
#else
      *(f16x8*)(&As[row*32+kp]) = *(const f16x8*)(A + (size_t)ar*pitchA + k0 + kp);
      *(f16x8*)(&Bs[row*32+kp]) = *(const f16x8*)(Bt + (size_t)(n0+row)*1024 + k0 + kp);
#endif
    }
    __syncthreads();
    f16x8 af[4], bfr[4];
    #pragma unroll
    for(int i=0;i<4;i++){
      af[i]  = *(const f16x8*)(&As[(wm*64 + i*16 + l16)*32 + l4*8]);
      bfr[i] = *(const f16x8*)(&Bs[(wn*64 + i*16 + l16)*32 + l4*8]);
    }
    #pragma unroll
    for(int i=0;i<4;i++)
      #pragma unroll
      for(int j=0;j<4;j++)
        acc[i][j] = __builtin_amdgcn_mfma_f32_16x16x32_f16(af[i], bfr[j], acc[i][j], 0,0,0);
  }

  if(MODE==0){
    #pragma unroll
    for(int i=0;i<4;i++){
      const int rb = m0 + wm*64 + i*16 + l4*4;
      #pragma unroll
      for(int j=0;j<4;j++){
        const int col = n0 + wn*64 + j*16 + l16;
        const float bb = bias[col];
        #pragma unroll
        for(int r=0;r<4;r++)
          Cf[(size_t)(rb+r)*N + col] = acc[i][j][r] + bb;
      }
    }
    return;
  }

  float biasv[4];
  #pragma unroll
  for(int j=0;j<4;j++) biasv[j] = bias[n0 + wn*64 + j*16 + l16];

  const bool vpath = (MODE==2) && (n0 >= 1024);
  if(!vpath){
    // ---- RoPE + per-head LN epilogue (Q or K) ----
    float gv[4], bv[4];
    #pragma unroll
    for(int j=0;j<4;j++){ gv[j] = lg[j*16+l16]; bv[j] = lb[j*16+l16]; }
    const int h = (n0>>6) + wn;
    const float scl = (MODE==1) ? 0.125f*1.44269504f : 1.0f;   // fold 1/sqrt(64) * log2(e)
    const float sgn = (l16&1) ? 1.f : -1.f;
    #pragma unroll
    for(int i=0;i<4;i++){
      #pragma unroll
      for(int r=0;r<4;r++){
        int row = m0 + wm*64 + i*16 + l4*4 + r;
        const int rowc = (row < M) ? row : (M-1);
        const int tpos = (MODE==2) ? rowc*st : rowc;
        const float mg = mag[tpos];
        float v[4], pr[4], o4[4];
        #pragma unroll
        for(int j=0;j<4;j++) v[j] = acc[i][j][r] + biasv[j];
        #pragma unroll
        for(int j=0;j<4;j++) pr[j] = __shfl_xor(v[j], 1);
        float s1 = 0.f, s2 = 0.f;
        #pragma unroll
        for(int j=0;j<4;j++){
          const float2 cs = tab[(size_t)tpos*32 + j*8 + (l16>>1)];
          const float e = mg * (v[j]*cs.x + sgn*pr[j]*cs.y);
          o4[j] = e; s1 += e; s2 += e*e;
        }
        #pragma unroll
        for(int mm=1;mm<16;mm<<=1){ s1 += __shfl_xor(s1,mm,64); s2 += __shfl_xor(s2,mm,64); }
        const float mean = s1*(1.f/HD);
        const float var  = s2*(1.f/HD) - mean*mean;
        const float rstd = rsqrtf(var + 1e-5f);
        if(row < M){
          h16* dst = OutB + ((size_t)h*SEQ + row)*HD;
          #pragma unroll
          for(int j=0;j<4;j++)
            dst[j*16 + l16] = (h16)(((o4[j]-mean)*rstd*gv[j] + bv[j])*scl);
        }
      }
    }
  } else {
    // ---- V path: bias, LDS transpose, coalesced vT[h][d][key] writes ----
    __syncthreads();
    #pragma unroll
    for(int i=0;i<4;i++)
      #pragma unroll
      for(int j=0;j<4;j++)
        #pragma unroll
        for(int r=0;r<4;r++){
          const int key = wm*64 + i*16 + l4*4 + r;
          smem[(wn*64 + j*16 + l16)*136 + key] = (h16)(acc[i][j][r] + biasv[j]);
        }
    __syncthreads();
    const int rowT = t>>1, dh = rowT & 63, hloc = rowT>>6;
    const int hglob = ((n0-1024)>>6) + hloc;
    const h16* src = &smem[rowT*136 + (t&1)*64];
    h16* dstv = vT + ((size_t)hglob*HD + dh)*SEQ + m0 + (t&1)*64;
    #pragma unroll
    for(int c=0;c<64;c+=4)
      *(h16x4*)(dstv+c) = *(const h16x4*)(src+c);
  }
}

// ---------------- zero-pad vT tail keys up to 64-boundary ----------------
__global__ void k_pad_vt(h16* __restrict__ vT, const int* __restrict__ skip_p){
  const int st = max(1, 4 - skip_p[0]);
  const int n_kv = (SEQ + st - 1)/st;
  const int kb = ((n_kv + 63)/64)*64;
  const int pad = min(kb, SEQ) - n_kv;
  if(pad <= 0) return;
  const int total = NH*HD*pad;
  for(int i = threadIdx.x; i < total; i += 256){
    const int key = n_kv + (i % pad);
    const int hd = i / pad;
    vT[(size_t)hd*SEQ + key] = (h16)0.f;
  }
}

// ---------------- flash attention: synchronous single-buffer staging (GEMM contract) ----------------
// grid (head=16, qblk=64): linear id = h + 16*qb -> XCD = h&7 -> 2 heads/XCD L2
// BYTE-IDENTICAL to round-14's verified k_attn.
__launch_bounds__(256)
__global__ void k_attn(const h16* __restrict__ qn, const h16* __restrict__ kn,
                       const h16* __restrict__ vT, h16* __restrict__ aout,
                       const int* __restrict__ skip_p){
  const int st = max(1, 4 - skip_p[0]);
  const int n_kv = (SEQ + st - 1)/st;
  const int h = blockIdx.x, q0 = blockIdx.y*128;
  const int w = threadIdx.x >> 6, l = threadIdx.x & 63;
  const int l4 = l >> 4, l16 = l & 15;
  __shared__ __align__(16) h16 Kl[64*64];
  __shared__ __align__(16) h16 Vl[64*64];
  __shared__ __align__(16) h16 Pl[4][16*64];   // per-wave, per-mi overwrite
  const h16* Qh = qn + (size_t)h*SEQ*HD;
  const h16* Kh = kn + (size_t)h*SEQ*HD;
  const h16* Vh = vT + (size_t)h*HD*SEQ;
  // staging geometry: 8 rows x 128B per gload; swizzled GLOBAL source, linear LDS dest (rule 21)
  const int srow = l >> 3;
  const int scol = ((l & 7) << 4) ^ (srow << 4);   // byte offset within 128B row
  const int swz  = (l16 & 7) << 4;                 // read-side swizzle (byte)

  f16x8 onesv;
  #pragma unroll
  for(int i=0;i<8;i++) onesv[i] = (h16)1.f;
  const f32x4 zf = {0.f, 0.f, 0.f, 0.f};           // hoisted zero C-operand

  f16x8 qf[2][2];
  #pragma unroll
  for(int mi=0;mi<2;mi++)
    #pragma unroll
    for(int ks=0;ks<2;ks++)
      qf[mi][ks] = *(const f16x8*)(Qh + (size_t)(q0 + w*32 + mi*16 + l16)*HD + ks*32 + l4*8);
  f32x4 o[2][4], osum[2];
  float mrow[2];
  #pragma unroll
  for(int mi=0;mi<2;mi++){
    mrow[mi] = -1e30f;
    #pragma unroll
    for(int r=0;r<4;r++) osum[mi][r] = 0.f;
    #pragma unroll
    for(int j=0;j<4;j++)
      #pragma unroll
      for(int r=0;r<4;r++) o[mi][j][r] = 0.f;
  }

  const int nkb = (n_kv + 63) >> 6;
  for(int kb=0; kb<nkb; kb++){
    const int kb0 = kb*64, r0 = w*16;
    // ---- synchronous stage (exact GEMM contract: barrier / gload / barrier) ----
    __syncthreads();   // all waves done reading previous tile
    gload16(&Kl[(r0+0)*64], (const h16*)((const char*)(Kh + (size_t)(kb0+r0+srow)*HD) + scol));
    gload16(&Kl[(r0+8)*64], (const h16*)((const char*)(Kh + (size_t)(kb0+r0+8+srow)*HD) + scol));
    gload16(&Vl[(r0+0)*64], (const h16*)((const char*)(Vh + (size_t)(r0+srow)*SEQ + kb0) + scol));
    gload16(&Vl[(r0+8)*64], (const h16*)((const char*)(Vh + (size_t)(r0+8+srow)*SEQ + kb0) + scol));
    __syncthreads();   // compiler-managed vmcnt drain; tile visible to all waves
    f32x4 S[2][4];
    __builtin_amdgcn_s_setprio(1);
    {   // ks = 0: C = zf (no per-iter zero-init of S)
      f16x8 kf[4];
      #pragma unroll
      for(int nj=0;nj<4;nj++)
        kf[nj] = *(const f16x8*)((const char*)&Kl[(nj*16+l16)*64] + ((0*64 + l4*16) ^ swz));
      #pragma unroll
      for(int mi=0;mi<2;mi++)
        #pragma unroll
        for(int nj=0;nj<4;nj++)
          S[mi][nj] = __builtin_amdgcn_mfma_f32_16x16x32_f16(kf[nj], qf[mi][0], zf, 0,0,0);
    }
    {   // ks = 1: accumulate
      f16x8 kf[4];
      #pragma unroll
      for(int nj=0;nj<4;nj++)
        kf[nj] = *(const f16x8*)((const char*)&Kl[(nj*16+l16)*64] + ((1*64 + l4*16) ^ swz));
      #pragma unroll
      for(int mi=0;mi<2;mi++)
        #pragma unroll
        for(int nj=0;nj<4;nj++)
          S[mi][nj] = __builtin_amdgcn_mfma_f32_16x16x32_f16(kf[nj], qf[mi][1], S[mi][nj], 0,0,0);
    }
    __builtin_amdgcn_s_setprio(0);
    // tail masking: only on the last k-tile (uniform branch; no-op when n_kv%64==0)
    if(kb == nkb-1 && (n_kv & 63)){
      #pragma unroll
      for(int nj=0;nj<4;nj++){
        const int keyb = kb0 + nj*16 + l4*4;
        #pragma unroll
        for(int r=0;r<4;r++)
          if(keyb + r >= n_kv){ S[0][nj][r] = -1e30f; S[1][nj][r] = -1e30f; }
      }
    }
    // per-mi: softmax -> P write -> lgkm drain -> PV (+osum MFMA)
    #pragma unroll
    for(int mi=0;mi<2;mi++){
      f32x4 t4;
      #pragma unroll
      for(int r=0;r<4;r++)
        t4[r] = fmaxf(fmaxf(S[mi][0][r],S[mi][1][r]), fmaxf(S[mi][2][r],S[mi][3][r]));
      float mx = fmaxf(fmaxf(t4[0],t4[1]), fmaxf(t4[2],t4[3]));
      mx = fmaxf(mx, __shfl_xor(mx,16,64));
      mx = fmaxf(mx, __shfl_xor(mx,32,64));
      if(!__all(mx <= mrow[mi] + 11.5f)){     // defer-max, THR ~ 8 nats in log2 units
        const float mnew = fmaxf(mrow[mi], mx);
        const float fac = FEXP2(mrow[mi] - mnew);
        mrow[mi] = mnew;
        #pragma unroll
        for(int r=0;r<4;r++){
          const float f2 = __shfl(fac, (l & 48) | (l4*4 + r), 64);
          #pragma unroll
          for(int j2=0;j2<4;j2++) o[mi][j2][r] *= f2;
          osum[mi][r] *= f2;
        }
      }
      #pragma unroll
      for(int nj=0;nj<4;nj++){
        #pragma unroll
        for(int r=0;r<4;r++)
          S[mi][nj][r] = FEXP2(S[mi][nj][r] - mrow[mi]);
        const unsigned plo = __builtin_bit_cast(unsigned,
            __builtin_amdgcn_cvt_pkrtz(S[mi][nj][0], S[mi][nj][1]));
        const unsigned phi = __builtin_bit_cast(unsigned,
            __builtin_amdgcn_cvt_pkrtz(S[mi][nj][2], S[mi][nj][3]));
        uint2 pw; pw.x = plo; pw.y = phi;
        *(uint2*)((char*)&Pl[w][l16*64] + ((nj*32 + l4*8) ^ swz)) = pw;
      }
      asm volatile("s_waitcnt lgkmcnt(0)" ::: "memory");
      __builtin_amdgcn_sched_barrier(0);
      __builtin_amdgcn_s_setprio(1);
      #pragma unroll
      for(int ks=0;ks<2;ks++){
        const f16x8 pf = *(const f16x8*)((const char*)&Pl[w][l16*64] + ((ks*64 + l4*16) ^ swz));
        #pragma unroll
        for(int j2=0;j2<4;j2++){
          const f16x8 vf = *(const f16x8*)((const char*)&Vl[(j2*16+l16)*64] + ((ks*64 + l4*16) ^ swz));
          o[mi][j2] = __builtin_amdgcn_mfma_f32_16x16x32_f16(pf, vf, o[mi][j2], 0,0,0);
        }
        osum[mi] = __builtin_amdgcn_mfma_f32_16x16x32_f16(pf, onesv, osum[mi], 0,0,0);
      }
      __builtin_amdgcn_s_setprio(0);
    }
  }
  // epilogue: o rows are q = mi*16 + l4*4 + r; osum has the row-sum in the SAME layout
  #pragma unroll
  for(int mi=0;mi<2;mi++){
    #pragma unroll
    for(int r=0;r<4;r++){
      const float iv = 1.f/osum[mi][r];
      const int row = q0 + w*32 + mi*16 + l4*4 + r;
      #pragma unroll
      for(int j2=0;j2<4;j2++)
        aout[(size_t)row*DIMS + h*HD + j2*16 + l16] = (h16)(o[mi][j2][r]*iv);
    }
  }
}

// ---------------- launch ----------------
extern "C" void kernel_launch(void* const* d_in, const int* in_sizes, int n_in,
                              void* d_out, int out_size, void* d_ws, size_t ws_size,
                              hipStream_t stream){
  const float* x    = (const float*)d_in[0];
  const float* qn_g = (const float*)d_in[1];
  const float* qn_b = (const float*)d_in[2];
  const float* Wq   = (const float*)d_in[3];
  const float* bq   = (const float*)d_in[4];
  const float* kvn_g= (const float*)d_in[5];
  const float* kvn_b= (const float*)d_in[6];
  const float* Wkv  = (const float*)d_in[7];
  const float* bkv  = (const float*)d_in[8];
  const float* Wout = (const float*)d_in[9];
  const float* bout = (const float*)d_in[10];
  const float* ln_g = (const float*)d_in[11];
  const float* ln_b = (const float*)d_in[12];
  const int*  skip  = (const int*)d_in[13];

  // Workspace budget ~75 MB; refuse (clean fail, no OOB scribble) if undersized.
  if(ws_size < (size_t)79*1000*1000) return;

  char* p = (char*)d_ws;
  size_t off = 0;
  auto take = [&](size_t n)->char*{
    char* r = p + off; off = (off + n + 255) & ~(size_t)255; return r;
  };
  h16*    xhat = (h16*)   take((size_t)SEQ*DIMS*2);   // reused as abuf after kv GEMM
  float*  mag  = (float*) take((size_t)SEQ*4);
  float2* tab  = (float2*)take((size_t)SEQ*32*8);
  h16*    WqT  = (h16*)   take((size_t)1024*1024*2);
  h16*    WkvT = (h16*)   take((size_t)2048*1024*2);
  h16*    WoutT= (h16*)   take((size_t)1024*1024*2);
  float*  bqp  = (float*) take(1024*4);
  float*  bkvp = (float*) take(2048*4);
  h16*    qn   = (h16*)   take((size_t)NH*SEQ*HD*2);
  h16*    kn   = (h16*)   take((size_t)NH*SEQ*HD*2);
  h16*    vT   = (h16*)   take((size_t)NH*HD*SEQ*2);
  float*  partq= (float*) take((size_t)16*1024*4);
  float*  partkv=(float*) take((size_t)16*2048*4);
  h16*    abuf = xhat;   // alias: xhat dead after kv GEMM, attn writes after

  k_ln_stats<<<dim3(SEQ), dim3(256), 0, stream>>>(x, xhat, mag);
  k_sincos<<<dim3(SEQ*32/256), dim3(256), 0, stream>>>(tab);
  k_fold_part2<<<dim3(12,16), dim3(256), 0, stream>>>(Wq, qn_b, Wkv, kvn_b, partq, partkv);
  k_fold_sum2<<<dim3(12), dim3(256), 0, stream>>>(partq, partkv, bq, bkv, bqp, bkvp);
  k_prep_w3<<<dim3(64,16), dim3(256), 0, stream>>>(Wq, qn_g, Wkv, kvn_g, Wout, WqT, WkvT, WoutT);
  k_gemm<1><<<dim3(8,64),  dim3(256), 0, stream>>>(xhat, WqT,  bqp, nullptr, qn, nullptr,
                                                   mag, tab, ln_g, ln_b, 1024, skip);
  k_gemm<2><<<dim3(16,64), dim3(256), 0, stream>>>(xhat, WkvT, bkvp, nullptr, kn, vT,
                                                   mag, tab, ln_g, ln_b, 2048, skip);
  k_pad_vt<<<dim3(1), dim3(256), 0, stream>>>(vT, skip);
  k_attn<<<dim3(16,64), dim3(256), 0, stream>>>(qn, kn, vT, abuf, skip);
  k_gemm<0><<<dim3(8,64), dim3(256), 0, stream>>>(abuf, WoutT, bout, (float*)d_out,
                                                  nullptr, nullptr, nullptr, nullptr,
                                                  nullptr, nullptr, 1024, skip);
}

// Round 22
// 249.026 us; speedup vs baseline: 2.4852x; 1.0002x over previous
//
#include <hip/hip_runtime.h>
#include <hip/hip_bf16.h>
#include <math.h>

#define SEQ 8192
#define DIMS 1024
#define NH 16
#define HD 64

typedef _Float16 h16;
typedef __attribute__((ext_vector_type(8))) _Float16 f16x8;
typedef __attribute__((ext_vector_type(4))) _Float16 h16x4;
typedef __attribute__((ext_vector_type(4))) float f32x4;

#if defined(__has_builtin)
#if __has_builtin(__builtin_amdgcn_global_load_lds)
#define USE_GLOAD 1
#endif
#if __has_builtin(__builtin_amdgcn_exp2f)
#define FEXP2(x) __builtin_amdgcn_exp2f(x)
#endif
#endif
#ifndef USE_GLOAD
#define USE_GLOAD 0
#endif
#ifndef FEXP2
#define FEXP2(x) exp2f(x)
#endif

__device__ __forceinline__ void gload16(h16* lds, const h16* g){
#if USE_GLOAD
  __builtin_amdgcn_global_load_lds((const __attribute__((address_space(1))) void*)g,
                                   (__attribute__((address_space(3))) void*)lds, 16, 0, 0);
#endif
}

// ---------------- LN stats over x: xhat (fp16) + mag ----------------
__global__ void k_ln_stats(const float* __restrict__ x, h16* __restrict__ xhat,
                           float* __restrict__ mag){
  const int row = blockIdx.x, t = threadIdx.x;
  float4 v = ((const float4*)(x + (size_t)row*DIMS))[t];
  float s = v.x+v.y+v.z+v.w;
  float s2 = v.x*v.x+v.y*v.y+v.z*v.z+v.w*v.w;
  #pragma unroll
  for(int m=1;m<64;m<<=1){ s += __shfl_xor(s,m,64); s2 += __shfl_xor(s2,m,64); }
  __shared__ float ls[4], ls2[4];
  const int wid = t>>6;
  if((t&63)==0){ ls[wid]=s; ls2[wid]=s2; }
  __syncthreads();
  s  = ls[0]+ls[1]+ls[2]+ls[3];
  s2 = ls2[0]+ls2[1]+ls2[2]+ls2[3];
  const float mean = s*(1.f/DIMS);
  const float var  = s2*(1.f/DIMS) - mean*mean;
  const float rstd = rsqrtf(var + 1e-5f);
  if(t==0) mag[row] = mean;
  h16x4 o;
  o[0] = (h16)((v.x-mean)*rstd); o[1] = (h16)((v.y-mean)*rstd);
  o[2] = (h16)((v.z-mean)*rstd); o[3] = (h16)((v.w-mean)*rstd);
  ((h16x4*)(xhat + (size_t)row*DIMS))[t] = o;
}

// ---------------- cos/sin table (freq computed per block; f64 range-reduce) ----------------
__global__ void k_sincos(float2* __restrict__ tab){
  __shared__ double fr[32];
  const int t = threadIdx.x;
  if(t < 32) fr[t] = 0.2 * (pow(21.0, (double)t / 31.0) - 1.0);
  __syncthreads();
  const int id = blockIdx.x*256 + t;   // 8192*32 total
  const int tt = id >> 5, d = id & 31;
  const double ang = (double)tt * fr[d];
  const double k = rint(ang * 0.15915494309189535);
  const float red = (float)(ang - k * 6.283185307179586);
  float s, c;
  __sincosf(red, &s, &c);
  tab[id] = make_float2(c, s);
}

// ------- fused deterministic bias folds (disjoint outputs, single writer/elem) -------
__global__ void k_fold_part2(const float* __restrict__ Wq, const float* __restrict__ qb_ln,
                             const float* __restrict__ Wkv, const float* __restrict__ kvb_ln,
                             float* __restrict__ partq, float* __restrict__ partkv){
  const int bx = blockIdx.x, ib = blockIdx.y;
  const float* W; const float* bln; float* part; int C, j;
  if(bx < 4){ W = Wq;  bln = qb_ln;  part = partq;  C = 1024; j = bx*256 + threadIdx.x; }
  else      { W = Wkv; bln = kvb_ln; part = partkv; C = 2048; j = (bx-4)*256 + threadIdx.x; }
  float acc = 0.f;
  const int i0 = ib*64;
  #pragma unroll 4
  for(int i=i0;i<i0+64;i++) acc += bln[i]*W[(size_t)i*C + j];
  part[(size_t)ib*C + j] = acc;
}
__global__ void k_fold_sum2(const float* __restrict__ partq, const float* __restrict__ partkv,
                            const float* __restrict__ bq, const float* __restrict__ bkv,
                            float* __restrict__ bqp, float* __restrict__ bkvp){
  const int bx = blockIdx.x;
  if(bx < 4){
    const int j = bx*256 + threadIdx.x;
    float a = bq[j];
    #pragma unroll
    for(int ib=0; ib<16; ib++) a += partq[(size_t)ib*1024 + j];
    bqp[j] = a;
  } else {
    const int j = (bx-4)*256 + threadIdx.x;
    float a = bkv[j];
    #pragma unroll
    for(int ib=0; ib<16; ib++) a += partkv[(size_t)ib*2048 + j];
    bkvp[j] = a;
  }
}

// ------- fused weight prep: Wt[j][i] = g[i]*W[i][j] (fp16), 3 weights in one grid -------
__global__ void k_prep_w3(const float* __restrict__ Wq, const float* __restrict__ qg,
                          const float* __restrict__ Wkv, const float* __restrict__ kvg,
                          const float* __restrict__ Wout,
                          h16* __restrict__ WqT, h16* __restrict__ WkvT, h16* __restrict__ WoutT){
  __shared__ float tile[64][65];
  const int bx = blockIdx.x;
  const float* W; const float* g; h16* Wt; int C, cb;
  if(bx < 16)      { W = Wq;   g = qg;      Wt = WqT;   C = 1024; cb = bx; }
  else if(bx < 48) { W = Wkv;  g = kvg;     Wt = WkvT;  C = 2048; cb = bx-16; }
  else             { W = Wout; g = nullptr; Wt = WoutT; C = 1024; cb = bx-48; }
  const int R = 1024;
  const int c0 = cb*64, r0 = blockIdx.y*64;
  const int t = threadIdx.x;
  const int cl = t & 63, rl0 = t >> 6;
  #pragma unroll
  for(int i=0;i<16;i++){
    const int r = rl0 + i*4;
    const float w = W[(size_t)(r0+r)*C + c0 + cl];
    const float gg = g ? g[r0+r] : 1.f;
    tile[r][cl] = w*gg;
  }
  __syncthreads();
  const int jl = t >> 2, ic = (t & 3)*16;
  h16* dst = Wt + (size_t)(c0+jl)*R + r0 + ic;
  #pragma unroll
  for(int i=0;i<16;i+=4){
    h16x4 o;
    o[0] = (h16)tile[ic+i+0][jl];
    o[1] = (h16)tile[ic+i+1][jl];
    o[2] = (h16)tile[ic+i+2][jl];
    o[3] = (h16)tile[ic+i+3][jl];
    *(h16x4*)(dst + i) = o;
  }
}

// MODE 0: plain f32 C=A@Bt+bias   (final out GEMM)
// MODE 1: Q GEMM, epilogue RoPE + head-LN -> OutB=qn (x 0.125*log2e)
// MODE 2: KV GEMM (compacted strided rows); cols<1024: K path (RoPE+LN -> OutB=kn),
//         cols>=1024: V path (bias only, LDS transpose -> vT[h][d][key])
template<int MODE>
__global__ __launch_bounds__(256) void k_gemm(
    const h16* __restrict__ A, const h16* __restrict__ Bt,
    const float* __restrict__ bias, float* __restrict__ Cf,
    h16* __restrict__ OutB, h16* __restrict__ vT,
    const float* __restrict__ mag, const float2* __restrict__ tab,
    const float* __restrict__ lg, const float* __restrict__ lb,
    const int N, const int* __restrict__ skip_p){
  int M = SEQ, pitchA = DIMS, st = 1;
  if(MODE==2){
    st = max(1, 4 - skip_p[0]);
    M = (SEQ + st - 1)/st;
    pitchA = st*DIMS;
  }
  const int m0 = blockIdx.y*128, n0 = blockIdx.x*128;
  if(m0 >= M) return;
  __shared__ h16 smem[(MODE==2) ? 128*136 : 8192];
  h16* As = smem;
  h16* Bs = smem + 4096;
  const int t = threadIdx.x;
  const int w = t>>6, l = t&63, l4 = l>>4, l16 = l&15;
  const int wm = w>>1, wn = w&1;
  f32x4 acc[4][4];
  #pragma unroll
  for(int i=0;i<4;i++)
    #pragma unroll
    for(int j=0;j<4;j++)
      #pragma unroll
      for(int r=0;r<4;r++) acc[i][j][r] = 0.f;
  for(int k0=0;k0<1024;k0+=32){
    __syncthreads();
    #pragma unroll
    for(int c=t;c<512;c+=256){
      const int row = c>>2, kp = (c&3)*8;
      int ar = m0+row; if(ar > M-1) ar = M-1;
#if USE_GLOAD
      gload16(&As[row*32+kp], A + (size_t)ar*pitchA + k0 + kp);
      gload16(&Bs[row*32+kp], Bt + (size_t)(n0+row)*1024 + k0 + kp);
#else
      *(f16x8*)(&As[row*32+kp]) = *(const f16x8*)(A + (size_t)ar*pitchA + k0 + kp);
      *(f16x8*)(&Bs[row*32+kp]) = *(const f16x8*)(Bt + (size_t)(n0+row)*1024 + k0 + kp);
#endif
    }
    __syncthreads();
    f16x8 af[4], bfr[4];
    #pragma unroll
    for(int i=0;i<4;i++){
      af[i]  = *(const f16x8*)(&As[(wm*64 + i*16 + l16)*32 + l4*8]);
      bfr[i] = *(const f16x8*)(&Bs[(wn*64 + i*16 + l16)*32 + l4*8]);
    }
    #pragma unroll
    for(int i=0;i<4;i++)
      #pragma unroll
      for(int j=0;j<4;j++)
        acc[i][j] = __builtin_amdgcn_mfma_f32_16x16x32_f16(af[i], bfr[j], acc[i][j], 0,0,0);
  }

  if(MODE==0){
    #pragma unroll
    for(int i=0;i<4;i++){
      const int rb = m0 + wm*64 + i*16 + l4*4;
      #pragma unroll
      for(int j=0;j<4;j++){
        const int col = n0 + wn*64 + j*16 + l16;
        const float bb = bias[col];
        #pragma unroll
        for(int r=0;r<4;r++)
          Cf[(size_t)(rb+r)*N + col] = acc[i][j][r] + bb;
      }
    }
    return;
  }

  float biasv[4];
  #pragma unroll
  for(int j=0;j<4;j++) biasv[j] = bias[n0 + wn*64 + j*16 + l16];

  const bool vpath = (MODE==2) && (n0 >= 1024);
  if(!vpath){
    // ---- RoPE + per-head LN epilogue (Q or K) ----
    float gv[4], bv[4];
    #pragma unroll
    for(int j=0;j<4;j++){ gv[j] = lg[j*16+l16]; bv[j] = lb[j*16+l16]; }
    const int h = (n0>>6) + wn;
    const float scl = (MODE==1) ? 0.125f*1.44269504f : 1.0f;   // fold 1/sqrt(64) * log2(e)
    const float sgn = (l16&1) ? 1.f : -1.f;
    #pragma unroll
    for(int i=0;i<4;i++){
      #pragma unroll
      for(int r=0;r<4;r++){
        int row = m0 + wm*64 + i*16 + l4*4 + r;
        const int rowc = (row < M) ? row : (M-1);
        const int tpos = (MODE==2) ? rowc*st : rowc;
        const float mg = mag[tpos];
        float v[4], pr[4], o4[4];
        #pragma unroll
        for(int j=0;j<4;j++) v[j] = acc[i][j][r] + biasv[j];
        #pragma unroll
        for(int j=0;j<4;j++) pr[j] = __shfl_xor(v[j], 1);
        float s1 = 0.f, s2 = 0.f;
        #pragma unroll
        for(int j=0;j<4;j++){
          const float2 cs = tab[(size_t)tpos*32 + j*8 + (l16>>1)];
          const float e = mg * (v[j]*cs.x + sgn*pr[j]*cs.y);
          o4[j] = e; s1 += e; s2 += e*e;
        }
        #pragma unroll
        for(int mm=1;mm<16;mm<<=1){ s1 += __shfl_xor(s1,mm,64); s2 += __shfl_xor(s2,mm,64); }
        const float mean = s1*(1.f/HD);
        const float var  = s2*(1.f/HD) - mean*mean;
        const float rstd = rsqrtf(var + 1e-5f);
        if(row < M){
          h16* dst = OutB + ((size_t)h*SEQ + row)*HD;
          #pragma unroll
          for(int j=0;j<4;j++)
            dst[j*16 + l16] = (h16)(((o4[j]-mean)*rstd*gv[j] + bv[j])*scl);
        }
      }
    }
  } else {
    // ---- V path: bias, LDS transpose, coalesced vT[h][d][key] writes ----
    __syncthreads();
    #pragma unroll
    for(int i=0;i<4;i++)
      #pragma unroll
      for(int j=0;j<4;j++)
        #pragma unroll
        for(int r=0;r<4;r++){
          const int key = wm*64 + i*16 + l4*4 + r;
          smem[(wn*64 + j*16 + l16)*136 + key] = (h16)(acc[i][j][r] + biasv[j]);
        }
    __syncthreads();
    const int rowT = t>>1, dh = rowT & 63, hloc = rowT>>6;
    const int hglob = ((n0-1024)>>6) + hloc;
    const h16* src = &smem[rowT*136 + (t&1)*64];
    h16* dstv = vT + ((size_t)hglob*HD + dh)*SEQ + m0 + (t&1)*64;
    #pragma unroll
    for(int c=0;c<64;c+=4)
      *(h16x4*)(dstv+c) = *(const h16x4*)(src+c);
  }
}

// ---------------- zero-pad vT tail keys up to 64-boundary ----------------
__global__ void k_pad_vt(h16* __restrict__ vT, const int* __restrict__ skip_p){
  const int st = max(1, 4 - skip_p[0]);
  const int n_kv = (SEQ + st - 1)/st;
  const int kb = ((n_kv + 63)/64)*64;
  const int pad = min(kb, SEQ) - n_kv;
  if(pad <= 0) return;
  const int total = NH*HD*pad;
  for(int i = threadIdx.x; i < total; i += 256){
    const int key = n_kv + (i % pad);
    const int hd = i / pad;
    vT[(size_t)hd*SEQ + key] = (h16)0.f;
  }
}

// ---------------- flash attention: synchronous single-buffer staging (GEMM contract) ----------------
// grid (head=16, qblk=64): linear id = h + 16*qb -> XCD = h&7 -> 2 heads/XCD L2
// BYTE-IDENTICAL to round-14's verified k_attn.
__launch_bounds__(256)
__global__ void k_attn(const h16* __restrict__ qn, const h16* __restrict__ kn,
                       const h16* __restrict__ vT, h16* __restrict__ aout,
                       const int* __restrict__ skip_p){
  const int st = max(1, 4 - skip_p[0]);
  const int n_kv = (SEQ + st - 1)/st;
  const int h = blockIdx.x, q0 = blockIdx.y*128;
  const int w = threadIdx.x >> 6, l = threadIdx.x & 63;
  const int l4 = l >> 4, l16 = l & 15;
  __shared__ __align__(16) h16 Kl[64*64];
  __shared__ __align__(16) h16 Vl[64*64];
  __shared__ __align__(16) h16 Pl[4][16*64];   // per-wave, per-mi overwrite
  const h16* Qh = qn + (size_t)h*SEQ*HD;
  const h16* Kh = kn + (size_t)h*SEQ*HD;
  const h16* Vh = vT + (size_t)h*HD*SEQ;
  // staging geometry: 8 rows x 128B per gload; swizzled GLOBAL source, linear LDS dest (rule 21)
  const int srow = l >> 3;
  const int scol = ((l & 7) << 4) ^ (srow << 4);   // byte offset within 128B row
  const int swz  = (l16 & 7) << 4;                 // read-side swizzle (byte)

  f16x8 onesv;
  #pragma unroll
  for(int i=0;i<8;i++) onesv[i] = (h16)1.f;
  const f32x4 zf = {0.f, 0.f, 0.f, 0.f};           // hoisted zero C-operand

  f16x8 qf[2][2];
  #pragma unroll
  for(int mi=0;mi<2;mi++)
    #pragma unroll
    for(int ks=0;ks<2;ks++)
      qf[mi][ks] = *(const f16x8*)(Qh + (size_t)(q0 + w*32 + mi*16 + l16)*HD + ks*32 + l4*8);
  f32x4 o[2][4], osum[2];
  float mrow[2];
  #pragma unroll
  for(int mi=0;mi<2;mi++){
    mrow[mi] = -1e30f;
    #pragma unroll
    for(int r=0;r<4;r++) osum[mi][r] = 0.f;
    #pragma unroll
    for(int j=0;j<4;j++)
      #pragma unroll
      for(int r=0;r<4;r++) o[mi][j][r] = 0.f;
  }

  const int nkb = (n_kv + 63) >> 6;
  for(int kb=0; kb<nkb; kb++){
    const int kb0 = kb*64, r0 = w*16;
    // ---- synchronous stage (exact GEMM contract: barrier / gload / barrier) ----
    __syncthreads();   // all waves done reading previous tile
    gload16(&Kl[(r0+0)*64], (const h16*)((const char*)(Kh + (size_t)(kb0+r0+srow)*HD) + scol));
    gload16(&Kl[(r0+8)*64], (const h16*)((const char*)(Kh + (size_t)(kb0+r0+8+srow)*HD) + scol));
    gload16(&Vl[(r0+0)*64], (const h16*)((const char*)(Vh + (size_t)(r0+srow)*SEQ + kb0) + scol));
    gload16(&Vl[(r0+8)*64], (const h16*)((const char*)(Vh + (size_t)(r0+8+srow)*SEQ + kb0) + scol));
    __syncthreads();   // compiler-managed vmcnt drain; tile visible to all waves
    f32x4 S[2][4];
    __builtin_amdgcn_s_setprio(1);
    {   // ks = 0: C = zf (no per-iter zero-init of S)
      f16x8 kf[4];
      #pragma unroll
      for(int nj=0;nj<4;nj++)
        kf[nj] = *(const f16x8*)((const char*)&Kl[(nj*16+l16)*64] + ((0*64 + l4*16) ^ swz));
      #pragma unroll
      for(int mi=0;mi<2;mi++)
        #pragma unroll
        for(int nj=0;nj<4;nj++)
          S[mi][nj] = __builtin_amdgcn_mfma_f32_16x16x32_f16(kf[nj], qf[mi][0], zf, 0,0,0);
    }
    {   // ks = 1: accumulate
      f16x8 kf[4];
      #pragma unroll
      for(int nj=0;nj<4;nj++)
        kf[nj] = *(const f16x8*)((const char*)&Kl[(nj*16+l16)*64] + ((1*64 + l4*16) ^ swz));
      #pragma unroll
      for(int mi=0;mi<2;mi++)
        #pragma unroll
        for(int nj=0;nj<4;nj++)
          S[mi][nj] = __builtin_amdgcn_mfma_f32_16x16x32_f16(kf[nj], qf[mi][1], S[mi][nj], 0,0,0);
    }
    __builtin_amdgcn_s_setprio(0);
    // tail masking: only on the last k-tile (uniform branch; no-op when n_kv%64==0)
    if(kb == nkb-1 && (n_kv & 63)){
      #pragma unroll
      for(int nj=0;nj<4;nj++){
        const int keyb = kb0 + nj*16 + l4*4;
        #pragma unroll
        for(int r=0;r<4;r++)
          if(keyb + r >= n_kv){ S[0][nj][r] = -1e30f; S[1][nj][r] = -1e30f; }
      }
    }
    // per-mi: softmax -> P write -> lgkm drain -> PV (+osum MFMA)
    #pragma unroll
    for(int mi=0;mi<2;mi++){
      f32x4 t4;
      #pragma unroll
      for(int r=0;r<4;r++)
        t4[r] = fmaxf(fmaxf(S[mi][0][r],S[mi][1][r]), fmaxf(S[mi][2][r],S[mi][3][r]));
      float mx = fmaxf(fmaxf(t4[0],t4[1]), fmaxf(t4[2],t4[3]));
      mx = fmaxf(mx, __shfl_xor(mx,16,64));
      mx = fmaxf(mx, __shfl_xor(mx,32,64));
      if(!__all(mx <= mrow[mi] + 11.5f)){     // defer-max, THR ~ 8 nats in log2 units
        const float mnew = fmaxf(mrow[mi], mx);
        const float fac = FEXP2(mrow[mi] - mnew);
        mrow[mi] = mnew;
        #pragma unroll
        for(int r=0;r<4;r++){
          const float f2 = __shfl(fac, (l & 48) | (l4*4 + r), 64);
          #pragma unroll
          for(int j2=0;j2<4;j2++) o[mi][j2][r] *= f2;
          osum[mi][r] *= f2;
        }
      }
      #pragma unroll
      for(int nj=0;nj<4;nj++){
        #pragma unroll
        for(int r=0;r<4;r++)
          S[mi][nj][r] = FEXP2(S[mi][nj][r] - mrow[mi]);
        const unsigned plo = __builtin_bit_cast(unsigned,
            __builtin_amdgcn_cvt_pkrtz(S[mi][nj][0], S[mi][nj][1]));
        const unsigned phi = __builtin_bit_cast(unsigned,
            __builtin_amdgcn_cvt_pkrtz(S[mi][nj][2], S[mi][nj][3]));
        uint2 pw; pw.x = plo; pw.y = phi;
        *(uint2*)((char*)&Pl[w][l16*64] + ((nj*32 + l4*8) ^ swz)) = pw;
      }
      asm volatile("s_waitcnt lgkmcnt(0)" ::: "memory");
      __builtin_amdgcn_sched_barrier(0);
      __builtin_amdgcn_s_setprio(1);
      #pragma unroll
      for(int ks=0;ks<2;ks++){
        const f16x8 pf = *(const f16x8*)((const char*)&Pl[w][l16*64] + ((ks*64 + l4*16) ^ swz));
        #pragma unroll
        for(int j2=0;j2<4;j2++){
          const f16x8 vf = *(const f16x8*)((const char*)&Vl[(j2*16+l16)*64] + ((ks*64 + l4*16) ^ swz));
          o[mi][j2] = __builtin_amdgcn_mfma_f32_16x16x32_f16(pf, vf, o[mi][j2], 0,0,0);
        }
        osum[mi] = __builtin_amdgcn_mfma_f32_16x16x32_f16(pf, onesv, osum[mi], 0,0,0);
      }
      __builtin_amdgcn_s_setprio(0);
    }
  }
  // epilogue: o rows are q = mi*16 + l4*4 + r; osum has the row-sum in the SAME layout
  #pragma unroll
  for(int mi=0;mi<2;mi++){
    #pragma unroll
    for(int r=0;r<4;r++){
      const float iv = 1.f/osum[mi][r];
      const int row = q0 + w*32 + mi*16 + l4*4 + r;
      #pragma unroll
      for(int j2=0;j2<4;j2++)
        aout[(size_t)row*DIMS + h*HD + j2*16 + l16] = (h16)(o[mi][j2][r]*iv);
    }
  }
}

// ---------------- launch ----------------
extern "C" void kernel_launch(void* const* d_in, const int* in_sizes, int n_in,
                              void* d_out, int out_size, void* d_ws, size_t ws_size,
                              hipStream_t stream){
  const float* x    = (const float*)d_in[0];
  const float* qn_g = (const float*)d_in[1];
  const float* qn_b = (const float*)d_in[2];
  const float* Wq   = (const float*)d_in[3];
  const float* bq   = (const float*)d_in[4];
  const float* kvn_g= (const float*)d_in[5];
  const float* kvn_b= (const float*)d_in[6];
  const float* Wkv  = (const float*)d_in[7];
  const float* bkv  = (const float*)d_in[8];
  const float* Wout = (const float*)d_in[9];
  const float* bout = (const float*)d_in[10];
  const float* ln_g = (const float*)d_in[11];
  const float* ln_b = (const float*)d_in[12];
  const int*  skip  = (const int*)d_in[13];

  // Workspace budget ~75 MB; refuse (clean fail, no OOB scribble) if undersized.
  if(ws_size < (size_t)79*1000*1000) return;

  char* p = (char*)d_ws;
  size_t off = 0;
  auto take = [&](size_t n)->char*{
    char* r = p + off; off = (off + n + 255) & ~(size_t)255; return r;
  };
  h16*    xhat = (h16*)   take((size_t)SEQ*DIMS*2);   // reused as abuf after kv GEMM
  float*  mag  = (float*) take((size_t)SEQ*4);
  float2* tab  = (float2*)take((size_t)SEQ*32*8);
  h16*    WqT  = (h16*)   take((size_t)1024*1024*2);
  h16*    WkvT = (h16*)   take((size_t)2048*1024*2);
  h16*    WoutT= (h16*)   take((size_t)1024*1024*2);
  float*  bqp  = (float*) take(1024*4);
  float*  bkvp = (float*) take(2048*4);
  h16*    qn   = (h16*)   take((size_t)NH*SEQ*HD*2);
  h16*    kn   = (h16*)   take((size_t)NH*SEQ*HD*2);
  h16*    vT   = (h16*)   take((size_t)NH*HD*SEQ*2);
  float*  partq= (float*) take((size_t)16*1024*4);
  float*  partkv=(float*) take((size_t)16*2048*4);
  h16*    abuf = xhat;   // alias: xhat dead after kv GEMM, attn writes after

  k_ln_stats<<<dim3(SEQ), dim3(256), 0, stream>>>(x, xhat, mag);
  k_sincos<<<dim3(SEQ*32/256), dim3(256), 0, stream>>>(tab);
  k_fold_part2<<<dim3(12,16), dim3(256), 0, stream>>>(Wq, qn_b, Wkv, kvn_b, partq, partkv);
  k_fold_sum2<<<dim3(12), dim3(256), 0, stream>>>(partq, partkv, bq, bkv, bqp, bkvp);
  k_prep_w3<<<dim3(64,16), dim3(256), 0, stream>>>(Wq, qn_g, Wkv, kvn_g, Wout, WqT, WkvT, WoutT);
  k_gemm<1><<<dim3(8,64),  dim3(256), 0, stream>>>(xhat, WqT,  bqp, nullptr, qn, nullptr,
                                                   mag, tab, ln_g, ln_b, 1024, skip);
  k_gemm<2><<<dim3(16,64), dim3(256), 0, stream>>>(xhat, WkvT, bkvp, nullptr, kn, vT,
                                                   mag, tab, ln_g, ln_b, 2048, skip);
  k_pad_vt<<<dim3(1), dim3(256), 0, stream>>>(vT, skip);
  k_attn<<<dim3(16,64), dim3(256), 0, stream>>>(qn, kn, vT, abuf, skip);
  k_gemm<0><<<dim3(8,64), dim3(256), 0, stream>>>(abuf, WoutT, bout, (float*)d_out,
                                                  nullptr, nullptr, nullptr, nullptr,
                                                  nullptr, nullptr, 1024, skip);
}